// Round 20
// baseline (252.711 us; speedup 1.0000x reference)
//
#include <hip/hip_runtime.h>
#include <stdint.h>
#include <math.h>

#define B_    2
#define T_    2048
#define DIM_  2048
#define H_    16
#define DC_   512
#define DCQ_  1536
#define NROWS (B_*T_)   // 4096

typedef unsigned short u16;
typedef __attribute__((ext_vector_type(8))) __bf16 bf16x8;
typedef __attribute__((ext_vector_type(4))) float  f32x4;
typedef __attribute__((ext_vector_type(8))) unsigned short u16x8;
typedef __attribute__((ext_vector_type(4))) float  f4v;

__device__ __forceinline__ u16 f2bf(float f){
  unsigned u = __float_as_uint(f);
  u += 0x7FFFu + ((u >> 16) & 1u);   // RNE
  return (u16)(u >> 16);
}
__device__ __forceinline__ float bf2f(u16 h){ return __uint_as_float(((unsigned)h) << 16); }

__device__ __forceinline__ unsigned cvt_pk_bf16(float lo, float hi){
  unsigned r;
  asm("v_cvt_pk_bf16_f32 %0, %1, %2" : "=v"(r) : "v"(lo), "v"(hi));
  return r;
}

// async global->LDS, 16B per lane; LDS dest = wave-uniform base + lane*16.
__device__ __forceinline__ void gld_lds16(const void* g, void* l){
  auto gp = reinterpret_cast<__attribute__((address_space(1))) unsigned int*>(
      reinterpret_cast<uintptr_t>(g));
  auto lp = reinterpret_cast<__attribute__((address_space(3))) unsigned int*>(
      reinterpret_cast<uintptr_t>(l));
  __builtin_amdgcn_global_load_lds(gp, lp, 16, 0, 0);
}

__device__ __forceinline__ f32x4 mfma16(bf16x8 a, bf16x8 b, f32x4 c){
  return __builtin_amdgcn_mfma_f32_16x16x32_bf16(a, b, c, 0, 0, 0);
}

__device__ __forceinline__ void vmwait0(){ asm volatile("s_waitcnt vmcnt(0)" ::: "memory"); }
__device__ __forceinline__ void vmwait8(){ asm volatile("s_waitcnt vmcnt(8)" ::: "memory"); }
__device__ __forceinline__ void barr(){ asm volatile("s_barrier" ::: "memory"); }

// ---------------- dtype detect + ticket reset (8 XCD-partition tickets, stride 16)
__global__ void k_detect(const u16* cosr, int* flag, int* ticket){
  if (threadIdx.x == 0) *flag = (cosr[0] == (u16)0x3F80u) ? 1 : 0;
  if (threadIdx.x < 128) ticket[threadIdx.x] = 0;
}

// ---------------- merged x-convert + 8 weight transposes (one launch)
struct TDesc { const void* src; u16* dst; int srcStride, dstStride, cblk, nbx, blk0; };
struct TPack { TDesc d[8]; };
#define CONVBLK 8192

__global__ void k_prep(const void* __restrict__ xsrc, u16* __restrict__ x_bf,
                       TPack p, const int* flag){
  __shared__ u16 tile[64][72];
  const int bid = blockIdx.x;
  const int tid = threadIdx.x;
  const int f = *flag;
  if (bid < CONVBLK){
    if (f) return;                            // bf16 input: G13 reads x directly, skip copy
    int id = bid * 256 + tid;                 // n4 = 2097152 = 8192*256 exactly
    f4v v = reinterpret_cast<const f4v*>(xsrc)[id];
    unsigned lo = (unsigned)f2bf(v.x) | ((unsigned)f2bf(v.y) << 16);
    unsigned hi = (unsigned)f2bf(v.z) | ((unsigned)f2bf(v.w) << 16);
    reinterpret_cast<uint2*>(x_bf)[id] = make_uint2(lo, hi);
    return;
  }
  const int tb = bid - CONVBLK;
  int i = 0;
  #pragma unroll
  for (int k = 1; k < 8; ++k) if (tb >= p.d[k].blk0) i = k;
  const void* src = p.d[i].src;
  u16* dst = p.d[i].dst;
  const int srcStride = p.d[i].srcStride, dstStride = p.d[i].dstStride;
  const int rel = tb - p.d[i].blk0;
  const int bx = rel % p.d[i].nbx, by = rel / p.d[i].nbx;
  const int r0 = by << 6, c0 = bx * p.d[i].cblk;
  #pragma unroll
  for (int it = 0; it < 2; ++it){
    int task = (it << 8) + tid;
    int r = task >> 3, c8 = (task & 7) << 3;
    if (f){
      const u16* pp = (const u16*)src + (size_t)(r0 + r) * srcStride + c0 + c8;
      u16x8 v = *reinterpret_cast<const u16x8*>(pp);
      #pragma unroll
      for (int j = 0; j < 8; ++j) tile[r][c8 + j] = v[j];
    } else {
      const float* pp = (const float*)src + (size_t)(r0 + r) * srcStride + c0 + c8;
      f4v a = reinterpret_cast<const f4v*>(pp)[0];
      f4v b = reinterpret_cast<const f4v*>(pp)[1];
      tile[r][c8+0]=f2bf(a.x); tile[r][c8+1]=f2bf(a.y); tile[r][c8+2]=f2bf(a.z); tile[r][c8+3]=f2bf(a.w);
      tile[r][c8+4]=f2bf(b.x); tile[r][c8+5]=f2bf(b.y); tile[r][c8+6]=f2bf(b.z); tile[r][c8+7]=f2bf(b.w);
    }
  }
  __syncthreads();
  #pragma unroll
  for (int it = 0; it < 2; ++it){
    int task = (it << 8) + tid;
    int rr = task >> 3, cc8 = (task & 7) << 3;
    u16x8 v;
    #pragma unroll
    for (int j = 0; j < 8; ++j) v[j] = tile[cc8 + j][rr];
    *reinterpret_cast<u16x8*>(dst + (size_t)((bx << 6) + rr) * dstStride + r0 + cc8) = v;
  }
}

// ---------------- unified 128x128 GEMM: 256 thr / 4 waves (2x2), 64x64 per wave,
// LDS 64 KB -> 2 blocks/CU. Row-XOR swizzle via inverse-swizzled global_load_lds sources;
// counted vmcnt(8) pipeline; setprio around MFMA cluster. Two groups by N-tile index.
// alt-A: bf16 passthrough of unconverted input when *flag.
// vt: group output cols >= 1024 are V -> written TRANSPOSED to vT[bh][d][t].
// ropeK/ropeQ: N-tile 16 of G13 is the pre-rope block; rotation partner col c^32 is
// acc[mi][ni^2][j] (same thread) -> rope computed in-epilogue, xc store skipped.
__global__ __launch_bounds__(256, 2) void k_gemm(
    const u16* __restrict__ A0, int lda0, const u16* __restrict__ Bt0, int K0,
    u16* __restrict__ C0, int ldc0, float os0,
    const u16* __restrict__ A1, int lda1, const u16* __restrict__ Bt1, int K1,
    u16* __restrict__ C1, int ldc1, float os1,
    int ysplit, int swz, void* outp, const int* flag,
    const u16* __restrict__ alt0, const u16* __restrict__ alt1,
    u16* __restrict__ vt0, u16* __restrict__ vt1,
    const void* __restrict__ cosp, const void* __restrict__ sinp,
    u16* __restrict__ ropeK, u16* __restrict__ ropeQ){
  __shared__ alignas(16) u16 lds[32768];   // 64 KB
  const int tid = threadIdx.x;
  const int wid = tid >> 6, lane = tid & 63;
  const int wr = wid >> 1, wc = wid & 1;
  const int l16 = lane & 15, g = lane >> 4;
  int lin = blockIdx.y * 32 + blockIdx.x;    // gridDim.x == 32 (M-tiles)
  if (swz){
    const int q8 = (gridDim.x * gridDim.y) >> 3;
    lin = (lin & 7) * q8 + (lin >> 3);       // bijective XCD chunking (nwg%8==0)
  }
  const int m0 = (lin & 31) << 7;
  int nt = lin >> 5;
  const u16 *A, *Bt, *alt; u16 *C, *vtp; int lda, K, ldc; float oscale;
  if (nt < ysplit){ A = A0; lda = lda0; Bt = Bt0; K = K0; C = C0; ldc = ldc0; oscale = os0; alt = alt0; vtp = vt0; }
  else { nt -= ysplit; A = A1; lda = lda1; Bt = Bt1; K = K1; C = C1; ldc = ldc1; oscale = os1; alt = alt1; vtp = vt1; }
  const int f = flag ? *flag : 1;
  if (alt && f) A = alt;                     // bf16 input: read source directly
  const int n0 = nt << 7;
  const size_t Kz = (size_t)K;
  const int nkt = K >> 6;

  auto STAGE = [&](int kt, int bufn){
    const int kb = kt << 6;
    #pragma unroll
    for (int q = 0; q < 8; ++q){
      const int ht = q >> 2;                 // 0 = A half, 1 = B half
      const int cq = ((q & 3) << 8) + tid;   // chunk 0..1023 within half
      const int Lb = cq << 4;                // byte in [128][128B] half-tile
      const int row = Lb >> 7;
      const int colb = (Lb & 127) ^ ((row & 7) << 4);   // inverse-swizzled source
      const u16* src = ht ? (Bt + (size_t)(n0 + row) * Kz + kb + (colb >> 1))
                          : (A  + (size_t)(m0 + row) * lda + kb + (colb >> 1));
      gld_lds16(src, &lds[bufn * 16384 + ht * 8192 + (cq << 3)]);
    }
  };

  f32x4 acc[4][4] = {};

  STAGE(0, 0);
  int buf = 0;

  for (int kt = 0; kt < nkt; ++kt){
    if (kt + 1 < nkt){ STAGE(kt + 1, buf ^ 1); vmwait8(); }   // waits tile-kt's 8 loads
    else vmwait0();
    barr();                                                    // staged tile visible to all
    bf16x8 af[2][4], bfr[2][4];
    #pragma unroll
    for (int ks = 0; ks < 2; ++ks){
      #pragma unroll
      for (int mi = 0; mi < 4; ++mi){
        int row = (wr << 6) + (mi << 4) + l16;
        int cb = ((ks << 6) + (g << 4)) ^ ((row & 7) << 4);
        af[ks][mi] = *reinterpret_cast<const bf16x8*>(&lds[buf * 16384 + (((row << 7) + cb) >> 1)]);
      }
      #pragma unroll
      for (int ni = 0; ni < 4; ++ni){
        int row = (wc << 6) + (ni << 4) + l16;
        int cb = ((ks << 6) + (g << 4)) ^ ((row & 7) << 4);
        bfr[ks][ni] = *reinterpret_cast<const bf16x8*>(&lds[buf * 16384 + 8192 + (((row << 7) + cb) >> 1)]);
      }
    }
    __builtin_amdgcn_s_setprio(1);
    #pragma unroll
    for (int ks = 0; ks < 2; ++ks)
      #pragma unroll
      for (int mi = 0; mi < 4; ++mi)
        #pragma unroll
        for (int ni = 0; ni < 4; ++ni)
          acc[mi][ni] = mfma16(af[ks][mi], bfr[ks][ni], acc[mi][ni]);
    __builtin_amdgcn_s_setprio(0);
    barr();                                  // reads done before next STAGE overwrites
    buf ^= 1;
  }

  const int r4 = g << 2;

  if (ropeK && nt == 16){
    // Fused RoPE epilogue: this tile's cols 2048..2175 are the pre-rope block.
    // Thread owns cols d = ni*16+l16 (k part wc=0, q part wc=1); partner d^32 -> ni^2.
    const int dbase = l16;
    #pragma unroll
    for (int mi = 0; mi < 4; ++mi){
      int row = m0 + (wr << 6) + (mi << 4) + r4;
      #pragma unroll
      for (int ni = 0; ni < 4; ++ni){
        const int d = (ni << 4) + dbase;       // 0..63
        const int i = d & 31;
        #pragma unroll
        for (int j = 0; j < 4; ++j){
          int t = (row + j) & (T_ - 1);
          float cs, sn;
          if (f){ cs = bf2f(((const u16*)cosp)[t * 32 + i]); sn = bf2f(((const u16*)sinp)[t * 32 + i]); }
          else  { cs = ((const float*)cosp)[t * 32 + i];     sn = ((const float*)sinp)[t * 32 + i]; }
          float own = acc[mi][ni][j];
          float par = acc[mi][ni ^ 2][j];
          float v = (d < 32) ? (own * cs - par * sn) : (own * cs + par * sn);
          if (wc) v *= 0.12753139626374414f;   // q part: 1/sqrt(128)*log2(e)
          (wc ? ropeQ : ropeK)[(size_t)(row + j) * 64 + d] = f2bf(v);
        }
      }
    }
    return;
  }

  #pragma unroll
  for (int mi = 0; mi < 4; ++mi){
    int row = m0 + (wr << 6) + (mi << 4) + r4;
    #pragma unroll
    for (int ni = 0; ni < 4; ++ni){
      int col = n0 + (wc << 6) + (ni << 4) + l16;
      if (vtp && col >= 1024){
        // V quadrant: write transposed to vT[bh][d][t]; rows j are consecutive t.
        int hd = col - 1024;
        u16* dst = vtp + (((size_t)(((row >> 11) << 4) + (hd >> 7)) << 7) + (hd & 127)) * (size_t)T_ + (row & (T_ - 1));
        union { u16 u[4]; uint2 v; } pk;
        #pragma unroll
        for (int j = 0; j < 4; ++j) pk.u[j] = f2bf(acc[mi][ni][j] * oscale);
        *reinterpret_cast<uint2*>(dst) = pk.v;
        continue;
      }
      #pragma unroll
      for (int j = 0; j < 4; ++j){
        float v = acc[mi][ni][j] * oscale;
        if (outp){
          if (f) ((u16*)outp)[(size_t)(row + j) * ldc + col] = f2bf(v);
          else   ((float*)outp)[(size_t)(row + j) * ldc + col] = v;
        } else {
          C[(size_t)(row + j) * ldc + col] = f2bf(v);
        }
      }
    }
  }
}

// ---------------- causal flash attention: 128-row items, 8 waves x 16 rows (512 thr).
// Round-17 config (measured best): 256 workers (1 block/CU), per-XCD tickets,
// 64 items over 32 workers/partition = 2:1 heavy-first STEALING (1:1 maps regress --
// rounds 12 & 18). 64KB LDS double-buffer; setprio around MFMA clusters.
__global__ __launch_bounds__(512, 2) void k_attn(const u16* __restrict__ qP,
                                                 const u16* __restrict__ kvP,
                                                 const u16* __restrict__ vT,
                                                 const u16* __restrict__ krope,
                                                 const u16* __restrict__ qrope,
                                                 u16* __restrict__ aout,
                                                 int* __restrict__ ticket){
  __shared__ alignas(16) u16 smem[32768];   // 64 KB: 2 buffers x (K [64][128] + V [128][64])
  const int tid = threadIdx.x, wid = tid >> 6, lane = tid & 63;
  const int l16 = lane & 15, g = lane >> 4;
  const int lk = g << 3, r4 = g << 2;
  const int sw8 = (l16 & 7) << 3;
  const int xcd = blockIdx.x & 7;

  while (true){
    if (tid == 0) *(int*)&smem[0] = atomicAdd(&ticket[xcd << 4], 1);
    __syncthreads();
    const int it = *(const int*)&smem[0];
    __syncthreads();
    if (it >= 64) break;
    const int qt = 15 - (it >> 2);          // heavy-first within partition (128-row tiles)
    const int bh = (xcd << 2) + (it & 3), b = bh >> 4, h = bh & 15;
    const int q0 = qt << 7;
    const size_t bT = (size_t)b * T_;
    const u16* kvPb = kvP + bT * 1024 + (h << 6);
    const u16* krb  = krope + bT * 64;
    const u16* vTb  = vT + (size_t)bh * 128 * T_;
    const int qlo = q0 + (wid << 4);
    const int qhi = qlo + 15;
    const int nkv = (qt << 1) + 2;

    auto STAGE = [&](int buf, int k0){
      const int base = buf << 14;
      #pragma unroll
      for (int r = 0; r < 4; ++r){
        int c = (r << 9) + tid;              // 0..2047 chunks of 16B
        const u16* src;
        if (r < 2){
          int row = c >> 4, cc = c & 15;
          int ccx = (cc & 8) | ((cc & 7) ^ (row & 7));
          int col0 = ccx << 3;
          src = (col0 < 64) ? (kvPb + (size_t)(k0 + row) * 1024 + col0)
                            : (krb  + (size_t)(k0 + row) * 64 + (col0 - 64));
        } else {
          int cv = c - 1024;
          int row = cv >> 3, cc = cv & 7;
          int ccx = cc ^ (row & 7);
          src = vTb + (size_t)row * T_ + k0 + (ccx << 3);
        }
        gld_lds16(src, &smem[base + (c << 3)]);
      }
    };

    bf16x8 qf[4];
    {
      size_t grow = bT + qlo + l16;
      #pragma unroll
      for (int ks = 0; ks < 4; ++ks){
        int d = (ks << 5) + lk;
        const u16* src = (ks < 2) ? (qP + grow * 1024 + (h << 6) + d)
                                  : (qrope + grow * 64 + (d - 64));
        qf[ks] = *reinterpret_cast<const bf16x8*>(src);
      }
    }
    f32x4 o[8] = {};
    float m = -3e38f, l = 0.f;

    STAGE(0, 0);
    __syncthreads();
    int cur = 0;

    for (int kv = 0; kv < nkv; ++kv){
      const int k0 = kv << 6;
      if (kv + 1 < nkv) STAGE(cur ^ 1, (kv + 1) << 6);
      if (k0 <= qhi){
        const int kb = cur << 14;
        f32x4 s[4] = {};
        __builtin_amdgcn_s_setprio(1);
        #pragma unroll
        for (int ks = 0; ks < 4; ++ks){
          int colsw = ((ks << 5) + lk) ^ sw8;
          #pragma unroll
          for (int n = 0; n < 4; ++n){
            bf16x8 kf = *reinterpret_cast<const bf16x8*>(&smem[kb + ((n << 4) + l16) * 128 + colsw]);
            s[n] = mfma16(kf, qf[ks], s[n]);
          }
        }
        __builtin_amdgcn_s_setprio(0);
        if (k0 + 63 > qlo){                  // only the wave's diagonal tile needs masking
          const int tq = qlo + l16;
          #pragma unroll
          for (int n = 0; n < 4; ++n)
            #pragma unroll
            for (int j = 0; j < 4; ++j)
              s[n][j] = (k0 + (n << 4) + r4 + j <= tq) ? s[n][j] : -3e38f;
        }
        float mx;
        {
          float a0 = fmaxf(fmaxf(s[0][0], s[0][1]), fmaxf(s[0][2], s[0][3]));
          float a1 = fmaxf(fmaxf(s[1][0], s[1][1]), fmaxf(s[1][2], s[1][3]));
          float a2 = fmaxf(fmaxf(s[2][0], s[2][1]), fmaxf(s[2][2], s[2][3]));
          float a3 = fmaxf(fmaxf(s[3][0], s[3][1]), fmaxf(s[3][2], s[3][3]));
          mx = fmaxf(fmaxf(a0, a1), fmaxf(a2, a3));
          mx = fmaxf(mx, __shfl_xor(mx, 16));
          mx = fmaxf(mx, __shfl_xor(mx, 32));
        }
        if (__ballot(mx > m + 8.f)){
          float mnew = fmaxf(m, mx);
          float alpha = exp2f(m - mnew);
          m = mnew; l *= alpha;
          #pragma unroll
          for (int j = 0; j < 4; ++j){
            float av = __shfl(alpha, r4 + j);
            #pragma unroll
            for (int db = 0; db < 8; ++db) o[db][j] *= av;
          }
        }
        unsigned w[4][2];
        float rs = 0.f;
        #pragma unroll
        for (int n = 0; n < 4; ++n)
          #pragma unroll
          for (int jh = 0; jh < 2; ++jh){
            float p0 = exp2f(s[n][2*jh]     - m);
            float p1 = exp2f(s[n][2*jh + 1] - m);
            rs += p0 + p1;
            w[n][jh] = cvt_pk_bf16(p0, p1);
          }
        rs += __shfl_xor(rs, 16);
        rs += __shfl_xor(rs, 32);
        l += rs;
        const int srcA = l16 + ((g & 1) << 5);
        const int srcB = srcA + 16;
        const bool hi = (g >= 2);
        bf16x8 pa[2];
        #pragma unroll
        for (int ks2 = 0; ks2 < 2; ++ks2){
          unsigned a0 = __shfl((int)w[2*ks2][0],     srcA);
          unsigned b0 = __shfl((int)w[2*ks2 + 1][0], srcA);
          unsigned a1 = __shfl((int)w[2*ks2][1],     srcA);
          unsigned b1 = __shfl((int)w[2*ks2 + 1][1], srcA);
          unsigned a2 = __shfl((int)w[2*ks2][0],     srcB);
          unsigned b2 = __shfl((int)w[2*ks2 + 1][0], srcB);
          unsigned a3 = __shfl((int)w[2*ks2][1],     srcB);
          unsigned b3 = __shfl((int)w[2*ks2 + 1][1], srcB);
          union { unsigned u[4]; bf16x8 v; } pk;
          pk.u[0] = hi ? b0 : a0;
          pk.u[1] = hi ? b1 : a1;
          pk.u[2] = hi ? b2 : a2;
          pk.u[3] = hi ? b3 : a3;
          pa[ks2] = pk.v;
        }
        __builtin_amdgcn_s_setprio(1);
        #pragma unroll
        for (int ks2 = 0; ks2 < 2; ++ks2){
          int colsw = ((ks2 << 5) + lk) ^ sw8;
          #pragma unroll
          for (int db = 0; db < 8; ++db){
            bf16x8 vb = *reinterpret_cast<const bf16x8*>(&smem[(cur << 14) + 8192 + ((db << 4) + l16) * 64 + colsw]);
            o[db] = mfma16(pa[ks2], vb, o[db]);
          }
        }
        __builtin_amdgcn_s_setprio(0);
      }
      __syncthreads();                      // drains prefetch; reads done before buffer reuse
      cur ^= 1;
    }
    #pragma unroll
    for (int j = 0; j < 4; ++j){
      float lv = __shfl(l, r4 + j);
      float rinv = 1.f / lv;
      const int tq = qlo + r4 + j;
      u16* dst = aout + (bT + tq) * 2048 + (h << 7) + l16;
      #pragma unroll
      for (int db = 0; db < 8; ++db)
        dst[db << 4] = f2bf(o[db][j] * rinv);
    }
  }
}

extern "C" void kernel_launch(void* const* d_in, const int* in_sizes, int n_in,
                              void* d_out, int out_size, void* d_ws, size_t ws_size,
                              hipStream_t stream){
  const void* x       = d_in[0];
  const void* cosp    = d_in[1];
  const void* sinp    = d_in[2];
  const void* w_kv    = d_in[3];
  const void* w_kdec  = d_in[4];
  const void* w_vdec  = d_in[5];
  const void* w_qc    = d_in[6];
  const void* w_qdec  = d_in[7];
  const void* w_krope = d_in[8];
  const void* w_qrope = d_in[9];
  const void* w_o     = d_in[10];

  char* ws = (char*)d_ws;
  size_t off = 0;
  auto alloc = [&](size_t bytes){ void* p = ws + off; off += (bytes + 255) & ~(size_t)255; return p; };
  int* flag     = (int*)alloc(256);
  int* ticket   = (int*)alloc(1024);                         // 8 tickets, stride 16 ints
  u16* x_bf     = (u16*)alloc((size_t)NROWS * DIM_ * 2);
  u16* w_c1T    = (u16*)alloc((size_t)2304 * DIM_ * 2);      // [kvT(512); qcT(1536); kropeT(64); qropeT(64); pad(128)] x 2048
  u16* w_kvdT   = (u16*)alloc((size_t)3072 * DC_ * 2);       // [kdecPackedT(1024); vdecT(2048)] x 512
  u16* w_qdPT   = (u16*)alloc((size_t)1024 * DCQ_ * 2);      // packed qdecT (1024 x 1536)
  u16* w_oT     = (u16*)alloc((size_t)DIM_ * DIM_ * 2);
  u16* xc       = (u16*)alloc((size_t)NROWS * 2304 * 2);     // [c_kv(512) | c_q(1536) | rope-unused]
  u16* qP       = (u16*)alloc((size_t)NROWS * 1024 * 2);     // packed q decode (pre-scaled)
  u16* kvP      = (u16*)alloc((size_t)NROWS * 1024 * 2);     // packed K only (stride 1024)
  u16* krope    = (u16*)alloc((size_t)NROWS * 64 * 2);
  u16* qrope    = (u16*)alloc((size_t)NROWS * 64 * 2);       // pre-scaled
  u16* vT       = (u16*)alloc((size_t)32 * 128 * T_ * 2);    // [bh][d][t], written by G2 epilogue
  u16* aout     = (u16*)alloc((size_t)NROWS * DIM_ * 2);
  (void)in_sizes; (void)n_in; (void)out_size; (void)ws_size;

  const float SC2 = 0.12753139626374414f;   // 1/sqrt(128) * log2(e)

  hipLaunchKernelGGL(k_detect, dim3(1), dim3(128), 0, stream, (const u16*)cosp, flag, ticket);

  // merged x-convert + weight transposes (8192 conv blocks + 2880 transpose blocks)
  TPack tp;
  tp.d[0] = { w_kv,    w_c1T,                        512,  2048, 64,  8,  0    };
  tp.d[1] = { w_qc,    w_c1T + (size_t)512 * 2048,   1536, 2048, 64,  24, 256  };
  tp.d[2] = { w_krope, w_c1T + (size_t)2048 * 2048,  64,   2048, 64,  1,  1024 };
  tp.d[3] = { w_qrope, w_c1T + (size_t)2112 * 2048,  64,   2048, 64,  1,  1056 };
  tp.d[4] = { w_kdec,  w_kvdT,                       2048, 512,  128, 16, 1088 };
  tp.d[5] = { w_vdec,  w_kvdT + (size_t)1024 * 512,  2048, 512,  64,  32, 1216 };
  tp.d[6] = { w_qdec,  w_qdPT,                       2048, 1536, 128, 16, 1472 };
  tp.d[7] = { w_o,     w_oT,                         2048, 2048, 64,  32, 1856 };
  hipLaunchKernelGGL(k_prep, dim3(CONVBLK + 2880), dim3(256), 0, stream, x, x_bf, tp, flag);

  // G13: xc[:, :2048] = x @ [w_kv | w_qc]; N-tile 16 = rope block -> fused RoPE epilogue.
  // Grid (32,17) = 544 blocks (pad tile dropped; 544%8==0 keeps swizzle bijective).
  hipLaunchKernelGGL(k_gemm, dim3(32, 17), dim3(256), 0, stream,
                     x_bf, DIM_, w_c1T, DIM_, xc, 2304, 1.0f,
                     x_bf, DIM_, w_c1T, DIM_, xc, 2304, 1.0f,
                     17, 1, (void*)nullptr, (const int*)flag,
                     (const u16*)x, (const u16*)x,
                     (u16*)nullptr, (u16*)nullptr,
                     cosp, sinp, krope, qrope);
  // G4 + G2 grouped on 128^2 tiles (1024 blocks; heavy K=1536 group first):
  //   nt<8:  qP = xc[:, 512:2048] @ w_qdecP  (4096 x 1024, K=1536), pre-scaled
  //   nt>=8: K -> kvP (stride 1024, cols<1024); V -> vT DIRECT TRANSPOSED (cols>=1024)
  hipLaunchKernelGGL(k_gemm, dim3(32, 32), dim3(256), 0, stream,
                     xc + 512, 2304, w_qdPT, DCQ_, qP, 1024, SC2,
                     xc, 2304, w_kvdT, DC_, kvP, 1024, 1.0f,
                     8, 0, (void*)nullptr, (const int*)nullptr,
                     (const u16*)nullptr, (const u16*)nullptr,
                     (u16*)nullptr, vT,
                     (const void*)nullptr, (const void*)nullptr,
                     (u16*)nullptr, (u16*)nullptr);
  // attention (256 workers x 8 waves, 128-row items, 2:1 stealing, XCD-partitioned tickets)
  hipLaunchKernelGGL(k_attn, dim3(256), dim3(512), 0, stream,
                     qP, kvP, vT, krope, qrope, aout, ticket);
  // G5: out = aout @ w_o  (4096 x 2048, K=2048) -> (32,16) = 512 blocks = 2/CU, XCD-chunked
  hipLaunchKernelGGL(k_gemm, dim3(32, 16), dim3(256), 0, stream,
                     aout, DIM_, w_oT, DIM_, (u16*)nullptr, DIM_, 1.0f,
                     aout, DIM_, w_oT, DIM_, (u16*)nullptr, DIM_, 1.0f,
                     16, 1, d_out, (const int*)flag,
                     (const u16*)nullptr, (const u16*)nullptr,
                     (u16*)nullptr, (u16*)nullptr,
                     (const void*)nullptr, (const void*)nullptr,
                     (u16*)nullptr, (u16*)nullptr);
}

// Round 21
// 248.546 us; speedup vs baseline: 1.0168x; 1.0168x over previous
//
#include <hip/hip_runtime.h>
#include <stdint.h>
#include <math.h>

#define B_    2
#define T_    2048
#define DIM_  2048
#define H_    16
#define DC_   512
#define DCQ_  1536
#define NROWS (B_*T_)   // 4096

typedef unsigned short u16;
typedef __attribute__((ext_vector_type(8))) __bf16 bf16x8;
typedef __attribute__((ext_vector_type(4))) float  f32x4;
typedef __attribute__((ext_vector_type(8))) unsigned short u16x8;
typedef __attribute__((ext_vector_type(4))) float  f4v;

__device__ __forceinline__ u16 f2bf(float f){
  unsigned u = __float_as_uint(f);
  u += 0x7FFFu + ((u >> 16) & 1u);   // RNE
  return (u16)(u >> 16);
}
__device__ __forceinline__ float bf2f(u16 h){ return __uint_as_float(((unsigned)h) << 16); }

__device__ __forceinline__ unsigned cvt_pk_bf16(float lo, float hi){
  unsigned r;
  asm("v_cvt_pk_bf16_f32 %0, %1, %2" : "=v"(r) : "v"(lo), "v"(hi));
  return r;
}

// async global->LDS, 16B per lane; LDS dest = wave-uniform base + lane*16.
__device__ __forceinline__ void gld_lds16(const void* g, void* l){
  auto gp = reinterpret_cast<__attribute__((address_space(1))) unsigned int*>(
      reinterpret_cast<uintptr_t>(g));
  auto lp = reinterpret_cast<__attribute__((address_space(3))) unsigned int*>(
      reinterpret_cast<uintptr_t>(l));
  __builtin_amdgcn_global_load_lds(gp, lp, 16, 0, 0);
}

__device__ __forceinline__ f32x4 mfma16(bf16x8 a, bf16x8 b, f32x4 c){
  return __builtin_amdgcn_mfma_f32_16x16x32_bf16(a, b, c, 0, 0, 0);
}

__device__ __forceinline__ void vmwait0(){ asm volatile("s_waitcnt vmcnt(0)" ::: "memory"); }
__device__ __forceinline__ void vmwait8(){ asm volatile("s_waitcnt vmcnt(8)" ::: "memory"); }
__device__ __forceinline__ void barr(){ asm volatile("s_barrier" ::: "memory"); }

// ---------------- dtype detect + ticket reset (8 XCD-partition tickets, stride 16)
__global__ void k_detect(const u16* cosr, int* flag, int* ticket){
  if (threadIdx.x == 0) *flag = (cosr[0] == (u16)0x3F80u) ? 1 : 0;
  if (threadIdx.x < 128) ticket[threadIdx.x] = 0;
}

// ---------------- merged x-convert + 8 weight transposes (one launch)
struct TDesc { const void* src; u16* dst; int srcStride, dstStride, cblk, nbx, blk0; };
struct TPack { TDesc d[8]; };
#define CONVBLK 8192

__global__ void k_prep(const void* __restrict__ xsrc, u16* __restrict__ x_bf,
                       TPack p, const int* flag){
  __shared__ u16 tile[64][72];
  const int bid = blockIdx.x;
  const int tid = threadIdx.x;
  const int f = *flag;
  if (bid < CONVBLK){
    if (f) return;                            // bf16 input: G13 reads x directly, skip copy
    int id = bid * 256 + tid;                 // n4 = 2097152 = 8192*256 exactly
    f4v v = reinterpret_cast<const f4v*>(xsrc)[id];
    unsigned lo = (unsigned)f2bf(v.x) | ((unsigned)f2bf(v.y) << 16);
    unsigned hi = (unsigned)f2bf(v.z) | ((unsigned)f2bf(v.w) << 16);
    reinterpret_cast<uint2*>(x_bf)[id] = make_uint2(lo, hi);
    return;
  }
  const int tb = bid - CONVBLK;
  int i = 0;
  #pragma unroll
  for (int k = 1; k < 8; ++k) if (tb >= p.d[k].blk0) i = k;
  const void* src = p.d[i].src;
  u16* dst = p.d[i].dst;
  const int srcStride = p.d[i].srcStride, dstStride = p.d[i].dstStride;
  const int rel = tb - p.d[i].blk0;
  const int bx = rel % p.d[i].nbx, by = rel / p.d[i].nbx;
  const int r0 = by << 6, c0 = bx * p.d[i].cblk;
  #pragma unroll
  for (int it = 0; it < 2; ++it){
    int task = (it << 8) + tid;
    int r = task >> 3, c8 = (task & 7) << 3;
    if (f){
      const u16* pp = (const u16*)src + (size_t)(r0 + r) * srcStride + c0 + c8;
      u16x8 v = *reinterpret_cast<const u16x8*>(pp);
      #pragma unroll
      for (int j = 0; j < 8; ++j) tile[r][c8 + j] = v[j];
    } else {
      const float* pp = (const float*)src + (size_t)(r0 + r) * srcStride + c0 + c8;
      f4v a = reinterpret_cast<const f4v*>(pp)[0];
      f4v b = reinterpret_cast<const f4v*>(pp)[1];
      tile[r][c8+0]=f2bf(a.x); tile[r][c8+1]=f2bf(a.y); tile[r][c8+2]=f2bf(a.z); tile[r][c8+3]=f2bf(a.w);
      tile[r][c8+4]=f2bf(b.x); tile[r][c8+5]=f2bf(b.y); tile[r][c8+6]=f2bf(b.z); tile[r][c8+7]=f2bf(b.w);
    }
  }
  __syncthreads();
  #pragma unroll
  for (int it = 0; it < 2; ++it){
    int task = (it << 8) + tid;
    int rr = task >> 3, cc8 = (task & 7) << 3;
    u16x8 v;
    #pragma unroll
    for (int j = 0; j < 8; ++j) v[j] = tile[cc8 + j][rr];
    *reinterpret_cast<u16x8*>(dst + (size_t)((bx << 6) + rr) * dstStride + r0 + cc8) = v;
  }
}

// ---------------- unified 128x128 GEMM: 256 thr / 4 waves (2x2), 64x64 per wave,
// LDS 64 KB -> 2 blocks/CU. Row-XOR swizzle via inverse-swizzled global_load_lds sources;
// counted vmcnt(8) pipeline; setprio around MFMA cluster. Two groups by N-tile index.
// alt-A: bf16 passthrough of unconverted input when *flag.
// vt: group output cols >= 1024 are V -> written TRANSPOSED to vT[bh][d][t].
__global__ __launch_bounds__(256, 2) void k_gemm(
    const u16* __restrict__ A0, int lda0, const u16* __restrict__ Bt0, int K0,
    u16* __restrict__ C0, int ldc0, float os0,
    const u16* __restrict__ A1, int lda1, const u16* __restrict__ Bt1, int K1,
    u16* __restrict__ C1, int ldc1, float os1,
    int ysplit, int swz, void* outp, const int* flag,
    const u16* __restrict__ alt0, const u16* __restrict__ alt1,
    u16* __restrict__ vt0, u16* __restrict__ vt1){
  __shared__ alignas(16) u16 lds[32768];   // 64 KB
  const int tid = threadIdx.x;
  const int wid = tid >> 6, lane = tid & 63;
  const int wr = wid >> 1, wc = wid & 1;
  const int l16 = lane & 15, g = lane >> 4;
  int lin = blockIdx.y * 32 + blockIdx.x;    // gridDim.x == 32 (M-tiles)
  if (swz){
    const int q8 = (gridDim.x * gridDim.y) >> 3;
    lin = (lin & 7) * q8 + (lin >> 3);       // bijective XCD chunking (nwg%8==0)
  }
  const int m0 = (lin & 31) << 7;
  int nt = lin >> 5;
  const u16 *A, *Bt, *alt; u16 *C, *vtp; int lda, K, ldc; float oscale;
  if (nt < ysplit){ A = A0; lda = lda0; Bt = Bt0; K = K0; C = C0; ldc = ldc0; oscale = os0; alt = alt0; vtp = vt0; }
  else { nt -= ysplit; A = A1; lda = lda1; Bt = Bt1; K = K1; C = C1; ldc = ldc1; oscale = os1; alt = alt1; vtp = vt1; }
  const int f = flag ? *flag : 1;
  if (alt && f) A = alt;                     // bf16 input: read source directly
  const int n0 = nt << 7;
  const size_t Kz = (size_t)K;
  const int nkt = K >> 6;

  auto STAGE = [&](int kt, int bufn){
    const int kb = kt << 6;
    #pragma unroll
    for (int q = 0; q < 8; ++q){
      const int ht = q >> 2;                 // 0 = A half, 1 = B half
      const int cq = ((q & 3) << 8) + tid;   // chunk 0..1023 within half
      const int Lb = cq << 4;                // byte in [128][128B] half-tile
      const int row = Lb >> 7;
      const int colb = (Lb & 127) ^ ((row & 7) << 4);   // inverse-swizzled source
      const u16* src = ht ? (Bt + (size_t)(n0 + row) * Kz + kb + (colb >> 1))
                          : (A  + (size_t)(m0 + row) * lda + kb + (colb >> 1));
      gld_lds16(src, &lds[bufn * 16384 + ht * 8192 + (cq << 3)]);
    }
  };

  f32x4 acc[4][4] = {};

  STAGE(0, 0);
  int buf = 0;

  for (int kt = 0; kt < nkt; ++kt){
    if (kt + 1 < nkt){ STAGE(kt + 1, buf ^ 1); vmwait8(); }   // waits tile-kt's 8 loads
    else vmwait0();
    barr();                                                    // staged tile visible to all
    bf16x8 af[2][4], bfr[2][4];
    #pragma unroll
    for (int ks = 0; ks < 2; ++ks){
      #pragma unroll
      for (int mi = 0; mi < 4; ++mi){
        int row = (wr << 6) + (mi << 4) + l16;
        int cb = ((ks << 6) + (g << 4)) ^ ((row & 7) << 4);
        af[ks][mi] = *reinterpret_cast<const bf16x8*>(&lds[buf * 16384 + (((row << 7) + cb) >> 1)]);
      }
      #pragma unroll
      for (int ni = 0; ni < 4; ++ni){
        int row = (wc << 6) + (ni << 4) + l16;
        int cb = ((ks << 6) + (g << 4)) ^ ((row & 7) << 4);
        bfr[ks][ni] = *reinterpret_cast<const bf16x8*>(&lds[buf * 16384 + 8192 + (((row << 7) + cb) >> 1)]);
      }
    }
    __builtin_amdgcn_s_setprio(1);
    #pragma unroll
    for (int ks = 0; ks < 2; ++ks)
      #pragma unroll
      for (int mi = 0; mi < 4; ++mi)
        #pragma unroll
        for (int ni = 0; ni < 4; ++ni)
          acc[mi][ni] = mfma16(af[ks][mi], bfr[ks][ni], acc[mi][ni]);
    __builtin_amdgcn_s_setprio(0);
    barr();                                  // reads done before next STAGE overwrites
    buf ^= 1;
  }

  const int r4 = g << 2;
  #pragma unroll
  for (int mi = 0; mi < 4; ++mi){
    int row = m0 + (wr << 6) + (mi << 4) + r4;
    #pragma unroll
    for (int ni = 0; ni < 4; ++ni){
      int col = n0 + (wc << 6) + (ni << 4) + l16;
      if (vtp && col >= 1024){
        // V quadrant: write transposed to vT[bh][d][t]; rows j are consecutive t.
        int hd = col - 1024;
        u16* dst = vtp + (((size_t)(((row >> 11) << 4) + (hd >> 7)) << 7) + (hd & 127)) * (size_t)T_ + (row & (T_ - 1));
        union { u16 u[4]; uint2 v; } pk;
        #pragma unroll
        for (int j = 0; j < 4; ++j) pk.u[j] = f2bf(acc[mi][ni][j] * oscale);
        *reinterpret_cast<uint2*>(dst) = pk.v;
        continue;
      }
      #pragma unroll
      for (int j = 0; j < 4; ++j){
        float v = acc[mi][ni][j] * oscale;
        if (outp){
          if (f) ((u16*)outp)[(size_t)(row + j) * ldc + col] = f2bf(v);
          else   ((float*)outp)[(size_t)(row + j) * ldc + col] = v;
        } else {
          C[(size_t)(row + j) * ldc + col] = f2bf(v);
        }
      }
    }
  }
}

// ---------------- RoPE (2048 blocks; reads xc cols 2048..2175, stride 2304)
__global__ void k_rope(const u16* __restrict__ xc, const void* __restrict__ cosp,
                       const void* __restrict__ sinp, const int* flag,
                       u16* __restrict__ krope, u16* __restrict__ qrope){
  int id = blockIdx.x * 256 + threadIdx.x;   // exactly NROWS*128
  int row = id >> 7, c = id & 127;
  int t = row & (T_ - 1);
  int d = c & 63, i = d & 31;
  float cs, sn;
  if (*flag){ cs = bf2f(((const u16*)cosp)[t * 32 + i]); sn = bf2f(((const u16*)sinp)[t * 32 + i]); }
  else      { cs = ((const float*)cosp)[t * 32 + i];     sn = ((const float*)sinp)[t * 32 + i]; }
  int base = c & 64;
  float t1 = bf2f(xc[(size_t)row * 2304 + 2048 + base + i]);
  float t2 = bf2f(xc[(size_t)row * 2304 + 2048 + base + 32 + i]);
  float v = (d < 32) ? (t1 * cs - t2 * sn) : (t2 * cs + t1 * sn);
  if (c >= 64) v *= 0.12753139626374414f;   // 1/sqrt(128)*log2(e) folded into q
  ((c < 64) ? krope : qrope)[(size_t)row * 64 + d] = f2bf(v);
}

// ---------------- causal flash attention: 128-row items, 8 waves x 16 rows (512 thr).
// Round-17 config (measured best): 256 workers (1 block/CU), per-XCD tickets,
// 64 items over 32 workers/partition = 2:1 heavy-first STEALING (1:1 maps regress --
// rounds 12 & 18). 64KB LDS double-buffer; setprio around MFMA clusters.
__global__ __launch_bounds__(512, 2) void k_attn(const u16* __restrict__ qP,
                                                 const u16* __restrict__ kvP,
                                                 const u16* __restrict__ vT,
                                                 const u16* __restrict__ krope,
                                                 const u16* __restrict__ qrope,
                                                 u16* __restrict__ aout,
                                                 int* __restrict__ ticket){
  __shared__ alignas(16) u16 smem[32768];   // 64 KB: 2 buffers x (K [64][128] + V [128][64])
  const int tid = threadIdx.x, wid = tid >> 6, lane = tid & 63;
  const int l16 = lane & 15, g = lane >> 4;
  const int lk = g << 3, r4 = g << 2;
  const int sw8 = (l16 & 7) << 3;
  const int xcd = blockIdx.x & 7;

  while (true){
    if (tid == 0) *(int*)&smem[0] = atomicAdd(&ticket[xcd << 4], 1);
    __syncthreads();
    const int it = *(const int*)&smem[0];
    __syncthreads();
    if (it >= 64) break;
    const int qt = 15 - (it >> 2);          // heavy-first within partition (128-row tiles)
    const int bh = (xcd << 2) + (it & 3), b = bh >> 4, h = bh & 15;
    const int q0 = qt << 7;
    const size_t bT = (size_t)b * T_;
    const u16* kvPb = kvP + bT * 1024 + (h << 6);
    const u16* krb  = krope + bT * 64;
    const u16* vTb  = vT + (size_t)bh * 128 * T_;
    const int qlo = q0 + (wid << 4);
    const int qhi = qlo + 15;
    const int nkv = (qt << 1) + 2;

    auto STAGE = [&](int buf, int k0){
      const int base = buf << 14;
      #pragma unroll
      for (int r = 0; r < 4; ++r){
        int c = (r << 9) + tid;              // 0..2047 chunks of 16B
        const u16* src;
        if (r < 2){
          int row = c >> 4, cc = c & 15;
          int ccx = (cc & 8) | ((cc & 7) ^ (row & 7));
          int col0 = ccx << 3;
          src = (col0 < 64) ? (kvPb + (size_t)(k0 + row) * 1024 + col0)
                            : (krb  + (size_t)(k0 + row) * 64 + (col0 - 64));
        } else {
          int cv = c - 1024;
          int row = cv >> 3, cc = cv & 7;
          int ccx = cc ^ (row & 7);
          src = vTb + (size_t)row * T_ + k0 + (ccx << 3);
        }
        gld_lds16(src, &smem[base + (c << 3)]);
      }
    };

    bf16x8 qf[4];
    {
      size_t grow = bT + qlo + l16;
      #pragma unroll
      for (int ks = 0; ks < 4; ++ks){
        int d = (ks << 5) + lk;
        const u16* src = (ks < 2) ? (qP + grow * 1024 + (h << 6) + d)
                                  : (qrope + grow * 64 + (d - 64));
        qf[ks] = *reinterpret_cast<const bf16x8*>(src);
      }
    }
    f32x4 o[8] = {};
    float m = -3e38f, l = 0.f;

    STAGE(0, 0);
    __syncthreads();
    int cur = 0;

    for (int kv = 0; kv < nkv; ++kv){
      const int k0 = kv << 6;
      if (kv + 1 < nkv) STAGE(cur ^ 1, (kv + 1) << 6);
      if (k0 <= qhi){
        const int kb = cur << 14;
        f32x4 s[4] = {};
        __builtin_amdgcn_s_setprio(1);
        #pragma unroll
        for (int ks = 0; ks < 4; ++ks){
          int colsw = ((ks << 5) + lk) ^ sw8;
          #pragma unroll
          for (int n = 0; n < 4; ++n){
            bf16x8 kf = *reinterpret_cast<const bf16x8*>(&smem[kb + ((n << 4) + l16) * 128 + colsw]);
            s[n] = mfma16(kf, qf[ks], s[n]);
          }
        }
        __builtin_amdgcn_s_setprio(0);
        if (k0 + 63 > qlo){                  // only the wave's diagonal tile needs masking
          const int tq = qlo + l16;
          #pragma unroll
          for (int n = 0; n < 4; ++n)
            #pragma unroll
            for (int j = 0; j < 4; ++j)
              s[n][j] = (k0 + (n << 4) + r4 + j <= tq) ? s[n][j] : -3e38f;
        }
        float mx;
        {
          float a0 = fmaxf(fmaxf(s[0][0], s[0][1]), fmaxf(s[0][2], s[0][3]));
          float a1 = fmaxf(fmaxf(s[1][0], s[1][1]), fmaxf(s[1][2], s[1][3]));
          float a2 = fmaxf(fmaxf(s[2][0], s[2][1]), fmaxf(s[2][2], s[2][3]));
          float a3 = fmaxf(fmaxf(s[3][0], s[3][1]), fmaxf(s[3][2], s[3][3]));
          mx = fmaxf(fmaxf(a0, a1), fmaxf(a2, a3));
          mx = fmaxf(mx, __shfl_xor(mx, 16));
          mx = fmaxf(mx, __shfl_xor(mx, 32));
        }
        if (__ballot(mx > m + 8.f)){
          float mnew = fmaxf(m, mx);
          float alpha = exp2f(m - mnew);
          m = mnew; l *= alpha;
          #pragma unroll
          for (int j = 0; j < 4; ++j){
            float av = __shfl(alpha, r4 + j);
            #pragma unroll
            for (int db = 0; db < 8; ++db) o[db][j] *= av;
          }
        }
        unsigned w[4][2];
        float rs = 0.f;
        #pragma unroll
        for (int n = 0; n < 4; ++n)
          #pragma unroll
          for (int jh = 0; jh < 2; ++jh){
            float p0 = exp2f(s[n][2*jh]     - m);
            float p1 = exp2f(s[n][2*jh + 1] - m);
            rs += p0 + p1;
            w[n][jh] = cvt_pk_bf16(p0, p1);
          }
        rs += __shfl_xor(rs, 16);
        rs += __shfl_xor(rs, 32);
        l += rs;
        const int srcA = l16 + ((g & 1) << 5);
        const int srcB = srcA + 16;
        const bool hi = (g >= 2);
        bf16x8 pa[2];
        #pragma unroll
        for (int ks2 = 0; ks2 < 2; ++ks2){
          unsigned a0 = __shfl((int)w[2*ks2][0],     srcA);
          unsigned b0 = __shfl((int)w[2*ks2 + 1][0], srcA);
          unsigned a1 = __shfl((int)w[2*ks2][1],     srcA);
          unsigned b1 = __shfl((int)w[2*ks2 + 1][1], srcA);
          unsigned a2 = __shfl((int)w[2*ks2][0],     srcB);
          unsigned b2 = __shfl((int)w[2*ks2 + 1][0], srcB);
          unsigned a3 = __shfl((int)w[2*ks2][1],     srcB);
          unsigned b3 = __shfl((int)w[2*ks2 + 1][1], srcB);
          union { unsigned u[4]; bf16x8 v; } pk;
          pk.u[0] = hi ? b0 : a0;
          pk.u[1] = hi ? b1 : a1;
          pk.u[2] = hi ? b2 : a2;
          pk.u[3] = hi ? b3 : a3;
          pa[ks2] = pk.v;
        }
        __builtin_amdgcn_s_setprio(1);
        #pragma unroll
        for (int ks2 = 0; ks2 < 2; ++ks2){
          int colsw = ((ks2 << 5) + lk) ^ sw8;
          #pragma unroll
          for (int db = 0; db < 8; ++db){
            bf16x8 vb = *reinterpret_cast<const bf16x8*>(&smem[(cur << 14) + 8192 + ((db << 4) + l16) * 64 + colsw]);
            o[db] = mfma16(pa[ks2], vb, o[db]);
          }
        }
        __builtin_amdgcn_s_setprio(0);
      }
      __syncthreads();                      // drains prefetch; reads done before buffer reuse
      cur ^= 1;
    }
    #pragma unroll
    for (int j = 0; j < 4; ++j){
      float lv = __shfl(l, r4 + j);
      float rinv = 1.f / lv;
      const int tq = qlo + r4 + j;
      u16* dst = aout + (bT + tq) * 2048 + (h << 7) + l16;
      #pragma unroll
      for (int db = 0; db < 8; ++db)
        dst[db << 4] = f2bf(o[db][j] * rinv);
    }
  }
}

extern "C" void kernel_launch(void* const* d_in, const int* in_sizes, int n_in,
                              void* d_out, int out_size, void* d_ws, size_t ws_size,
                              hipStream_t stream){
  const void* x       = d_in[0];
  const void* cosp    = d_in[1];
  const void* sinp    = d_in[2];
  const void* w_kv    = d_in[3];
  const void* w_kdec  = d_in[4];
  const void* w_vdec  = d_in[5];
  const void* w_qc    = d_in[6];
  const void* w_qdec  = d_in[7];
  const void* w_krope = d_in[8];
  const void* w_qrope = d_in[9];
  const void* w_o     = d_in[10];

  char* ws = (char*)d_ws;
  size_t off = 0;
  auto alloc = [&](size_t bytes){ void* p = ws + off; off += (bytes + 255) & ~(size_t)255; return p; };
  int* flag     = (int*)alloc(256);
  int* ticket   = (int*)alloc(1024);                         // 8 tickets, stride 16 ints
  u16* x_bf     = (u16*)alloc((size_t)NROWS * DIM_ * 2);
  u16* w_c1T    = (u16*)alloc((size_t)2304 * DIM_ * 2);      // [kvT(512); qcT(1536); kropeT(64); qropeT(64); pad(128)] x 2048
  u16* w_kvdT   = (u16*)alloc((size_t)3072 * DC_ * 2);       // [kdecPackedT(1024); vdecT(2048)] x 512
  u16* w_qdPT   = (u16*)alloc((size_t)1024 * DCQ_ * 2);      // packed qdecT (1024 x 1536)
  u16* w_oT     = (u16*)alloc((size_t)DIM_ * DIM_ * 2);
  u16* xc       = (u16*)alloc((size_t)NROWS * 2304 * 2);     // [c_kv(512) | c_q(1536) | ropes(128) | pad]
  u16* qP       = (u16*)alloc((size_t)NROWS * 1024 * 2);     // packed q decode (pre-scaled)
  u16* kvP      = (u16*)alloc((size_t)NROWS * 1024 * 2);     // packed K only (stride 1024)
  u16* krope    = (u16*)alloc((size_t)NROWS * 64 * 2);
  u16* qrope    = (u16*)alloc((size_t)NROWS * 64 * 2);       // pre-scaled
  u16* vT       = (u16*)alloc((size_t)32 * 128 * T_ * 2);    // [bh][d][t], written by G2 epilogue
  u16* aout     = (u16*)alloc((size_t)NROWS * DIM_ * 2);
  (void)in_sizes; (void)n_in; (void)out_size; (void)ws_size;

  const float SC2 = 0.12753139626374414f;   // 1/sqrt(128) * log2(e)

  hipLaunchKernelGGL(k_detect, dim3(1), dim3(128), 0, stream, (const u16*)cosp, flag, ticket);

  // merged x-convert + weight transposes (8192 conv blocks + 2880 transpose blocks)
  TPack tp;
  tp.d[0] = { w_kv,    w_c1T,                        512,  2048, 64,  8,  0    };
  tp.d[1] = { w_qc,    w_c1T + (size_t)512 * 2048,   1536, 2048, 64,  24, 256  };
  tp.d[2] = { w_krope, w_c1T + (size_t)2048 * 2048,  64,   2048, 64,  1,  1024 };
  tp.d[3] = { w_qrope, w_c1T + (size_t)2112 * 2048,  64,   2048, 64,  1,  1056 };
  tp.d[4] = { w_kdec,  w_kvdT,                       2048, 512,  128, 16, 1088 };
  tp.d[5] = { w_vdec,  w_kvdT + (size_t)1024 * 512,  2048, 512,  64,  32, 1216 };
  tp.d[6] = { w_qdec,  w_qdPT,                       2048, 1536, 128, 16, 1472 };
  tp.d[7] = { w_o,     w_oT,                         2048, 2048, 64,  32, 1856 };
  hipLaunchKernelGGL(k_prep, dim3(CONVBLK + 2880), dim3(256), 0, stream, x, x_bf, tp, flag);

  // G13: xc = x @ [w_kv | w_qc | rope-pre]  (4096 x 2176 used), grid (32,17) = 544 blocks
  // (pad N-tile dropped; 544%8==0 keeps XCD swizzle bijective); A straight from x when bf16
  hipLaunchKernelGGL(k_gemm, dim3(32, 17), dim3(256), 0, stream,
                     x_bf, DIM_, w_c1T, DIM_, xc, 2304, 1.0f,
                     x_bf, DIM_, w_c1T, DIM_, xc, 2304, 1.0f,
                     17, 1, (void*)nullptr, (const int*)flag,
                     (const u16*)x, (const u16*)x,
                     (u16*)nullptr, (u16*)nullptr);
  // G4 + G2 grouped on 128^2 tiles (1024 blocks; heavy K=1536 group first):
  //   nt<8:  qP = xc[:, 512:2048] @ w_qdecP  (4096 x 1024, K=1536), pre-scaled
  //   nt>=8: K -> kvP (stride 1024, cols<1024); V -> vT DIRECT TRANSPOSED (cols>=1024)
  hipLaunchKernelGGL(k_gemm, dim3(32, 32), dim3(256), 0, stream,
                     xc + 512, 2304, w_qdPT, DCQ_, qP, 1024, SC2,
                     xc, 2304, w_kvdT, DC_, kvP, 1024, 1.0f,
                     8, 0, (void*)nullptr, (const int*)nullptr,
                     (const u16*)nullptr, (const u16*)nullptr,
                     (u16*)nullptr, vT);
  // RoPE (2048 blocks)
  hipLaunchKernelGGL(k_rope, dim3(2048), dim3(256), 0, stream,
                     xc, cosp, sinp, flag, krope, qrope);
  // attention (256 workers x 8 waves, 128-row items, 2:1 stealing, XCD-partitioned tickets)
  hipLaunchKernelGGL(k_attn, dim3(256), dim3(512), 0, stream,
                     qP, kvP, vT, krope, qrope, aout, ticket);
  // G5: out = aout @ w_o  (4096 x 2048, K=2048) -> (32,16) = 512 blocks = 2/CU, XCD-chunked
  hipLaunchKernelGGL(k_gemm, dim3(32, 16), dim3(256), 0, stream,
                     aout, DIM_, w_oT, DIM_, (u16*)nullptr, DIM_, 1.0f,
                     aout, DIM_, w_oT, DIM_, (u16*)nullptr, DIM_, 1.0f,
                     16, 1, d_out, (const int*)flag,
                     (const u16*)nullptr, (const u16*)nullptr,
                     (u16*)nullptr, (u16*)nullptr);
}

// Round 22
// 237.346 us; speedup vs baseline: 1.0647x; 1.0472x over previous
//
#include <hip/hip_runtime.h>
#include <stdint.h>
#include <math.h>

#define B_    2
#define T_    2048
#define DIM_  2048
#define H_    16
#define DC_   512
#define DCQ_  1536
#define NROWS (B_*T_)   // 4096

typedef unsigned short u16;
typedef __attribute__((ext_vector_type(8))) __bf16 bf16x8;
typedef __attribute__((ext_vector_type(4))) float  f32x4;
typedef __attribute__((ext_vector_type(8))) unsigned short u16x8;
typedef __attribute__((ext_vector_type(4))) float  f4v;

__device__ __forceinline__ u16 f2bf(float f){
  unsigned u = __float_as_uint(f);
  u += 0x7FFFu + ((u >> 16) & 1u);   // RNE
  return (u16)(u >> 16);
}
__device__ __forceinline__ float bf2f(u16 h){ return __uint_as_float(((unsigned)h) << 16); }

__device__ __forceinline__ unsigned cvt_pk_bf16(float lo, float hi){
  unsigned r;
  asm("v_cvt_pk_bf16_f32 %0, %1, %2" : "=v"(r) : "v"(lo), "v"(hi));
  return r;
}

// async global->LDS, 16B per lane; LDS dest = wave-uniform base + lane*16.
__device__ __forceinline__ void gld_lds16(const void* g, void* l){
  auto gp = reinterpret_cast<__attribute__((address_space(1))) unsigned int*>(
      reinterpret_cast<uintptr_t>(g));
  auto lp = reinterpret_cast<__attribute__((address_space(3))) unsigned int*>(
      reinterpret_cast<uintptr_t>(l));
  __builtin_amdgcn_global_load_lds(gp, lp, 16, 0, 0);
}

__device__ __forceinline__ f32x4 mfma16(bf16x8 a, bf16x8 b, f32x4 c){
  return __builtin_amdgcn_mfma_f32_16x16x32_bf16(a, b, c, 0, 0, 0);
}

__device__ __forceinline__ void vmwait0(){ asm volatile("s_waitcnt vmcnt(0)" ::: "memory"); }
__device__ __forceinline__ void vmwait8(){ asm volatile("s_waitcnt vmcnt(8)" ::: "memory"); }
__device__ __forceinline__ void barr(){ asm volatile("s_barrier" ::: "memory"); }

// dtype flag: cos[0,0]==1.0 -> bf16 u16[0]=0x3F80, fp32 u16[0]=0x0000 (computed inline
// by each kernel from the cos table's first element; k_detect launch eliminated).

// ---------------- merged x-convert + 8 weight transposes (one launch)
struct TDesc { const void* src; u16* dst; int srcStride, dstStride, cblk, nbx, blk0; };
struct TPack { TDesc d[8]; };
#define CONVBLK 8192

__global__ void k_prep(const void* __restrict__ xsrc, u16* __restrict__ x_bf,
                       TPack p, const u16* __restrict__ cosr){
  __shared__ u16 tile[64][72];
  const int bid = blockIdx.x;
  const int tid = threadIdx.x;
  const int f = (cosr[0] == (u16)0x3F80u);
  if (bid < CONVBLK){
    if (f) return;                            // bf16 input: G13 reads x directly, skip copy
    int id = bid * 256 + tid;                 // n4 = 2097152 = 8192*256 exactly
    f4v v = reinterpret_cast<const f4v*>(xsrc)[id];
    unsigned lo = (unsigned)f2bf(v.x) | ((unsigned)f2bf(v.y) << 16);
    unsigned hi = (unsigned)f2bf(v.z) | ((unsigned)f2bf(v.w) << 16);
    reinterpret_cast<uint2*>(x_bf)[id] = make_uint2(lo, hi);
    return;
  }
  const int tb = bid - CONVBLK;
  int i = 0;
  #pragma unroll
  for (int k = 1; k < 8; ++k) if (tb >= p.d[k].blk0) i = k;
  const void* src = p.d[i].src;
  u16* dst = p.d[i].dst;
  const int srcStride = p.d[i].srcStride, dstStride = p.d[i].dstStride;
  const int rel = tb - p.d[i].blk0;
  const int bx = rel % p.d[i].nbx, by = rel / p.d[i].nbx;
  const int r0 = by << 6, c0 = bx * p.d[i].cblk;
  #pragma unroll
  for (int it = 0; it < 2; ++it){
    int task = (it << 8) + tid;
    int r = task >> 3, c8 = (task & 7) << 3;
    if (f){
      const u16* pp = (const u16*)src + (size_t)(r0 + r) * srcStride + c0 + c8;
      u16x8 v = *reinterpret_cast<const u16x8*>(pp);
      #pragma unroll
      for (int j = 0; j < 8; ++j) tile[r][c8 + j] = v[j];
    } else {
      const float* pp = (const float*)src + (size_t)(r0 + r) * srcStride + c0 + c8;
      f4v a = reinterpret_cast<const f4v*>(pp)[0];
      f4v b = reinterpret_cast<const f4v*>(pp)[1];
      tile[r][c8+0]=f2bf(a.x); tile[r][c8+1]=f2bf(a.y); tile[r][c8+2]=f2bf(a.z); tile[r][c8+3]=f2bf(a.w);
      tile[r][c8+4]=f2bf(b.x); tile[r][c8+5]=f2bf(b.y); tile[r][c8+6]=f2bf(b.z); tile[r][c8+7]=f2bf(b.w);
    }
  }
  __syncthreads();
  #pragma unroll
  for (int it = 0; it < 2; ++it){
    int task = (it << 8) + tid;
    int rr = task >> 3, cc8 = (task & 7) << 3;
    u16x8 v;
    #pragma unroll
    for (int j = 0; j < 8; ++j) v[j] = tile[cc8 + j][rr];
    *reinterpret_cast<u16x8*>(dst + (size_t)((bx << 6) + rr) * dstStride + r0 + cc8) = v;
  }
}

// ---------------- unified 128x128 GEMM: 256 thr / 4 waves (2x2), 64x64 per wave,
// LDS 64 KB -> 2 blocks/CU. Row-XOR swizzle via inverse-swizzled global_load_lds sources;
// counted vmcnt(8) pipeline; setprio around MFMA cluster. Two groups by N-tile index.
// alt-A: bf16 passthrough of unconverted input when input dtype is bf16 (cosr flag).
// vt: group output cols >= 1024 are V -> written TRANSPOSED to vT[bh][d][t].
__global__ __launch_bounds__(256, 2) void k_gemm(
    const u16* __restrict__ A0, int lda0, const u16* __restrict__ Bt0, int K0,
    u16* __restrict__ C0, int ldc0, float os0,
    const u16* __restrict__ A1, int lda1, const u16* __restrict__ Bt1, int K1,
    u16* __restrict__ C1, int ldc1, float os1,
    int ysplit, int swz, void* outp, const u16* __restrict__ cosr,
    const u16* __restrict__ alt0, const u16* __restrict__ alt1,
    u16* __restrict__ vt0, u16* __restrict__ vt1){
  __shared__ alignas(16) u16 lds[32768];   // 64 KB
  const int tid = threadIdx.x;
  const int wid = tid >> 6, lane = tid & 63;
  const int wr = wid >> 1, wc = wid & 1;
  const int l16 = lane & 15, g = lane >> 4;
  int lin = blockIdx.y * 32 + blockIdx.x;    // gridDim.x == 32 (M-tiles)
  if (swz){
    const int q8 = (gridDim.x * gridDim.y) >> 3;
    lin = (lin & 7) * q8 + (lin >> 3);       // bijective XCD chunking (nwg%8==0)
  }
  const int m0 = (lin & 31) << 7;
  int nt = lin >> 5;
  const u16 *A, *Bt, *alt; u16 *C, *vtp; int lda, K, ldc; float oscale;
  if (nt < ysplit){ A = A0; lda = lda0; Bt = Bt0; K = K0; C = C0; ldc = ldc0; oscale = os0; alt = alt0; vtp = vt0; }
  else { nt -= ysplit; A = A1; lda = lda1; Bt = Bt1; K = K1; C = C1; ldc = ldc1; oscale = os1; alt = alt1; vtp = vt1; }
  const int f = cosr ? (cosr[0] == (u16)0x3F80u) : 1;
  if (alt && f) A = alt;                     // bf16 input: read source directly
  const int n0 = nt << 7;
  const size_t Kz = (size_t)K;
  const int nkt = K >> 6;

  auto STAGE = [&](int kt, int bufn){
    const int kb = kt << 6;
    #pragma unroll
    for (int q = 0; q < 8; ++q){
      const int ht = q >> 2;                 // 0 = A half, 1 = B half
      const int cq = ((q & 3) << 8) + tid;   // chunk 0..1023 within half
      const int Lb = cq << 4;                // byte in [128][128B] half-tile
      const int row = Lb >> 7;
      const int colb = (Lb & 127) ^ ((row & 7) << 4);   // inverse-swizzled source
      const u16* src = ht ? (Bt + (size_t)(n0 + row) * Kz + kb + (colb >> 1))
                          : (A  + (size_t)(m0 + row) * lda + kb + (colb >> 1));
      gld_lds16(src, &lds[bufn * 16384 + ht * 8192 + (cq << 3)]);
    }
  };

  f32x4 acc[4][4] = {};

  STAGE(0, 0);
  int buf = 0;

  for (int kt = 0; kt < nkt; ++kt){
    if (kt + 1 < nkt){ STAGE(kt + 1, buf ^ 1); vmwait8(); }   // waits tile-kt's 8 loads
    else vmwait0();
    barr();                                                    // staged tile visible to all
    bf16x8 af[2][4], bfr[2][4];
    #pragma unroll
    for (int ks = 0; ks < 2; ++ks){
      #pragma unroll
      for (int mi = 0; mi < 4; ++mi){
        int row = (wr << 6) + (mi << 4) + l16;
        int cb = ((ks << 6) + (g << 4)) ^ ((row & 7) << 4);
        af[ks][mi] = *reinterpret_cast<const bf16x8*>(&lds[buf * 16384 + (((row << 7) + cb) >> 1)]);
      }
      #pragma unroll
      for (int ni = 0; ni < 4; ++ni){
        int row = (wc << 6) + (ni << 4) + l16;
        int cb = ((ks << 6) + (g << 4)) ^ ((row & 7) << 4);
        bfr[ks][ni] = *reinterpret_cast<const bf16x8*>(&lds[buf * 16384 + 8192 + (((row << 7) + cb) >> 1)]);
      }
    }
    __builtin_amdgcn_s_setprio(1);
    #pragma unroll
    for (int ks = 0; ks < 2; ++ks)
      #pragma unroll
      for (int mi = 0; mi < 4; ++mi)
        #pragma unroll
        for (int ni = 0; ni < 4; ++ni)
          acc[mi][ni] = mfma16(af[ks][mi], bfr[ks][ni], acc[mi][ni]);
    __builtin_amdgcn_s_setprio(0);
    barr();                                  // reads done before next STAGE overwrites
    buf ^= 1;
  }

  const int r4 = g << 2;
  #pragma unroll
  for (int mi = 0; mi < 4; ++mi){
    int row = m0 + (wr << 6) + (mi << 4) + r4;
    #pragma unroll
    for (int ni = 0; ni < 4; ++ni){
      int col = n0 + (wc << 6) + (ni << 4) + l16;
      if (vtp && col >= 1024){
        // V quadrant: write transposed to vT[bh][d][t]; rows j are consecutive t.
        int hd = col - 1024;
        u16* dst = vtp + (((size_t)(((row >> 11) << 4) + (hd >> 7)) << 7) + (hd & 127)) * (size_t)T_ + (row & (T_ - 1));
        union { u16 u[4]; uint2 v; } pk;
        #pragma unroll
        for (int j = 0; j < 4; ++j) pk.u[j] = f2bf(acc[mi][ni][j] * oscale);
        *reinterpret_cast<uint2*>(dst) = pk.v;
        continue;
      }
      #pragma unroll
      for (int j = 0; j < 4; ++j){
        float v = acc[mi][ni][j] * oscale;
        if (outp){
          if (f) ((u16*)outp)[(size_t)(row + j) * ldc + col] = f2bf(v);
          else   ((float*)outp)[(size_t)(row + j) * ldc + col] = v;
        } else {
          C[(size_t)(row + j) * ldc + col] = f2bf(v);
        }
      }
    }
  }
}

// ---------------- RoPE (2048 blocks; reads xc cols 2048..2175, stride 2304).
// Block 0 also resets the 8 XCD tickets (stream-ordered before k_attn; replay-safe).
__global__ void k_rope(const u16* __restrict__ xc, const void* __restrict__ cosp,
                       const void* __restrict__ sinp,
                       u16* __restrict__ krope, u16* __restrict__ qrope,
                       int* __restrict__ ticket){
  if (blockIdx.x == 0 && threadIdx.x < 128) ticket[threadIdx.x] = 0;
  const int f = (((const u16*)cosp)[0] == (u16)0x3F80u);
  int id = blockIdx.x * 256 + threadIdx.x;   // exactly NROWS*128
  int row = id >> 7, c = id & 127;
  int t = row & (T_ - 1);
  int d = c & 63, i = d & 31;
  float cs, sn;
  if (f){ cs = bf2f(((const u16*)cosp)[t * 32 + i]); sn = bf2f(((const u16*)sinp)[t * 32 + i]); }
  else  { cs = ((const float*)cosp)[t * 32 + i];     sn = ((const float*)sinp)[t * 32 + i]; }
  int base = c & 64;
  float t1 = bf2f(xc[(size_t)row * 2304 + 2048 + base + i]);
  float t2 = bf2f(xc[(size_t)row * 2304 + 2048 + base + 32 + i]);
  float v = (d < 32) ? (t1 * cs - t2 * sn) : (t2 * cs + t1 * sn);
  if (c >= 64) v *= 0.12753139626374414f;   // 1/sqrt(128)*log2(e) folded into q
  ((c < 64) ? krope : qrope)[(size_t)row * 64 + d] = f2bf(v);
}

// ---------------- causal flash attention: 128-row items, 8 waves x 16 rows (512 thr).
// Round-17 config (measured best): 256 workers (1 block/CU), per-XCD tickets,
// 64 items over 32 workers/partition = 2:1 heavy-first STEALING (1:1 maps regress --
// rounds 12 & 18). 64KB LDS double-buffer; setprio around MFMA clusters.
__global__ __launch_bounds__(512, 2) void k_attn(const u16* __restrict__ qP,
                                                 const u16* __restrict__ kvP,
                                                 const u16* __restrict__ vT,
                                                 const u16* __restrict__ krope,
                                                 const u16* __restrict__ qrope,
                                                 u16* __restrict__ aout,
                                                 int* __restrict__ ticket){
  __shared__ alignas(16) u16 smem[32768];   // 64 KB: 2 buffers x (K [64][128] + V [128][64])
  const int tid = threadIdx.x, wid = tid >> 6, lane = tid & 63;
  const int l16 = lane & 15, g = lane >> 4;
  const int lk = g << 3, r4 = g << 2;
  const int sw8 = (l16 & 7) << 3;
  const int xcd = blockIdx.x & 7;

  while (true){
    if (tid == 0) *(int*)&smem[0] = atomicAdd(&ticket[xcd << 4], 1);
    __syncthreads();
    const int it = *(const int*)&smem[0];
    __syncthreads();
    if (it >= 64) break;
    const int qt = 15 - (it >> 2);          // heavy-first within partition (128-row tiles)
    const int bh = (xcd << 2) + (it & 3), b = bh >> 4, h = bh & 15;
    const int q0 = qt << 7;
    const size_t bT = (size_t)b * T_;
    const u16* kvPb = kvP + bT * 1024 + (h << 6);
    const u16* krb  = krope + bT * 64;
    const u16* vTb  = vT + (size_t)bh * 128 * T_;
    const int qlo = q0 + (wid << 4);
    const int qhi = qlo + 15;
    const int nkv = (qt << 1) + 2;

    auto STAGE = [&](int buf, int k0){
      const int base = buf << 14;
      #pragma unroll
      for (int r = 0; r < 4; ++r){
        int c = (r << 9) + tid;              // 0..2047 chunks of 16B
        const u16* src;
        if (r < 2){
          int row = c >> 4, cc = c & 15;
          int ccx = (cc & 8) | ((cc & 7) ^ (row & 7));
          int col0 = ccx << 3;
          src = (col0 < 64) ? (kvPb + (size_t)(k0 + row) * 1024 + col0)
                            : (krb  + (size_t)(k0 + row) * 64 + (col0 - 64));
        } else {
          int cv = c - 1024;
          int row = cv >> 3, cc = cv & 7;
          int ccx = cc ^ (row & 7);
          src = vTb + (size_t)row * T_ + k0 + (ccx << 3);
        }
        gld_lds16(src, &smem[base + (c << 3)]);
      }
    };

    bf16x8 qf[4];
    {
      size_t grow = bT + qlo + l16;
      #pragma unroll
      for (int ks = 0; ks < 4; ++ks){
        int d = (ks << 5) + lk;
        const u16* src = (ks < 2) ? (qP + grow * 1024 + (h << 6) + d)
                                  : (qrope + grow * 64 + (d - 64));
        qf[ks] = *reinterpret_cast<const bf16x8*>(src);
      }
    }
    f32x4 o[8] = {};
    float m = -3e38f, l = 0.f;

    STAGE(0, 0);
    __syncthreads();
    int cur = 0;

    for (int kv = 0; kv < nkv; ++kv){
      const int k0 = kv << 6;
      if (kv + 1 < nkv) STAGE(cur ^ 1, (kv + 1) << 6);
      if (k0 <= qhi){
        const int kb = cur << 14;
        f32x4 s[4] = {};
        __builtin_amdgcn_s_setprio(1);
        #pragma unroll
        for (int ks = 0; ks < 4; ++ks){
          int colsw = ((ks << 5) + lk) ^ sw8;
          #pragma unroll
          for (int n = 0; n < 4; ++n){
            bf16x8 kf = *reinterpret_cast<const bf16x8*>(&smem[kb + ((n << 4) + l16) * 128 + colsw]);
            s[n] = mfma16(kf, qf[ks], s[n]);
          }
        }
        __builtin_amdgcn_s_setprio(0);
        if (k0 + 63 > qlo){                  // only the wave's diagonal tile needs masking
          const int tq = qlo + l16;
          #pragma unroll
          for (int n = 0; n < 4; ++n)
            #pragma unroll
            for (int j = 0; j < 4; ++j)
              s[n][j] = (k0 + (n << 4) + r4 + j <= tq) ? s[n][j] : -3e38f;
        }
        float mx;
        {
          float a0 = fmaxf(fmaxf(s[0][0], s[0][1]), fmaxf(s[0][2], s[0][3]));
          float a1 = fmaxf(fmaxf(s[1][0], s[1][1]), fmaxf(s[1][2], s[1][3]));
          float a2 = fmaxf(fmaxf(s[2][0], s[2][1]), fmaxf(s[2][2], s[2][3]));
          float a3 = fmaxf(fmaxf(s[3][0], s[3][1]), fmaxf(s[3][2], s[3][3]));
          mx = fmaxf(fmaxf(a0, a1), fmaxf(a2, a3));
          mx = fmaxf(mx, __shfl_xor(mx, 16));
          mx = fmaxf(mx, __shfl_xor(mx, 32));
        }
        if (__ballot(mx > m + 8.f)){
          float mnew = fmaxf(m, mx);
          float alpha = exp2f(m - mnew);
          m = mnew; l *= alpha;
          #pragma unroll
          for (int j = 0; j < 4; ++j){
            float av = __shfl(alpha, r4 + j);
            #pragma unroll
            for (int db = 0; db < 8; ++db) o[db][j] *= av;
          }
        }
        unsigned w[4][2];
        float rs = 0.f;
        #pragma unroll
        for (int n = 0; n < 4; ++n)
          #pragma unroll
          for (int jh = 0; jh < 2; ++jh){
            float p0 = exp2f(s[n][2*jh]     - m);
            float p1 = exp2f(s[n][2*jh + 1] - m);
            rs += p0 + p1;
            w[n][jh] = cvt_pk_bf16(p0, p1);
          }
        rs += __shfl_xor(rs, 16);
        rs += __shfl_xor(rs, 32);
        l += rs;
        const int srcA = l16 + ((g & 1) << 5);
        const int srcB = srcA + 16;
        const bool hi = (g >= 2);
        bf16x8 pa[2];
        #pragma unroll
        for (int ks2 = 0; ks2 < 2; ++ks2){
          unsigned a0 = __shfl((int)w[2*ks2][0],     srcA);
          unsigned b0 = __shfl((int)w[2*ks2 + 1][0], srcA);
          unsigned a1 = __shfl((int)w[2*ks2][1],     srcA);
          unsigned b1 = __shfl((int)w[2*ks2 + 1][1], srcA);
          unsigned a2 = __shfl((int)w[2*ks2][0],     srcB);
          unsigned b2 = __shfl((int)w[2*ks2 + 1][0], srcB);
          unsigned a3 = __shfl((int)w[2*ks2][1],     srcB);
          unsigned b3 = __shfl((int)w[2*ks2 + 1][1], srcB);
          union { unsigned u[4]; bf16x8 v; } pk;
          pk.u[0] = hi ? b0 : a0;
          pk.u[1] = hi ? b1 : a1;
          pk.u[2] = hi ? b2 : a2;
          pk.u[3] = hi ? b3 : a3;
          pa[ks2] = pk.v;
        }
        __builtin_amdgcn_s_setprio(1);
        #pragma unroll
        for (int ks2 = 0; ks2 < 2; ++ks2){
          int colsw = ((ks2 << 5) + lk) ^ sw8;
          #pragma unroll
          for (int db = 0; db < 8; ++db){
            bf16x8 vb = *reinterpret_cast<const bf16x8*>(&smem[(cur << 14) + 8192 + ((db << 4) + l16) * 64 + colsw]);
            o[db] = mfma16(pa[ks2], vb, o[db]);
          }
        }
        __builtin_amdgcn_s_setprio(0);
      }
      __syncthreads();                      // drains prefetch; reads done before buffer reuse
      cur ^= 1;
    }
    #pragma unroll
    for (int j = 0; j < 4; ++j){
      float lv = __shfl(l, r4 + j);
      float rinv = 1.f / lv;
      const int tq = qlo + r4 + j;
      u16* dst = aout + (bT + tq) * 2048 + (h << 7) + l16;
      #pragma unroll
      for (int db = 0; db < 8; ++db)
        dst[db << 4] = f2bf(o[db][j] * rinv);
    }
  }
}

extern "C" void kernel_launch(void* const* d_in, const int* in_sizes, int n_in,
                              void* d_out, int out_size, void* d_ws, size_t ws_size,
                              hipStream_t stream){
  const void* x       = d_in[0];
  const void* cosp    = d_in[1];
  const void* sinp    = d_in[2];
  const void* w_kv    = d_in[3];
  const void* w_kdec  = d_in[4];
  const void* w_vdec  = d_in[5];
  const void* w_qc    = d_in[6];
  const void* w_qdec  = d_in[7];
  const void* w_krope = d_in[8];
  const void* w_qrope = d_in[9];
  const void* w_o     = d_in[10];

  char* ws = (char*)d_ws;
  size_t off = 0;
  auto alloc = [&](size_t bytes){ void* p = ws + off; off += (bytes + 255) & ~(size_t)255; return p; };
  int* ticket   = (int*)alloc(1024);                         // 8 tickets, stride 16 ints
  u16* x_bf     = (u16*)alloc((size_t)NROWS * DIM_ * 2);
  u16* w_c1T    = (u16*)alloc((size_t)2304 * DIM_ * 2);      // [kvT(512); qcT(1536); kropeT(64); qropeT(64); pad(128)] x 2048
  u16* w_kvdT   = (u16*)alloc((size_t)3072 * DC_ * 2);       // [kdecPackedT(1024); vdecT(2048)] x 512
  u16* w_qdPT   = (u16*)alloc((size_t)1024 * DCQ_ * 2);      // packed qdecT (1024 x 1536)
  u16* w_oT     = (u16*)alloc((size_t)DIM_ * DIM_ * 2);
  u16* xc       = (u16*)alloc((size_t)NROWS * 2304 * 2);     // [c_kv(512) | c_q(1536) | ropes(128) | pad]
  u16* qP       = (u16*)alloc((size_t)NROWS * 1024 * 2);     // packed q decode (pre-scaled)
  u16* kvP      = (u16*)alloc((size_t)NROWS * 1024 * 2);     // packed K only (stride 1024)
  u16* krope    = (u16*)alloc((size_t)NROWS * 64 * 2);
  u16* qrope    = (u16*)alloc((size_t)NROWS * 64 * 2);       // pre-scaled
  u16* vT       = (u16*)alloc((size_t)32 * 128 * T_ * 2);    // [bh][d][t], written by G2 epilogue
  u16* aout     = (u16*)alloc((size_t)NROWS * DIM_ * 2);
  (void)in_sizes; (void)n_in; (void)out_size; (void)ws_size;

  const float SC2 = 0.12753139626374414f;   // 1/sqrt(128) * log2(e)
  const u16* cosr = (const u16*)cosp;

  // merged x-convert + weight transposes (8192 conv blocks + 2880 transpose blocks)
  TPack tp;
  tp.d[0] = { w_kv,    w_c1T,                        512,  2048, 64,  8,  0    };
  tp.d[1] = { w_qc,    w_c1T + (size_t)512 * 2048,   1536, 2048, 64,  24, 256  };
  tp.d[2] = { w_krope, w_c1T + (size_t)2048 * 2048,  64,   2048, 64,  1,  1024 };
  tp.d[3] = { w_qrope, w_c1T + (size_t)2112 * 2048,  64,   2048, 64,  1,  1056 };
  tp.d[4] = { w_kdec,  w_kvdT,                       2048, 512,  128, 16, 1088 };
  tp.d[5] = { w_vdec,  w_kvdT + (size_t)1024 * 512,  2048, 512,  64,  32, 1216 };
  tp.d[6] = { w_qdec,  w_qdPT,                       2048, 1536, 128, 16, 1472 };
  tp.d[7] = { w_o,     w_oT,                         2048, 2048, 64,  32, 1856 };
  hipLaunchKernelGGL(k_prep, dim3(CONVBLK + 2880), dim3(256), 0, stream, x, x_bf, tp, cosr);

  // G13: xc = x @ [w_kv | w_qc | rope-pre]  (4096 x 2176 used), grid (32,17) = 544 blocks
  // (pad N-tile dropped; 544%8==0 keeps XCD swizzle bijective); A straight from x when bf16
  hipLaunchKernelGGL(k_gemm, dim3(32, 17), dim3(256), 0, stream,
                     x_bf, DIM_, w_c1T, DIM_, xc, 2304, 1.0f,
                     x_bf, DIM_, w_c1T, DIM_, xc, 2304, 1.0f,
                     17, 1, (void*)nullptr, cosr,
                     (const u16*)x, (const u16*)x,
                     (u16*)nullptr, (u16*)nullptr);
  // G4 + G2 grouped on 128^2 tiles (1024 blocks; heavy K=1536 group first):
  //   nt<8:  qP = xc[:, 512:2048] @ w_qdecP  (4096 x 1024, K=1536), pre-scaled
  //   nt>=8: K -> kvP (stride 1024, cols<1024); V -> vT DIRECT TRANSPOSED (cols>=1024)
  hipLaunchKernelGGL(k_gemm, dim3(32, 32), dim3(256), 0, stream,
                     xc + 512, 2304, w_qdPT, DCQ_, qP, 1024, SC2,
                     xc, 2304, w_kvdT, DC_, kvP, 1024, 1.0f,
                     8, 0, (void*)nullptr, (const u16*)nullptr,
                     (const u16*)nullptr, (const u16*)nullptr,
                     (u16*)nullptr, vT);
  // RoPE (2048 blocks; block 0 resets the XCD tickets ahead of k_attn)
  hipLaunchKernelGGL(k_rope, dim3(2048), dim3(256), 0, stream,
                     xc, cosp, sinp, krope, qrope, ticket);
  // attention (256 workers x 8 waves, 128-row items, 2:1 stealing, XCD-partitioned tickets)
  hipLaunchKernelGGL(k_attn, dim3(256), dim3(512), 0, stream,
                     qP, kvP, vT, krope, qrope, aout, ticket);
  // G5: out = aout @ w_o  (4096 x 2048, K=2048) -> (32,16) = 512 blocks = 2/CU, XCD-chunked
  hipLaunchKernelGGL(k_gemm, dim3(32, 16), dim3(256), 0, stream,
                     aout, DIM_, w_oT, DIM_, (u16*)nullptr, DIM_, 1.0f,
                     aout, DIM_, w_oT, DIM_, (u16*)nullptr, DIM_, 1.0f,
                     16, 1, d_out, cosr,
                     (const u16*)nullptr, (const u16*)nullptr,
                     (u16*)nullptr, (u16*)nullptr);
}

// Round 23
// 236.167 us; speedup vs baseline: 1.0701x; 1.0050x over previous
//
#include <hip/hip_runtime.h>
#include <stdint.h>
#include <math.h>

#define B_    2
#define T_    2048
#define DIM_  2048
#define H_    16
#define DC_   512
#define DCQ_  1536
#define NROWS (B_*T_)   // 4096

typedef unsigned short u16;
typedef __attribute__((ext_vector_type(8))) __bf16 bf16x8;
typedef __attribute__((ext_vector_type(4))) float  f32x4;
typedef __attribute__((ext_vector_type(8))) unsigned short u16x8;
typedef __attribute__((ext_vector_type(4))) float  f4v;

__device__ __forceinline__ u16 f2bf(float f){
  unsigned u = __float_as_uint(f);
  u += 0x7FFFu + ((u >> 16) & 1u);   // RNE
  return (u16)(u >> 16);
}
__device__ __forceinline__ float bf2f(u16 h){ return __uint_as_float(((unsigned)h) << 16); }

__device__ __forceinline__ unsigned cvt_pk_bf16(float lo, float hi){
  unsigned r;
  asm("v_cvt_pk_bf16_f32 %0, %1, %2" : "=v"(r) : "v"(lo), "v"(hi));
  return r;
}

// async global->LDS, 16B per lane; LDS dest = wave-uniform base + lane*16.
__device__ __forceinline__ void gld_lds16(const void* g, void* l){
  auto gp = reinterpret_cast<__attribute__((address_space(1))) unsigned int*>(
      reinterpret_cast<uintptr_t>(g));
  auto lp = reinterpret_cast<__attribute__((address_space(3))) unsigned int*>(
      reinterpret_cast<uintptr_t>(l));
  __builtin_amdgcn_global_load_lds(gp, lp, 16, 0, 0);
}

__device__ __forceinline__ f32x4 mfma16(bf16x8 a, bf16x8 b, f32x4 c){
  return __builtin_amdgcn_mfma_f32_16x16x32_bf16(a, b, c, 0, 0, 0);
}

__device__ __forceinline__ void vmwait0(){ asm volatile("s_waitcnt vmcnt(0)" ::: "memory"); }
__device__ __forceinline__ void vmwait8(){ asm volatile("s_waitcnt vmcnt(8)" ::: "memory"); }
__device__ __forceinline__ void barr(){ asm volatile("s_barrier" ::: "memory"); }

// dtype flag: cos[0,0]==1.0 -> bf16 u16[0]=0x3F80, fp32 u16[0]=0x0000 (computed inline
// by each kernel from the cos table's first element).

// ---------------- merged x-convert + 8 weight transposes (one launch)
struct TDesc { const void* src; u16* dst; int srcStride, dstStride, cblk, nbx, blk0; };
struct TPack { TDesc d[8]; };
#define CONVBLK 8192

__global__ void k_prep(const void* __restrict__ xsrc, u16* __restrict__ x_bf,
                       TPack p, const u16* __restrict__ cosr){
  __shared__ u16 tile[64][72];
  const int bid = blockIdx.x;
  const int tid = threadIdx.x;
  const int f = (cosr[0] == (u16)0x3F80u);
  if (bid < CONVBLK){
    if (f) return;                            // bf16 input: G13 reads x directly, skip copy
    int id = bid * 256 + tid;                 // n4 = 2097152 = 8192*256 exactly
    f4v v = reinterpret_cast<const f4v*>(xsrc)[id];
    unsigned lo = (unsigned)f2bf(v.x) | ((unsigned)f2bf(v.y) << 16);
    unsigned hi = (unsigned)f2bf(v.z) | ((unsigned)f2bf(v.w) << 16);
    reinterpret_cast<uint2*>(x_bf)[id] = make_uint2(lo, hi);
    return;
  }
  const int tb = bid - CONVBLK;
  int i = 0;
  #pragma unroll
  for (int k = 1; k < 8; ++k) if (tb >= p.d[k].blk0) i = k;
  const void* src = p.d[i].src;
  u16* dst = p.d[i].dst;
  const int srcStride = p.d[i].srcStride, dstStride = p.d[i].dstStride;
  const int rel = tb - p.d[i].blk0;
  const int bx = rel % p.d[i].nbx, by = rel / p.d[i].nbx;
  const int r0 = by << 6, c0 = bx * p.d[i].cblk;
  #pragma unroll
  for (int it = 0; it < 2; ++it){
    int task = (it << 8) + tid;
    int r = task >> 3, c8 = (task & 7) << 3;
    if (f){
      const u16* pp = (const u16*)src + (size_t)(r0 + r) * srcStride + c0 + c8;
      u16x8 v = *reinterpret_cast<const u16x8*>(pp);
      #pragma unroll
      for (int j = 0; j < 8; ++j) tile[r][c8 + j] = v[j];
    } else {
      const float* pp = (const float*)src + (size_t)(r0 + r) * srcStride + c0 + c8;
      f4v a = reinterpret_cast<const f4v*>(pp)[0];
      f4v b = reinterpret_cast<const f4v*>(pp)[1];
      tile[r][c8+0]=f2bf(a.x); tile[r][c8+1]=f2bf(a.y); tile[r][c8+2]=f2bf(a.z); tile[r][c8+3]=f2bf(a.w);
      tile[r][c8+4]=f2bf(b.x); tile[r][c8+5]=f2bf(b.y); tile[r][c8+6]=f2bf(b.z); tile[r][c8+7]=f2bf(b.w);
    }
  }
  __syncthreads();
  #pragma unroll
  for (int it = 0; it < 2; ++it){
    int task = (it << 8) + tid;
    int rr = task >> 3, cc8 = (task & 7) << 3;
    u16x8 v;
    #pragma unroll
    for (int j = 0; j < 8; ++j) v[j] = tile[cc8 + j][rr];
    *reinterpret_cast<u16x8*>(dst + (size_t)((bx << 6) + rr) * dstStride + r0 + cc8) = v;
  }
}

// ---------------- unified 128x128 GEMM: 256 thr / 4 waves (2x2), 64x64 per wave,
// LDS 64 KB -> 2 blocks/CU. Row-XOR swizzle via inverse-swizzled global_load_lds sources;
// counted vmcnt(8) pipeline; setprio around MFMA cluster. Two groups by N-tile index.
// alt-A: bf16 passthrough of unconverted input when input dtype is bf16 (cosr flag).
// vt: group output cols >= 1024 are V -> written TRANSPOSED to vT[bh][d][t].
// ropeXc: when set, blocks with flat id >= ngemm run the RoPE elementwise path instead
// (depends only on G13's xc -> legal in the same launch as G2G4; removes one launch;
// first rope block also resets the XCD tickets ahead of k_attn).
__global__ __launch_bounds__(256, 2) void k_gemm(
    const u16* __restrict__ A0, int lda0, const u16* __restrict__ Bt0, int K0,
    u16* __restrict__ C0, int ldc0, float os0,
    const u16* __restrict__ A1, int lda1, const u16* __restrict__ Bt1, int K1,
    u16* __restrict__ C1, int ldc1, float os1,
    int ysplit, int swz, void* outp, const u16* __restrict__ cosr,
    const u16* __restrict__ alt0, const u16* __restrict__ alt1,
    u16* __restrict__ vt0, u16* __restrict__ vt1,
    const u16* __restrict__ ropeXc, const void* __restrict__ rcosp,
    const void* __restrict__ rsinp, u16* __restrict__ ropeK,
    u16* __restrict__ ropeQ, int* __restrict__ rticket, int ngemm){
  __shared__ alignas(16) u16 lds[32768];   // 64 KB
  const int tid = threadIdx.x;
  const int flat = blockIdx.y * gridDim.x + blockIdx.x;

  if (ropeXc && flat >= ngemm){
    // ---- RoPE path (2048 trailing blocks; reads xc cols 2048..2175, stride 2304)
    const int rb = flat - ngemm;
    if (rb == 0 && tid < 128) rticket[tid] = 0;    // ticket reset ahead of k_attn
    const int f2 = (((const u16*)rcosp)[0] == (u16)0x3F80u);
    int id = rb * 256 + tid;                       // exactly NROWS*128
    int row = id >> 7, c = id & 127;
    int t = row & (T_ - 1);
    int d = c & 63, i = d & 31;
    float cs, sn;
    if (f2){ cs = bf2f(((const u16*)rcosp)[t * 32 + i]); sn = bf2f(((const u16*)rsinp)[t * 32 + i]); }
    else   { cs = ((const float*)rcosp)[t * 32 + i];     sn = ((const float*)rsinp)[t * 32 + i]; }
    int base = c & 64;
    float t1 = bf2f(ropeXc[(size_t)row * 2304 + 2048 + base + i]);
    float t2 = bf2f(ropeXc[(size_t)row * 2304 + 2048 + base + 32 + i]);
    float v = (d < 32) ? (t1 * cs - t2 * sn) : (t2 * cs + t1 * sn);
    if (c >= 64) v *= 0.12753139626374414f;        // 1/sqrt(128)*log2(e) folded into q
    ((c < 64) ? ropeK : ropeQ)[(size_t)row * 64 + d] = f2bf(v);
    return;
  }

  const int wid = tid >> 6, lane = tid & 63;
  const int wr = wid >> 1, wc = wid & 1;
  const int l16 = lane & 15, g = lane >> 4;
  int lin = flat;
  if (swz){
    const int q8 = (gridDim.x * gridDim.y) >> 3;
    lin = (lin & 7) * q8 + (lin >> 3);       // bijective XCD chunking (nwg%8==0)
  }
  const int m0 = (lin & 31) << 7;
  int nt = lin >> 5;
  const u16 *A, *Bt, *alt; u16 *C, *vtp; int lda, K, ldc; float oscale;
  if (nt < ysplit){ A = A0; lda = lda0; Bt = Bt0; K = K0; C = C0; ldc = ldc0; oscale = os0; alt = alt0; vtp = vt0; }
  else { nt -= ysplit; A = A1; lda = lda1; Bt = Bt1; K = K1; C = C1; ldc = ldc1; oscale = os1; alt = alt1; vtp = vt1; }
  const int f = cosr ? (cosr[0] == (u16)0x3F80u) : 1;
  if (alt && f) A = alt;                     // bf16 input: read source directly
  const int n0 = nt << 7;
  const size_t Kz = (size_t)K;
  const int nkt = K >> 6;

  auto STAGE = [&](int kt, int bufn){
    const int kb = kt << 6;
    #pragma unroll
    for (int q = 0; q < 8; ++q){
      const int ht = q >> 2;                 // 0 = A half, 1 = B half
      const int cq = ((q & 3) << 8) + tid;   // chunk 0..1023 within half
      const int Lb = cq << 4;                // byte in [128][128B] half-tile
      const int row = Lb >> 7;
      const int colb = (Lb & 127) ^ ((row & 7) << 4);   // inverse-swizzled source
      const u16* src = ht ? (Bt + (size_t)(n0 + row) * Kz + kb + (colb >> 1))
                          : (A  + (size_t)(m0 + row) * lda + kb + (colb >> 1));
      gld_lds16(src, &lds[bufn * 16384 + ht * 8192 + (cq << 3)]);
    }
  };

  f32x4 acc[4][4] = {};

  STAGE(0, 0);
  int buf = 0;

  for (int kt = 0; kt < nkt; ++kt){
    if (kt + 1 < nkt){ STAGE(kt + 1, buf ^ 1); vmwait8(); }   // waits tile-kt's 8 loads
    else vmwait0();
    barr();                                                    // staged tile visible to all
    bf16x8 af[2][4], bfr[2][4];
    #pragma unroll
    for (int ks = 0; ks < 2; ++ks){
      #pragma unroll
      for (int mi = 0; mi < 4; ++mi){
        int row = (wr << 6) + (mi << 4) + l16;
        int cb = ((ks << 6) + (g << 4)) ^ ((row & 7) << 4);
        af[ks][mi] = *reinterpret_cast<const bf16x8*>(&lds[buf * 16384 + (((row << 7) + cb) >> 1)]);
      }
      #pragma unroll
      for (int ni = 0; ni < 4; ++ni){
        int row = (wc << 6) + (ni << 4) + l16;
        int cb = ((ks << 6) + (g << 4)) ^ ((row & 7) << 4);
        bfr[ks][ni] = *reinterpret_cast<const bf16x8*>(&lds[buf * 16384 + 8192 + (((row << 7) + cb) >> 1)]);
      }
    }
    __builtin_amdgcn_s_setprio(1);
    #pragma unroll
    for (int ks = 0; ks < 2; ++ks)
      #pragma unroll
      for (int mi = 0; mi < 4; ++mi)
        #pragma unroll
        for (int ni = 0; ni < 4; ++ni)
          acc[mi][ni] = mfma16(af[ks][mi], bfr[ks][ni], acc[mi][ni]);
    __builtin_amdgcn_s_setprio(0);
    barr();                                  // reads done before next STAGE overwrites
    buf ^= 1;
  }

  const int r4 = g << 2;
  #pragma unroll
  for (int mi = 0; mi < 4; ++mi){
    int row = m0 + (wr << 6) + (mi << 4) + r4;
    #pragma unroll
    for (int ni = 0; ni < 4; ++ni){
      int col = n0 + (wc << 6) + (ni << 4) + l16;
      if (vtp && col >= 1024){
        // V quadrant: write transposed to vT[bh][d][t]; rows j are consecutive t.
        int hd = col - 1024;
        u16* dst = vtp + (((size_t)(((row >> 11) << 4) + (hd >> 7)) << 7) + (hd & 127)) * (size_t)T_ + (row & (T_ - 1));
        union { u16 u[4]; uint2 v; } pk;
        #pragma unroll
        for (int j = 0; j < 4; ++j) pk.u[j] = f2bf(acc[mi][ni][j] * oscale);
        *reinterpret_cast<uint2*>(dst) = pk.v;
        continue;
      }
      #pragma unroll
      for (int j = 0; j < 4; ++j){
        float v = acc[mi][ni][j] * oscale;
        if (outp){
          if (f) ((u16*)outp)[(size_t)(row + j) * ldc + col] = f2bf(v);
          else   ((float*)outp)[(size_t)(row + j) * ldc + col] = v;
        } else {
          C[(size_t)(row + j) * ldc + col] = f2bf(v);
        }
      }
    }
  }
}

// ---------------- causal flash attention: 128-row items, 8 waves x 16 rows (512 thr).
// Round-17 config (measured best): 256 workers (1 block/CU), per-XCD tickets,
// 64 items over 32 workers/partition = 2:1 heavy-first STEALING (1:1 maps regress --
// rounds 12 & 18). 64KB LDS double-buffer; setprio around MFMA clusters.
__global__ __launch_bounds__(512, 2) void k_attn(const u16* __restrict__ qP,
                                                 const u16* __restrict__ kvP,
                                                 const u16* __restrict__ vT,
                                                 const u16* __restrict__ krope,
                                                 const u16* __restrict__ qrope,
                                                 u16* __restrict__ aout,
                                                 int* __restrict__ ticket){
  __shared__ alignas(16) u16 smem[32768];   // 64 KB: 2 buffers x (K [64][128] + V [128][64])
  const int tid = threadIdx.x, wid = tid >> 6, lane = tid & 63;
  const int l16 = lane & 15, g = lane >> 4;
  const int lk = g << 3, r4 = g << 2;
  const int sw8 = (l16 & 7) << 3;
  const int xcd = blockIdx.x & 7;

  while (true){
    if (tid == 0) *(int*)&smem[0] = atomicAdd(&ticket[xcd << 4], 1);
    __syncthreads();
    const int it = *(const int*)&smem[0];
    __syncthreads();
    if (it >= 64) break;
    const int qt = 15 - (it >> 2);          // heavy-first within partition (128-row tiles)
    const int bh = (xcd << 2) + (it & 3), b = bh >> 4, h = bh & 15;
    const int q0 = qt << 7;
    const size_t bT = (size_t)b * T_;
    const u16* kvPb = kvP + bT * 1024 + (h << 6);
    const u16* krb  = krope + bT * 64;
    const u16* vTb  = vT + (size_t)bh * 128 * T_;
    const int qlo = q0 + (wid << 4);
    const int qhi = qlo + 15;
    const int nkv = (qt << 1) + 2;

    auto STAGE = [&](int buf, int k0){
      const int base = buf << 14;
      #pragma unroll
      for (int r = 0; r < 4; ++r){
        int c = (r << 9) + tid;              // 0..2047 chunks of 16B
        const u16* src;
        if (r < 2){
          int row = c >> 4, cc = c & 15;
          int ccx = (cc & 8) | ((cc & 7) ^ (row & 7));
          int col0 = ccx << 3;
          src = (col0 < 64) ? (kvPb + (size_t)(k0 + row) * 1024 + col0)
                            : (krb  + (size_t)(k0 + row) * 64 + (col0 - 64));
        } else {
          int cv = c - 1024;
          int row = cv >> 3, cc = cv & 7;
          int ccx = cc ^ (row & 7);
          src = vTb + (size_t)row * T_ + k0 + (ccx << 3);
        }
        gld_lds16(src, &smem[base + (c << 3)]);
      }
    };

    bf16x8 qf[4];
    {
      size_t grow = bT + qlo + l16;
      #pragma unroll
      for (int ks = 0; ks < 4; ++ks){
        int d = (ks << 5) + lk;
        const u16* src = (ks < 2) ? (qP + grow * 1024 + (h << 6) + d)
                                  : (qrope + grow * 64 + (d - 64));
        qf[ks] = *reinterpret_cast<const bf16x8*>(src);
      }
    }
    f32x4 o[8] = {};
    float m = -3e38f, l = 0.f;

    STAGE(0, 0);
    __syncthreads();
    int cur = 0;

    for (int kv = 0; kv < nkv; ++kv){
      const int k0 = kv << 6;
      if (kv + 1 < nkv) STAGE(cur ^ 1, (kv + 1) << 6);
      if (k0 <= qhi){
        const int kb = cur << 14;
        f32x4 s[4] = {};
        __builtin_amdgcn_s_setprio(1);
        #pragma unroll
        for (int ks = 0; ks < 4; ++ks){
          int colsw = ((ks << 5) + lk) ^ sw8;
          #pragma unroll
          for (int n = 0; n < 4; ++n){
            bf16x8 kf = *reinterpret_cast<const bf16x8*>(&smem[kb + ((n << 4) + l16) * 128 + colsw]);
            s[n] = mfma16(kf, qf[ks], s[n]);
          }
        }
        __builtin_amdgcn_s_setprio(0);
        if (k0 + 63 > qlo){                  // only the wave's diagonal tile needs masking
          const int tq = qlo + l16;
          #pragma unroll
          for (int n = 0; n < 4; ++n)
            #pragma unroll
            for (int j = 0; j < 4; ++j)
              s[n][j] = (k0 + (n << 4) + r4 + j <= tq) ? s[n][j] : -3e38f;
        }
        float mx;
        {
          float a0 = fmaxf(fmaxf(s[0][0], s[0][1]), fmaxf(s[0][2], s[0][3]));
          float a1 = fmaxf(fmaxf(s[1][0], s[1][1]), fmaxf(s[1][2], s[1][3]));
          float a2 = fmaxf(fmaxf(s[2][0], s[2][1]), fmaxf(s[2][2], s[2][3]));
          float a3 = fmaxf(fmaxf(s[3][0], s[3][1]), fmaxf(s[3][2], s[3][3]));
          mx = fmaxf(fmaxf(a0, a1), fmaxf(a2, a3));
          mx = fmaxf(mx, __shfl_xor(mx, 16));
          mx = fmaxf(mx, __shfl_xor(mx, 32));
        }
        if (__ballot(mx > m + 8.f)){
          float mnew = fmaxf(m, mx);
          float alpha = exp2f(m - mnew);
          m = mnew; l *= alpha;
          #pragma unroll
          for (int j = 0; j < 4; ++j){
            float av = __shfl(alpha, r4 + j);
            #pragma unroll
            for (int db = 0; db < 8; ++db) o[db][j] *= av;
          }
        }
        unsigned w[4][2];
        float rs = 0.f;
        #pragma unroll
        for (int n = 0; n < 4; ++n)
          #pragma unroll
          for (int jh = 0; jh < 2; ++jh){
            float p0 = exp2f(s[n][2*jh]     - m);
            float p1 = exp2f(s[n][2*jh + 1] - m);
            rs += p0 + p1;
            w[n][jh] = cvt_pk_bf16(p0, p1);
          }
        rs += __shfl_xor(rs, 16);
        rs += __shfl_xor(rs, 32);
        l += rs;
        const int srcA = l16 + ((g & 1) << 5);
        const int srcB = srcA + 16;
        const bool hi = (g >= 2);
        bf16x8 pa[2];
        #pragma unroll
        for (int ks2 = 0; ks2 < 2; ++ks2){
          unsigned a0 = __shfl((int)w[2*ks2][0],     srcA);
          unsigned b0 = __shfl((int)w[2*ks2 + 1][0], srcA);
          unsigned a1 = __shfl((int)w[2*ks2][1],     srcA);
          unsigned b1 = __shfl((int)w[2*ks2 + 1][1], srcA);
          unsigned a2 = __shfl((int)w[2*ks2][0],     srcB);
          unsigned b2 = __shfl((int)w[2*ks2 + 1][0], srcB);
          unsigned a3 = __shfl((int)w[2*ks2][1],     srcB);
          unsigned b3 = __shfl((int)w[2*ks2 + 1][1], srcB);
          union { unsigned u[4]; bf16x8 v; } pk;
          pk.u[0] = hi ? b0 : a0;
          pk.u[1] = hi ? b1 : a1;
          pk.u[2] = hi ? b2 : a2;
          pk.u[3] = hi ? b3 : a3;
          pa[ks2] = pk.v;
        }
        __builtin_amdgcn_s_setprio(1);
        #pragma unroll
        for (int ks2 = 0; ks2 < 2; ++ks2){
          int colsw = ((ks2 << 5) + lk) ^ sw8;
          #pragma unroll
          for (int db = 0; db < 8; ++db){
            bf16x8 vb = *reinterpret_cast<const bf16x8*>(&smem[(cur << 14) + 8192 + ((db << 4) + l16) * 64 + colsw]);
            o[db] = mfma16(pa[ks2], vb, o[db]);
          }
        }
        __builtin_amdgcn_s_setprio(0);
      }
      __syncthreads();                      // drains prefetch; reads done before buffer reuse
      cur ^= 1;
    }
    #pragma unroll
    for (int j = 0; j < 4; ++j){
      float lv = __shfl(l, r4 + j);
      float rinv = 1.f / lv;
      const int tq = qlo + r4 + j;
      u16* dst = aout + (bT + tq) * 2048 + (h << 7) + l16;
      #pragma unroll
      for (int db = 0; db < 8; ++db)
        dst[db << 4] = f2bf(o[db][j] * rinv);
    }
  }
}

extern "C" void kernel_launch(void* const* d_in, const int* in_sizes, int n_in,
                              void* d_out, int out_size, void* d_ws, size_t ws_size,
                              hipStream_t stream){
  const void* x       = d_in[0];
  const void* cosp    = d_in[1];
  const void* sinp    = d_in[2];
  const void* w_kv    = d_in[3];
  const void* w_kdec  = d_in[4];
  const void* w_vdec  = d_in[5];
  const void* w_qc    = d_in[6];
  const void* w_qdec  = d_in[7];
  const void* w_krope = d_in[8];
  const void* w_qrope = d_in[9];
  const void* w_o     = d_in[10];

  char* ws = (char*)d_ws;
  size_t off = 0;
  auto alloc = [&](size_t bytes){ void* p = ws + off; off += (bytes + 255) & ~(size_t)255; return p; };
  int* ticket   = (int*)alloc(1024);                         // 8 tickets, stride 16 ints
  u16* x_bf     = (u16*)alloc((size_t)NROWS * DIM_ * 2);
  u16* w_c1T    = (u16*)alloc((size_t)2304 * DIM_ * 2);      // [kvT(512); qcT(1536); kropeT(64); qropeT(64); pad(128)] x 2048
  u16* w_kvdT   = (u16*)alloc((size_t)3072 * DC_ * 2);       // [kdecPackedT(1024); vdecT(2048)] x 512
  u16* w_qdPT   = (u16*)alloc((size_t)1024 * DCQ_ * 2);      // packed qdecT (1024 x 1536)
  u16* w_oT     = (u16*)alloc((size_t)DIM_ * DIM_ * 2);
  u16* xc       = (u16*)alloc((size_t)NROWS * 2304 * 2);     // [c_kv(512) | c_q(1536) | ropes(128) | pad]
  u16* qP       = (u16*)alloc((size_t)NROWS * 1024 * 2);     // packed q decode (pre-scaled)
  u16* kvP      = (u16*)alloc((size_t)NROWS * 1024 * 2);     // packed K only (stride 1024)
  u16* krope    = (u16*)alloc((size_t)NROWS * 64 * 2);
  u16* qrope    = (u16*)alloc((size_t)NROWS * 64 * 2);       // pre-scaled
  u16* vT       = (u16*)alloc((size_t)32 * 128 * T_ * 2);    // [bh][d][t], written by G2 epilogue
  u16* aout     = (u16*)alloc((size_t)NROWS * DIM_ * 2);
  (void)in_sizes; (void)n_in; (void)out_size; (void)ws_size;

  const float SC2 = 0.12753139626374414f;   // 1/sqrt(128) * log2(e)
  const u16* cosr = (const u16*)cosp;

  // merged x-convert + weight transposes (8192 conv blocks + 2880 transpose blocks)
  TPack tp;
  tp.d[0] = { w_kv,    w_c1T,                        512,  2048, 64,  8,  0    };
  tp.d[1] = { w_qc,    w_c1T + (size_t)512 * 2048,   1536, 2048, 64,  24, 256  };
  tp.d[2] = { w_krope, w_c1T + (size_t)2048 * 2048,  64,   2048, 64,  1,  1024 };
  tp.d[3] = { w_qrope, w_c1T + (size_t)2112 * 2048,  64,   2048, 64,  1,  1056 };
  tp.d[4] = { w_kdec,  w_kvdT,                       2048, 512,  128, 16, 1088 };
  tp.d[5] = { w_vdec,  w_kvdT + (size_t)1024 * 512,  2048, 512,  64,  32, 1216 };
  tp.d[6] = { w_qdec,  w_qdPT,                       2048, 1536, 128, 16, 1472 };
  tp.d[7] = { w_o,     w_oT,                         2048, 2048, 64,  32, 1856 };
  hipLaunchKernelGGL(k_prep, dim3(CONVBLK + 2880), dim3(256), 0, stream, x, x_bf, tp, cosr);

  // G13: xc = x @ [w_kv | w_qc | rope-pre]  (4096 x 2176 used), grid (32,17) = 544 blocks
  // (pad N-tile dropped; 544%8==0 keeps XCD swizzle bijective); A straight from x when bf16
  hipLaunchKernelGGL(k_gemm, dim3(32, 17), dim3(256), 0, stream,
                     x_bf, DIM_, w_c1T, DIM_, xc, 2304, 1.0f,
                     x_bf, DIM_, w_c1T, DIM_, xc, 2304, 1.0f,
                     17, 1, (void*)nullptr, cosr,
                     (const u16*)x, (const u16*)x,
                     (u16*)nullptr, (u16*)nullptr,
                     (const u16*)nullptr, (const void*)nullptr, (const void*)nullptr,
                     (u16*)nullptr, (u16*)nullptr, (int*)nullptr, 0);
  // G4 + G2 + RoPE in ONE launch (1024 gemm blocks + 2048 rope blocks, 1-D grid):
  //   flat<256:       qP = xc[:, 512:2048] @ w_qdecP  (K=1536, heavy group first)
  //   256<=flat<1024: K -> kvP (cols<1024); V -> vT direct transposed (cols>=1024)
  //   flat>=1024:     RoPE from xc cols 2048.. (depends only on G13; block 1024 resets tickets)
  hipLaunchKernelGGL(k_gemm, dim3(3072, 1), dim3(256), 0, stream,
                     xc + 512, 2304, w_qdPT, DCQ_, qP, 1024, SC2,
                     xc, 2304, w_kvdT, DC_, kvP, 1024, 1.0f,
                     8, 0, (void*)nullptr, (const u16*)nullptr,
                     (const u16*)nullptr, (const u16*)nullptr,
                     (u16*)nullptr, vT,
                     xc, cosp, sinp, krope, qrope, ticket, 1024);
  // attention (256 workers x 8 waves, 128-row items, 2:1 stealing, XCD-partitioned tickets)
  hipLaunchKernelGGL(k_attn, dim3(256), dim3(512), 0, stream,
                     qP, kvP, vT, krope, qrope, aout, ticket);
  // G5: out = aout @ w_o  (4096 x 2048, K=2048) -> (32,16) = 512 blocks = 2/CU, XCD-chunked
  hipLaunchKernelGGL(k_gemm, dim3(32, 16), dim3(256), 0, stream,
                     aout, DIM_, w_oT, DIM_, (u16*)nullptr, DIM_, 1.0f,
                     aout, DIM_, w_oT, DIM_, (u16*)nullptr, DIM_, 1.0f,
                     16, 1, d_out, cosr,
                     (const u16*)nullptr, (const u16*)nullptr,
                     (u16*)nullptr, (u16*)nullptr,
                     (const u16*)nullptr, (const void*)nullptr, (const void*)nullptr,
                     (u16*)nullptr, (u16*)nullptr, (int*)nullptr, 0);
}

// Round 24
// 232.419 us; speedup vs baseline: 1.0873x; 1.0161x over previous
//
#include <hip/hip_runtime.h>
#include <stdint.h>
#include <math.h>

#define B_    2
#define T_    2048
#define DIM_  2048
#define H_    16
#define DC_   512
#define DCQ_  1536
#define NROWS (B_*T_)   // 4096

typedef unsigned short u16;
typedef __attribute__((ext_vector_type(8))) __bf16 bf16x8;
typedef __attribute__((ext_vector_type(4))) float  f32x4;
typedef __attribute__((ext_vector_type(8))) unsigned short u16x8;
typedef __attribute__((ext_vector_type(4))) float  f4v;

__device__ __forceinline__ u16 f2bf(float f){
  unsigned u = __float_as_uint(f);
  u += 0x7FFFu + ((u >> 16) & 1u);   // RNE
  return (u16)(u >> 16);
}
__device__ __forceinline__ float bf2f(u16 h){ return __uint_as_float(((unsigned)h) << 16); }

__device__ __forceinline__ unsigned cvt_pk_bf16(float lo, float hi){
  unsigned r;
  asm("v_cvt_pk_bf16_f32 %0, %1, %2" : "=v"(r) : "v"(lo), "v"(hi));
  return r;
}

// async global->LDS, 16B per lane; LDS dest = wave-uniform base + lane*16.
__device__ __forceinline__ void gld_lds16(const void* g, void* l){
  auto gp = reinterpret_cast<__attribute__((address_space(1))) unsigned int*>(
      reinterpret_cast<uintptr_t>(g));
  auto lp = reinterpret_cast<__attribute__((address_space(3))) unsigned int*>(
      reinterpret_cast<uintptr_t>(l));
  __builtin_amdgcn_global_load_lds(gp, lp, 16, 0, 0);
}

__device__ __forceinline__ f32x4 mfma16(bf16x8 a, bf16x8 b, f32x4 c){
  return __builtin_amdgcn_mfma_f32_16x16x32_bf16(a, b, c, 0, 0, 0);
}

__device__ __forceinline__ void vmwait0(){ asm volatile("s_waitcnt vmcnt(0)" ::: "memory"); }
__device__ __forceinline__ void vmwait8(){ asm volatile("s_waitcnt vmcnt(8)" ::: "memory"); }
__device__ __forceinline__ void barr(){ asm volatile("s_barrier" ::: "memory"); }

// dtype flag: cos[0,0]==1.0 -> bf16 u16[0]=0x3F80, fp32 u16[0]=0x0000.

struct TDesc { const void* src; u16* dst; int srcStride, dstStride, cblk, nbx, blk0; };
struct TPack { TDesc d[8]; };
#define CONVBLK 8192

// transpose one 64x64 tile (shared by k_prep and k_gemm side path)
__device__ __forceinline__ void do_transpose(void* ldsbuf, const TPack& p, int tb,
                                             int tid, int f){
  u16 (*tile)[72] = reinterpret_cast<u16(*)[72]>(ldsbuf);
  int i = 0;
  #pragma unroll
  for (int k = 1; k < 8; ++k) if (tb >= p.d[k].blk0) i = k;
  const void* src = p.d[i].src;
  u16* dst = p.d[i].dst;
  const int srcStride = p.d[i].srcStride, dstStride = p.d[i].dstStride;
  const int rel = tb - p.d[i].blk0;
  const int bx = rel % p.d[i].nbx, by = rel / p.d[i].nbx;
  const int r0 = by << 6, c0 = bx * p.d[i].cblk;
  #pragma unroll
  for (int it = 0; it < 2; ++it){
    int task = (it << 8) + tid;
    int r = task >> 3, c8 = (task & 7) << 3;
    if (f){
      const u16* pp = (const u16*)src + (size_t)(r0 + r) * srcStride + c0 + c8;
      u16x8 v = *reinterpret_cast<const u16x8*>(pp);
      #pragma unroll
      for (int j = 0; j < 8; ++j) tile[r][c8 + j] = v[j];
    } else {
      const float* pp = (const float*)src + (size_t)(r0 + r) * srcStride + c0 + c8;
      f4v a = reinterpret_cast<const f4v*>(pp)[0];
      f4v b = reinterpret_cast<const f4v*>(pp)[1];
      tile[r][c8+0]=f2bf(a.x); tile[r][c8+1]=f2bf(a.y); tile[r][c8+2]=f2bf(a.z); tile[r][c8+3]=f2bf(a.w);
      tile[r][c8+4]=f2bf(b.x); tile[r][c8+5]=f2bf(b.y); tile[r][c8+6]=f2bf(b.z); tile[r][c8+7]=f2bf(b.w);
    }
  }
  __syncthreads();
  #pragma unroll
  for (int it = 0; it < 2; ++it){
    int task = (it << 8) + tid;
    int rr = task >> 3, cc8 = (task & 7) << 3;
    u16x8 v;
    #pragma unroll
    for (int j = 0; j < 8; ++j) v[j] = tile[cc8 + j][rr];
    *reinterpret_cast<u16x8*>(dst + (size_t)((bx << 6) + rr) * dstStride + r0 + cc8) = v;
  }
}

// ---------------- x-convert + w_c1T transposes only (d[0..3]); decode/output-weight
// transposes moved into the G13 launch's side path (fills its 32-block tail round).
__global__ void k_prep(const void* __restrict__ xsrc, u16* __restrict__ x_bf,
                       TPack p, const u16* __restrict__ cosr){
  __shared__ u16 tile[64][72];
  const int bid = blockIdx.x;
  const int tid = threadIdx.x;
  const int f = (cosr[0] == (u16)0x3F80u);
  if (bid < CONVBLK){
    if (f) return;                            // bf16 input: G13 reads x directly, skip copy
    int id = bid * 256 + tid;                 // n4 = 2097152 = 8192*256 exactly
    f4v v = reinterpret_cast<const f4v*>(xsrc)[id];
    unsigned lo = (unsigned)f2bf(v.x) | ((unsigned)f2bf(v.y) << 16);
    unsigned hi = (unsigned)f2bf(v.z) | ((unsigned)f2bf(v.w) << 16);
    reinterpret_cast<uint2*>(x_bf)[id] = make_uint2(lo, hi);
    return;
  }
  do_transpose(tile, p, bid - CONVBLK, tid, f);
}

// ---------------- unified 128x128 GEMM: 256 thr / 4 waves (2x2), 64x64 per wave,
// LDS 64 KB -> 2 blocks/CU. Row-XOR swizzle via inverse-swizzled global_load_lds sources;
// counted vmcnt(8) pipeline; setprio around MFMA cluster. Two groups by N-tile index.
// alt-A: bf16 passthrough of unconverted input. vt: group cols >= 1024 -> vT transposed.
// Side paths (blocks with flat >= ngemm; EARLY-RETURN, safe per round-23 evidence):
//   sidemode 1 = RoPE elementwise (depends only on G13's xc; used in G2G4 launch)
//   sidemode 2 = weight transposes (depend only on inputs; used in G13 launch, fills tail)
__global__ __launch_bounds__(256, 2) void k_gemm(
    const u16* __restrict__ A0, int lda0, const u16* __restrict__ Bt0, int K0,
    u16* __restrict__ C0, int ldc0, float os0,
    const u16* __restrict__ A1, int lda1, const u16* __restrict__ Bt1, int K1,
    u16* __restrict__ C1, int ldc1, float os1,
    int ysplit, int swz, void* outp, const u16* __restrict__ cosr,
    const u16* __restrict__ alt0, const u16* __restrict__ alt1,
    u16* __restrict__ vt0, u16* __restrict__ vt1,
    const u16* __restrict__ ropeXc, const void* __restrict__ rcosp,
    const void* __restrict__ rsinp, u16* __restrict__ ropeK,
    u16* __restrict__ ropeQ, int* __restrict__ rticket,
    int ngemm, int sidemode, TPack tpp){
  __shared__ alignas(16) u16 lds[32768];   // 64 KB
  const int tid = threadIdx.x;
  const int flat = blockIdx.y * gridDim.x + blockIdx.x;

  if (sidemode && flat >= ngemm){
    const int tb = flat - ngemm;
    if (sidemode == 1){
      // ---- RoPE path (2048 trailing blocks; reads xc cols 2048..2175, stride 2304)
      if (tb == 0 && tid < 128) rticket[tid] = 0;    // ticket reset ahead of k_attn
      const int f2 = (((const u16*)rcosp)[0] == (u16)0x3F80u);
      int id = tb * 256 + tid;                       // exactly NROWS*128
      int row = id >> 7, c = id & 127;
      int t = row & (T_ - 1);
      int d = c & 63, i = d & 31;
      float cs, sn;
      if (f2){ cs = bf2f(((const u16*)rcosp)[t * 32 + i]); sn = bf2f(((const u16*)rsinp)[t * 32 + i]); }
      else   { cs = ((const float*)rcosp)[t * 32 + i];     sn = ((const float*)rsinp)[t * 32 + i]; }
      int base = c & 64;
      float t1 = bf2f(ropeXc[(size_t)row * 2304 + 2048 + base + i]);
      float t2 = bf2f(ropeXc[(size_t)row * 2304 + 2048 + base + 32 + i]);
      float v = (d < 32) ? (t1 * cs - t2 * sn) : (t2 * cs + t1 * sn);
      if (c >= 64) v *= 0.12753139626374414f;        // 1/sqrt(128)*log2(e) folded into q
      ((c < 64) ? ropeK : ropeQ)[(size_t)row * 64 + d] = f2bf(v);
    } else {
      // ---- weight-transpose path (1792 trailing blocks in the G13 launch)
      const int f2 = cosr ? (cosr[0] == (u16)0x3F80u) : 1;
      do_transpose(lds, tpp, tb, tid, f2);
    }
    return;
  }

  const int wid = tid >> 6, lane = tid & 63;
  const int wr = wid >> 1, wc = wid & 1;
  const int l16 = lane & 15, g = lane >> 4;
  int lin = flat;
  if (swz){
    const int q8 = ngemm >> 3;               // swizzle over gemm blocks only (ngemm%8==0)
    lin = (lin & 7) * q8 + (lin >> 3);       // bijective XCD chunking
  }
  const int m0 = (lin & 31) << 7;
  int nt = lin >> 5;
  const u16 *A, *Bt, *alt; u16 *C, *vtp; int lda, K, ldc; float oscale;
  if (nt < ysplit){ A = A0; lda = lda0; Bt = Bt0; K = K0; C = C0; ldc = ldc0; oscale = os0; alt = alt0; vtp = vt0; }
  else { nt -= ysplit; A = A1; lda = lda1; Bt = Bt1; K = K1; C = C1; ldc = ldc1; oscale = os1; alt = alt1; vtp = vt1; }
  const int f = cosr ? (cosr[0] == (u16)0x3F80u) : 1;
  if (alt && f) A = alt;                     // bf16 input: read source directly
  const int n0 = nt << 7;
  const size_t Kz = (size_t)K;
  const int nkt = K >> 6;

  auto STAGE = [&](int kt, int bufn){
    const int kb = kt << 6;
    #pragma unroll
    for (int q = 0; q < 8; ++q){
      const int ht = q >> 2;                 // 0 = A half, 1 = B half
      const int cq = ((q & 3) << 8) + tid;   // chunk 0..1023 within half
      const int Lb = cq << 4;                // byte in [128][128B] half-tile
      const int row = Lb >> 7;
      const int colb = (Lb & 127) ^ ((row & 7) << 4);   // inverse-swizzled source
      const u16* src = ht ? (Bt + (size_t)(n0 + row) * Kz + kb + (colb >> 1))
                          : (A  + (size_t)(m0 + row) * lda + kb + (colb >> 1));
      gld_lds16(src, &lds[bufn * 16384 + ht * 8192 + (cq << 3)]);
    }
  };

  f32x4 acc[4][4] = {};

  STAGE(0, 0);
  int buf = 0;

  for (int kt = 0; kt < nkt; ++kt){
    if (kt + 1 < nkt){ STAGE(kt + 1, buf ^ 1); vmwait8(); }   // waits tile-kt's 8 loads
    else vmwait0();
    barr();                                                    // staged tile visible to all
    bf16x8 af[2][4], bfr[2][4];
    #pragma unroll
    for (int ks = 0; ks < 2; ++ks){
      #pragma unroll
      for (int mi = 0; mi < 4; ++mi){
        int row = (wr << 6) + (mi << 4) + l16;
        int cb = ((ks << 6) + (g << 4)) ^ ((row & 7) << 4);
        af[ks][mi] = *reinterpret_cast<const bf16x8*>(&lds[buf * 16384 + (((row << 7) + cb) >> 1)]);
      }
      #pragma unroll
      for (int ni = 0; ni < 4; ++ni){
        int row = (wc << 6) + (ni << 4) + l16;
        int cb = ((ks << 6) + (g << 4)) ^ ((row & 7) << 4);
        bfr[ks][ni] = *reinterpret_cast<const bf16x8*>(&lds[buf * 16384 + 8192 + (((row << 7) + cb) >> 1)]);
      }
    }
    __builtin_amdgcn_s_setprio(1);
    #pragma unroll
    for (int ks = 0; ks < 2; ++ks)
      #pragma unroll
      for (int mi = 0; mi < 4; ++mi)
        #pragma unroll
        for (int ni = 0; ni < 4; ++ni)
          acc[mi][ni] = mfma16(af[ks][mi], bfr[ks][ni], acc[mi][ni]);
    __builtin_amdgcn_s_setprio(0);
    barr();                                  // reads done before next STAGE overwrites
    buf ^= 1;
  }

  const int r4 = g << 2;
  #pragma unroll
  for (int mi = 0; mi < 4; ++mi){
    int row = m0 + (wr << 6) + (mi << 4) + r4;
    #pragma unroll
    for (int ni = 0; ni < 4; ++ni){
      int col = n0 + (wc << 6) + (ni << 4) + l16;
      if (vtp && col >= 1024){
        // V quadrant: write transposed to vT[bh][d][t]; rows j are consecutive t.
        int hd = col - 1024;
        u16* dst = vtp + (((size_t)(((row >> 11) << 4) + (hd >> 7)) << 7) + (hd & 127)) * (size_t)T_ + (row & (T_ - 1));
        union { u16 u[4]; uint2 v; } pk;
        #pragma unroll
        for (int j = 0; j < 4; ++j) pk.u[j] = f2bf(acc[mi][ni][j] * oscale);
        *reinterpret_cast<uint2*>(dst) = pk.v;
        continue;
      }
      #pragma unroll
      for (int j = 0; j < 4; ++j){
        float v = acc[mi][ni][j] * oscale;
        if (outp){
          if (f) ((u16*)outp)[(size_t)(row + j) * ldc + col] = f2bf(v);
          else   ((float*)outp)[(size_t)(row + j) * ldc + col] = v;
        } else {
          C[(size_t)(row + j) * ldc + col] = f2bf(v);
        }
      }
    }
  }
}

// ---------------- causal flash attention: 128-row items, 8 waves x 16 rows (512 thr).
// Round-17 config (measured best): 256 workers (1 block/CU), per-XCD tickets,
// 64 items over 32 workers/partition = 2:1 heavy-first STEALING (1:1 maps regress --
// rounds 12 & 18). 64KB LDS double-buffer; setprio around MFMA clusters.
__global__ __launch_bounds__(512, 2) void k_attn(const u16* __restrict__ qP,
                                                 const u16* __restrict__ kvP,
                                                 const u16* __restrict__ vT,
                                                 const u16* __restrict__ krope,
                                                 const u16* __restrict__ qrope,
                                                 u16* __restrict__ aout,
                                                 int* __restrict__ ticket){
  __shared__ alignas(16) u16 smem[32768];   // 64 KB: 2 buffers x (K [64][128] + V [128][64])
  const int tid = threadIdx.x, wid = tid >> 6, lane = tid & 63;
  const int l16 = lane & 15, g = lane >> 4;
  const int lk = g << 3, r4 = g << 2;
  const int sw8 = (l16 & 7) << 3;
  const int xcd = blockIdx.x & 7;

  while (true){
    if (tid == 0) *(int*)&smem[0] = atomicAdd(&ticket[xcd << 4], 1);
    __syncthreads();
    const int it = *(const int*)&smem[0];
    __syncthreads();
    if (it >= 64) break;
    const int qt = 15 - (it >> 2);          // heavy-first within partition (128-row tiles)
    const int bh = (xcd << 2) + (it & 3), b = bh >> 4, h = bh & 15;
    const int q0 = qt << 7;
    const size_t bT = (size_t)b * T_;
    const u16* kvPb = kvP + bT * 1024 + (h << 6);
    const u16* krb  = krope + bT * 64;
    const u16* vTb  = vT + (size_t)bh * 128 * T_;
    const int qlo = q0 + (wid << 4);
    const int qhi = qlo + 15;
    const int nkv = (qt << 1) + 2;

    auto STAGE = [&](int buf, int k0){
      const int base = buf << 14;
      #pragma unroll
      for (int r = 0; r < 4; ++r){
        int c = (r << 9) + tid;              // 0..2047 chunks of 16B
        const u16* src;
        if (r < 2){
          int row = c >> 4, cc = c & 15;
          int ccx = (cc & 8) | ((cc & 7) ^ (row & 7));
          int col0 = ccx << 3;
          src = (col0 < 64) ? (kvPb + (size_t)(k0 + row) * 1024 + col0)
                            : (krb  + (size_t)(k0 + row) * 64 + (col0 - 64));
        } else {
          int cv = c - 1024;
          int row = cv >> 3, cc = cv & 7;
          int ccx = cc ^ (row & 7);
          src = vTb + (size_t)row * T_ + k0 + (ccx << 3);
        }
        gld_lds16(src, &smem[base + (c << 3)]);
      }
    };

    bf16x8 qf[4];
    {
      size_t grow = bT + qlo + l16;
      #pragma unroll
      for (int ks = 0; ks < 4; ++ks){
        int d = (ks << 5) + lk;
        const u16* src = (ks < 2) ? (qP + grow * 1024 + (h << 6) + d)
                                  : (qrope + grow * 64 + (d - 64));
        qf[ks] = *reinterpret_cast<const bf16x8*>(src);
      }
    }
    f32x4 o[8] = {};
    float m = -3e38f, l = 0.f;

    STAGE(0, 0);
    __syncthreads();
    int cur = 0;

    for (int kv = 0; kv < nkv; ++kv){
      const int k0 = kv << 6;
      if (kv + 1 < nkv) STAGE(cur ^ 1, (kv + 1) << 6);
      if (k0 <= qhi){
        const int kb = cur << 14;
        f32x4 s[4] = {};
        __builtin_amdgcn_s_setprio(1);
        #pragma unroll
        for (int ks = 0; ks < 4; ++ks){
          int colsw = ((ks << 5) + lk) ^ sw8;
          #pragma unroll
          for (int n = 0; n < 4; ++n){
            bf16x8 kf = *reinterpret_cast<const bf16x8*>(&smem[kb + ((n << 4) + l16) * 128 + colsw]);
            s[n] = mfma16(kf, qf[ks], s[n]);
          }
        }
        __builtin_amdgcn_s_setprio(0);
        if (k0 + 63 > qlo){                  // only the wave's diagonal tile needs masking
          const int tq = qlo + l16;
          #pragma unroll
          for (int n = 0; n < 4; ++n)
            #pragma unroll
            for (int j = 0; j < 4; ++j)
              s[n][j] = (k0 + (n << 4) + r4 + j <= tq) ? s[n][j] : -3e38f;
        }
        float mx;
        {
          float a0 = fmaxf(fmaxf(s[0][0], s[0][1]), fmaxf(s[0][2], s[0][3]));
          float a1 = fmaxf(fmaxf(s[1][0], s[1][1]), fmaxf(s[1][2], s[1][3]));
          float a2 = fmaxf(fmaxf(s[2][0], s[2][1]), fmaxf(s[2][2], s[2][3]));
          float a3 = fmaxf(fmaxf(s[3][0], s[3][1]), fmaxf(s[3][2], s[3][3]));
          mx = fmaxf(fmaxf(a0, a1), fmaxf(a2, a3));
          mx = fmaxf(mx, __shfl_xor(mx, 16));
          mx = fmaxf(mx, __shfl_xor(mx, 32));
        }
        if (__ballot(mx > m + 8.f)){
          float mnew = fmaxf(m, mx);
          float alpha = exp2f(m - mnew);
          m = mnew; l *= alpha;
          #pragma unroll
          for (int j = 0; j < 4; ++j){
            float av = __shfl(alpha, r4 + j);
            #pragma unroll
            for (int db = 0; db < 8; ++db) o[db][j] *= av;
          }
        }
        unsigned w[4][2];
        float rs = 0.f;
        #pragma unroll
        for (int n = 0; n < 4; ++n)
          #pragma unroll
          for (int jh = 0; jh < 2; ++jh){
            float p0 = exp2f(s[n][2*jh]     - m);
            float p1 = exp2f(s[n][2*jh + 1] - m);
            rs += p0 + p1;
            w[n][jh] = cvt_pk_bf16(p0, p1);
          }
        rs += __shfl_xor(rs, 16);
        rs += __shfl_xor(rs, 32);
        l += rs;
        const int srcA = l16 + ((g & 1) << 5);
        const int srcB = srcA + 16;
        const bool hi = (g >= 2);
        bf16x8 pa[2];
        #pragma unroll
        for (int ks2 = 0; ks2 < 2; ++ks2){
          unsigned a0 = __shfl((int)w[2*ks2][0],     srcA);
          unsigned b0 = __shfl((int)w[2*ks2 + 1][0], srcA);
          unsigned a1 = __shfl((int)w[2*ks2][1],     srcA);
          unsigned b1 = __shfl((int)w[2*ks2 + 1][1], srcA);
          unsigned a2 = __shfl((int)w[2*ks2][0],     srcB);
          unsigned b2 = __shfl((int)w[2*ks2 + 1][0], srcB);
          unsigned a3 = __shfl((int)w[2*ks2][1],     srcB);
          unsigned b3 = __shfl((int)w[2*ks2 + 1][1], srcB);
          union { unsigned u[4]; bf16x8 v; } pk;
          pk.u[0] = hi ? b0 : a0;
          pk.u[1] = hi ? b1 : a1;
          pk.u[2] = hi ? b2 : a2;
          pk.u[3] = hi ? b3 : a3;
          pa[ks2] = pk.v;
        }
        __builtin_amdgcn_s_setprio(1);
        #pragma unroll
        for (int ks2 = 0; ks2 < 2; ++ks2){
          int colsw = ((ks2 << 5) + lk) ^ sw8;
          #pragma unroll
          for (int db = 0; db < 8; ++db){
            bf16x8 vb = *reinterpret_cast<const bf16x8*>(&smem[(cur << 14) + 8192 + ((db << 4) + l16) * 64 + colsw]);
            o[db] = mfma16(pa[ks2], vb, o[db]);
          }
        }
        __builtin_amdgcn_s_setprio(0);
      }
      __syncthreads();                      // drains prefetch; reads done before buffer reuse
      cur ^= 1;
    }
    #pragma unroll
    for (int j = 0; j < 4; ++j){
      float lv = __shfl(l, r4 + j);
      float rinv = 1.f / lv;
      const int tq = qlo + r4 + j;
      u16* dst = aout + (bT + tq) * 2048 + (h << 7) + l16;
      #pragma unroll
      for (int db = 0; db < 8; ++db)
        dst[db << 4] = f2bf(o[db][j] * rinv);
    }
  }
}

extern "C" void kernel_launch(void* const* d_in, const int* in_sizes, int n_in,
                              void* d_out, int out_size, void* d_ws, size_t ws_size,
                              hipStream_t stream){
  const void* x       = d_in[0];
  const void* cosp    = d_in[1];
  const void* sinp    = d_in[2];
  const void* w_kv    = d_in[3];
  const void* w_kdec  = d_in[4];
  const void* w_vdec  = d_in[5];
  const void* w_qc    = d_in[6];
  const void* w_qdec  = d_in[7];
  const void* w_krope = d_in[8];
  const void* w_qrope = d_in[9];
  const void* w_o     = d_in[10];

  char* ws = (char*)d_ws;
  size_t off = 0;
  auto alloc = [&](size_t bytes){ void* p = ws + off; off += (bytes + 255) & ~(size_t)255; return p; };
  int* ticket   = (int*)alloc(1024);                         // 8 tickets, stride 16 ints
  u16* x_bf     = (u16*)alloc((size_t)NROWS * DIM_ * 2);
  u16* w_c1T    = (u16*)alloc((size_t)2304 * DIM_ * 2);      // [kvT(512); qcT(1536); kropeT(64); qropeT(64); pad] x 2048
  u16* w_kvdT   = (u16*)alloc((size_t)3072 * DC_ * 2);       // [kdecPackedT(1024); vdecT(2048)] x 512
  u16* w_qdPT   = (u16*)alloc((size_t)1024 * DCQ_ * 2);      // packed qdecT (1024 x 1536)
  u16* w_oT     = (u16*)alloc((size_t)DIM_ * DIM_ * 2);
  u16* xc       = (u16*)alloc((size_t)NROWS * 2304 * 2);     // [c_kv(512) | c_q(1536) | ropes(128) | pad]
  u16* qP       = (u16*)alloc((size_t)NROWS * 1024 * 2);     // packed q decode (pre-scaled)
  u16* kvP      = (u16*)alloc((size_t)NROWS * 1024 * 2);     // packed K only (stride 1024)
  u16* krope    = (u16*)alloc((size_t)NROWS * 64 * 2);
  u16* qrope    = (u16*)alloc((size_t)NROWS * 64 * 2);       // pre-scaled
  u16* vT       = (u16*)alloc((size_t)32 * 128 * T_ * 2);    // [bh][d][t], written by G2 epilogue
  u16* aout     = (u16*)alloc((size_t)NROWS * DIM_ * 2);
  (void)in_sizes; (void)n_in; (void)out_size; (void)ws_size;

  const float SC2 = 0.12753139626374414f;   // 1/sqrt(128) * log2(e)
  const u16* cosr = (const u16*)cosp;

  // prep: x-convert (8192 blocks) + w_c1T transposes only (1088 blocks)
  TPack tp = {};
  tp.d[0] = { w_kv,    w_c1T,                        512,  2048, 64,  8,  0    };
  tp.d[1] = { w_qc,    w_c1T + (size_t)512 * 2048,   1536, 2048, 64,  24, 256  };
  tp.d[2] = { w_krope, w_c1T + (size_t)2048 * 2048,  64,   2048, 64,  1,  1024 };
  tp.d[3] = { w_qrope, w_c1T + (size_t)2112 * 2048,  64,   2048, 64,  1,  1056 };
  tp.d[4] = { nullptr, nullptr, 0, 0, 0, 1, 1 << 30 };
  tp.d[5] = { nullptr, nullptr, 0, 0, 0, 1, 1 << 30 };
  tp.d[6] = { nullptr, nullptr, 0, 0, 0, 1, 1 << 30 };
  tp.d[7] = { nullptr, nullptr, 0, 0, 0, 1, 1 << 30 };
  hipLaunchKernelGGL(k_prep, dim3(CONVBLK + 1088), dim3(256), 0, stream, x, x_bf, tp, cosr);

  // decode/output-weight transposes: side blocks of the G13 launch (fill its tail round)
  TPack ts = {};
  ts.d[0] = { w_kdec, w_kvdT,                       2048, 512,  128, 16, 0    };
  ts.d[1] = { w_vdec, w_kvdT + (size_t)1024 * 512,  2048, 512,  64,  32, 128  };
  ts.d[2] = { w_qdec, w_qdPT,                       2048, 1536, 128, 16, 384  };
  ts.d[3] = { w_o,    w_oT,                         2048, 2048, 64,  32, 768  };
  ts.d[4] = { nullptr, nullptr, 0, 0, 0, 1, 1 << 30 };
  ts.d[5] = { nullptr, nullptr, 0, 0, 0, 1, 1 << 30 };
  ts.d[6] = { nullptr, nullptr, 0, 0, 0, 1, 1 << 30 };
  ts.d[7] = { nullptr, nullptr, 0, 0, 0, 1, 1 << 30 };
  TPack tz = {};

  // G13: xc = x @ [w_kv | w_qc | rope-pre], 544 gemm blocks (XCD-swizzled over ngemm=544)
  // + 1792 transpose side blocks = 2336 total. A straight from x when bf16.
  hipLaunchKernelGGL(k_gemm, dim3(2336, 1), dim3(256), 0, stream,
                     x_bf, DIM_, w_c1T, DIM_, xc, 2304, 1.0f,
                     x_bf, DIM_, w_c1T, DIM_, xc, 2304, 1.0f,
                     17, 1, (void*)nullptr, cosr,
                     (const u16*)x, (const u16*)x,
                     (u16*)nullptr, (u16*)nullptr,
                     (const u16*)nullptr, (const void*)nullptr, (const void*)nullptr,
                     (u16*)nullptr, (u16*)nullptr, (int*)nullptr,
                     544, 2, ts);
  // G4 + G2 + RoPE in ONE launch (1024 gemm blocks + 2048 rope blocks):
  //   flat<256:       qP = xc[:, 512:2048] @ w_qdecP  (K=1536, heavy group first)
  //   256<=flat<1024: K -> kvP (cols<1024); V -> vT direct transposed (cols>=1024)
  //   flat>=1024:     RoPE from xc cols 2048.. (block 1024 resets tickets)
  hipLaunchKernelGGL(k_gemm, dim3(3072, 1), dim3(256), 0, stream,
                     xc + 512, 2304, w_qdPT, DCQ_, qP, 1024, SC2,
                     xc, 2304, w_kvdT, DC_, kvP, 1024, 1.0f,
                     8, 0, (void*)nullptr, (const u16*)nullptr,
                     (const u16*)nullptr, (const u16*)nullptr,
                     (u16*)nullptr, vT,
                     xc, cosp, sinp, krope, qrope, ticket,
                     1024, 1, tz);
  // attention (256 workers x 8 waves, 128-row items, 2:1 stealing, XCD-partitioned tickets)
  hipLaunchKernelGGL(k_attn, dim3(256), dim3(512), 0, stream,
                     qP, kvP, vT, krope, qrope, aout, ticket);
  // G5: out = aout @ w_o  (4096 x 2048, K=2048) -> (32,16) = 512 blocks = 2/CU, XCD-chunked
  hipLaunchKernelGGL(k_gemm, dim3(32, 16), dim3(256), 0, stream,
                     aout, DIM_, w_oT, DIM_, (u16*)nullptr, DIM_, 1.0f,
                     aout, DIM_, w_oT, DIM_, (u16*)nullptr, DIM_, 1.0f,
                     16, 1, d_out, cosr,
                     (const u16*)nullptr, (const u16*)nullptr,
                     (u16*)nullptr, (u16*)nullptr,
                     (const u16*)nullptr, (const void*)nullptr, (const void*)nullptr,
                     (u16*)nullptr, (u16*)nullptr, (int*)nullptr,
                     512, 0, tz);
}

// Round 25
// 229.796 us; speedup vs baseline: 1.0997x; 1.0114x over previous
//
#include <hip/hip_runtime.h>
#include <stdint.h>
#include <math.h>

#define B_    2
#define T_    2048
#define DIM_  2048
#define H_    16
#define DC_   512
#define DCQ_  1536
#define NROWS (B_*T_)   // 4096

typedef unsigned short u16;
typedef __attribute__((ext_vector_type(8))) __bf16 bf16x8;
typedef __attribute__((ext_vector_type(4))) float  f32x4;
typedef __attribute__((ext_vector_type(8))) unsigned short u16x8;
typedef __attribute__((ext_vector_type(4))) float  f4v;

__device__ __forceinline__ u16 f2bf(float f){
  unsigned u = __float_as_uint(f);
  u += 0x7FFFu + ((u >> 16) & 1u);   // RNE
  return (u16)(u >> 16);
}
__device__ __forceinline__ float bf2f(u16 h){ return __uint_as_float(((unsigned)h) << 16); }

__device__ __forceinline__ unsigned cvt_pk_bf16(float lo, float hi){
  unsigned r;
  asm("v_cvt_pk_bf16_f32 %0, %1, %2" : "=v"(r) : "v"(lo), "v"(hi));
  return r;
}

// async global->LDS, 16B per lane; LDS dest = wave-uniform base + lane*16.
__device__ __forceinline__ void gld_lds16(const void* g, void* l){
  auto gp = reinterpret_cast<__attribute__((address_space(1))) unsigned int*>(
      reinterpret_cast<uintptr_t>(g));
  auto lp = reinterpret_cast<__attribute__((address_space(3))) unsigned int*>(
      reinterpret_cast<uintptr_t>(l));
  __builtin_amdgcn_global_load_lds(gp, lp, 16, 0, 0);
}

__device__ __forceinline__ f32x4 mfma16(bf16x8 a, bf16x8 b, f32x4 c){
  return __builtin_amdgcn_mfma_f32_16x16x32_bf16(a, b, c, 0, 0, 0);
}

__device__ __forceinline__ void vmwait0(){ asm volatile("s_waitcnt vmcnt(0)" ::: "memory"); }
__device__ __forceinline__ void vmwait8(){ asm volatile("s_waitcnt vmcnt(8)" ::: "memory"); }
__device__ __forceinline__ void barr(){ asm volatile("s_barrier" ::: "memory"); }

// dtype flag: cos[0,0]==1.0 -> bf16 u16[0]=0x3F80, fp32 u16[0]=0x0000.

struct TDesc { const void* src; u16* dst; int srcStride, dstStride, cblk, nbx, blk0; };
struct TPack { TDesc d[8]; };
#define TBLK 1088
#define CONVBLK 2048

// transpose one 64x64 tile (shared by k_prep and k_gemm side path)
__device__ __forceinline__ void do_transpose(void* ldsbuf, const TPack& p, int tb,
                                             int tid, int f){
  u16 (*tile)[72] = reinterpret_cast<u16(*)[72]>(ldsbuf);
  int i = 0;
  #pragma unroll
  for (int k = 1; k < 8; ++k) if (tb >= p.d[k].blk0) i = k;
  const void* src = p.d[i].src;
  u16* dst = p.d[i].dst;
  const int srcStride = p.d[i].srcStride, dstStride = p.d[i].dstStride;
  const int rel = tb - p.d[i].blk0;
  const int bx = rel % p.d[i].nbx, by = rel / p.d[i].nbx;
  const int r0 = by << 6, c0 = bx * p.d[i].cblk;
  #pragma unroll
  for (int it = 0; it < 2; ++it){
    int task = (it << 8) + tid;
    int r = task >> 3, c8 = (task & 7) << 3;
    if (f){
      const u16* pp = (const u16*)src + (size_t)(r0 + r) * srcStride + c0 + c8;
      u16x8 v = *reinterpret_cast<const u16x8*>(pp);
      #pragma unroll
      for (int j = 0; j < 8; ++j) tile[r][c8 + j] = v[j];
    } else {
      const float* pp = (const float*)src + (size_t)(r0 + r) * srcStride + c0 + c8;
      f4v a = reinterpret_cast<const f4v*>(pp)[0];
      f4v b = reinterpret_cast<const f4v*>(pp)[1];
      tile[r][c8+0]=f2bf(a.x); tile[r][c8+1]=f2bf(a.y); tile[r][c8+2]=f2bf(a.z); tile[r][c8+3]=f2bf(a.w);
      tile[r][c8+4]=f2bf(b.x); tile[r][c8+5]=f2bf(b.y); tile[r][c8+6]=f2bf(b.z); tile[r][c8+7]=f2bf(b.w);
    }
  }
  __syncthreads();
  #pragma unroll
  for (int it = 0; it < 2; ++it){
    int task = (it << 8) + tid;
    int rr = task >> 3, cc8 = (task & 7) << 3;
    u16x8 v;
    #pragma unroll
    for (int j = 0; j < 8; ++j) v[j] = tile[cc8 + j][rr];
    *reinterpret_cast<u16x8*>(dst + (size_t)((bx << 6) + rr) * dstStride + r0 + cc8) = v;
  }
}

// ---------------- w_c1T transposes (grid head, G13's dependency) + x-convert (tail;
// 2048 blocks x 4 uint2/thread; all early-return when input is already bf16).
__global__ void k_prep(const void* __restrict__ xsrc, u16* __restrict__ x_bf,
                       TPack p, const u16* __restrict__ cosr){
  __shared__ u16 tile[64][72];
  const int bid = blockIdx.x;
  const int tid = threadIdx.x;
  const int f = (cosr[0] == (u16)0x3F80u);
  if (bid < TBLK){
    do_transpose(tile, p, bid, tid, f);
    return;
  }
  if (f) return;                              // bf16 input: G13 reads x directly, skip copy
  const int base = ((bid - TBLK) * 256 + tid) * 4;   // 4 uint2 per thread; n4 = 2097152
  #pragma unroll
  for (int q = 0; q < 4; ++q){
    int id = base + q;
    f4v v = reinterpret_cast<const f4v*>(xsrc)[id];
    unsigned lo = (unsigned)f2bf(v.x) | ((unsigned)f2bf(v.y) << 16);
    unsigned hi = (unsigned)f2bf(v.z) | ((unsigned)f2bf(v.w) << 16);
    reinterpret_cast<uint2*>(x_bf)[id] = make_uint2(lo, hi);
  }
}

// ---------------- unified 128x128 GEMM: 256 thr / 4 waves (2x2), 64x64 per wave,
// LDS 64 KB -> 2 blocks/CU. Row-XOR swizzle via inverse-swizzled global_load_lds sources;
// counted vmcnt(8) pipeline; setprio around MFMA cluster. Two groups by N-tile index.
// alt-A: bf16 passthrough of unconverted input. vt: group cols >= 1024 -> vT transposed.
// Side paths (blocks with flat >= ngemm; EARLY-RETURN, safe per round-23/24 evidence):
//   sidemode 1 = RoPE elementwise (depends only on G13's xc; used in G2G4 launch)
//   sidemode 2 = weight transposes (depend only on inputs; used in G13 launch, fills tail)
__global__ __launch_bounds__(256, 2) void k_gemm(
    const u16* __restrict__ A0, int lda0, const u16* __restrict__ Bt0, int K0,
    u16* __restrict__ C0, int ldc0, float os0,
    const u16* __restrict__ A1, int lda1, const u16* __restrict__ Bt1, int K1,
    u16* __restrict__ C1, int ldc1, float os1,
    int ysplit, int swz, void* outp, const u16* __restrict__ cosr,
    const u16* __restrict__ alt0, const u16* __restrict__ alt1,
    u16* __restrict__ vt0, u16* __restrict__ vt1,
    const u16* __restrict__ ropeXc, const void* __restrict__ rcosp,
    const void* __restrict__ rsinp, u16* __restrict__ ropeK,
    u16* __restrict__ ropeQ, int* __restrict__ rticket,
    int ngemm, int sidemode, TPack tpp){
  __shared__ alignas(16) u16 lds[32768];   // 64 KB
  const int tid = threadIdx.x;
  const int flat = blockIdx.y * gridDim.x + blockIdx.x;

  if (sidemode && flat >= ngemm){
    const int tb = flat - ngemm;
    if (sidemode == 1){
      // ---- RoPE path (2048 trailing blocks; reads xc cols 2048..2175, stride 2304)
      if (tb == 0 && tid < 128) rticket[tid] = 0;    // ticket reset ahead of k_attn
      const int f2 = (((const u16*)rcosp)[0] == (u16)0x3F80u);
      int id = tb * 256 + tid;                       // exactly NROWS*128
      int row = id >> 7, c = id & 127;
      int t = row & (T_ - 1);
      int d = c & 63, i = d & 31;
      float cs, sn;
      if (f2){ cs = bf2f(((const u16*)rcosp)[t * 32 + i]); sn = bf2f(((const u16*)rsinp)[t * 32 + i]); }
      else   { cs = ((const float*)rcosp)[t * 32 + i];     sn = ((const float*)rsinp)[t * 32 + i]; }
      int base = c & 64;
      float t1 = bf2f(ropeXc[(size_t)row * 2304 + 2048 + base + i]);
      float t2 = bf2f(ropeXc[(size_t)row * 2304 + 2048 + base + 32 + i]);
      float v = (d < 32) ? (t1 * cs - t2 * sn) : (t2 * cs + t1 * sn);
      if (c >= 64) v *= 0.12753139626374414f;        // 1/sqrt(128)*log2(e) folded into q
      ((c < 64) ? ropeK : ropeQ)[(size_t)row * 64 + d] = f2bf(v);
    } else {
      // ---- weight-transpose path (1792 trailing blocks in the G13 launch)
      const int f2 = cosr ? (cosr[0] == (u16)0x3F80u) : 1;
      do_transpose(lds, tpp, tb, tid, f2);
    }
    return;
  }

  const int wid = tid >> 6, lane = tid & 63;
  const int wr = wid >> 1, wc = wid & 1;
  const int l16 = lane & 15, g = lane >> 4;
  int lin = flat;
  if (swz){
    const int q8 = ngemm >> 3;               // swizzle over gemm blocks only (ngemm%8==0)
    lin = (lin & 7) * q8 + (lin >> 3);       // bijective XCD chunking
  }
  const int m0 = (lin & 31) << 7;
  int nt = lin >> 5;
  const u16 *A, *Bt, *alt; u16 *C, *vtp; int lda, K, ldc; float oscale;
  if (nt < ysplit){ A = A0; lda = lda0; Bt = Bt0; K = K0; C = C0; ldc = ldc0; oscale = os0; alt = alt0; vtp = vt0; }
  else { nt -= ysplit; A = A1; lda = lda1; Bt = Bt1; K = K1; C = C1; ldc = ldc1; oscale = os1; alt = alt1; vtp = vt1; }
  const int f = cosr ? (cosr[0] == (u16)0x3F80u) : 1;
  if (alt && f) A = alt;                     // bf16 input: read source directly
  const int n0 = nt << 7;
  const size_t Kz = (size_t)K;
  const int nkt = K >> 6;

  auto STAGE = [&](int kt, int bufn){
    const int kb = kt << 6;
    #pragma unroll
    for (int q = 0; q < 8; ++q){
      const int ht = q >> 2;                 // 0 = A half, 1 = B half
      const int cq = ((q & 3) << 8) + tid;   // chunk 0..1023 within half
      const int Lb = cq << 4;                // byte in [128][128B] half-tile
      const int row = Lb >> 7;
      const int colb = (Lb & 127) ^ ((row & 7) << 4);   // inverse-swizzled source
      const u16* src = ht ? (Bt + (size_t)(n0 + row) * Kz + kb + (colb >> 1))
                          : (A  + (size_t)(m0 + row) * lda + kb + (colb >> 1));
      gld_lds16(src, &lds[bufn * 16384 + ht * 8192 + (cq << 3)]);
    }
  };

  f32x4 acc[4][4] = {};

  STAGE(0, 0);
  int buf = 0;

  for (int kt = 0; kt < nkt; ++kt){
    if (kt + 1 < nkt){ STAGE(kt + 1, buf ^ 1); vmwait8(); }   // waits tile-kt's 8 loads
    else vmwait0();
    barr();                                                    // staged tile visible to all
    bf16x8 af[2][4], bfr[2][4];
    #pragma unroll
    for (int ks = 0; ks < 2; ++ks){
      #pragma unroll
      for (int mi = 0; mi < 4; ++mi){
        int row = (wr << 6) + (mi << 4) + l16;
        int cb = ((ks << 6) + (g << 4)) ^ ((row & 7) << 4);
        af[ks][mi] = *reinterpret_cast<const bf16x8*>(&lds[buf * 16384 + (((row << 7) + cb) >> 1)]);
      }
      #pragma unroll
      for (int ni = 0; ni < 4; ++ni){
        int row = (wc << 6) + (ni << 4) + l16;
        int cb = ((ks << 6) + (g << 4)) ^ ((row & 7) << 4);
        bfr[ks][ni] = *reinterpret_cast<const bf16x8*>(&lds[buf * 16384 + 8192 + (((row << 7) + cb) >> 1)]);
      }
    }
    __builtin_amdgcn_s_setprio(1);
    #pragma unroll
    for (int ks = 0; ks < 2; ++ks)
      #pragma unroll
      for (int mi = 0; mi < 4; ++mi)
        #pragma unroll
        for (int ni = 0; ni < 4; ++ni)
          acc[mi][ni] = mfma16(af[ks][mi], bfr[ks][ni], acc[mi][ni]);
    __builtin_amdgcn_s_setprio(0);
    barr();                                  // reads done before next STAGE overwrites
    buf ^= 1;
  }

  const int r4 = g << 2;
  #pragma unroll
  for (int mi = 0; mi < 4; ++mi){
    int row = m0 + (wr << 6) + (mi << 4) + r4;
    #pragma unroll
    for (int ni = 0; ni < 4; ++ni){
      int col = n0 + (wc << 6) + (ni << 4) + l16;
      if (vtp && col >= 1024){
        // V quadrant: write transposed to vT[bh][d][t]; rows j are consecutive t.
        int hd = col - 1024;
        u16* dst = vtp + (((size_t)(((row >> 11) << 4) + (hd >> 7)) << 7) + (hd & 127)) * (size_t)T_ + (row & (T_ - 1));
        union { u16 u[4]; uint2 v; } pk;
        #pragma unroll
        for (int j = 0; j < 4; ++j) pk.u[j] = f2bf(acc[mi][ni][j] * oscale);
        *reinterpret_cast<uint2*>(dst) = pk.v;
        continue;
      }
      #pragma unroll
      for (int j = 0; j < 4; ++j){
        float v = acc[mi][ni][j] * oscale;
        if (outp){
          if (f) ((u16*)outp)[(size_t)(row + j) * ldc + col] = f2bf(v);
          else   ((float*)outp)[(size_t)(row + j) * ldc + col] = v;
        } else {
          C[(size_t)(row + j) * ldc + col] = f2bf(v);
        }
      }
    }
  }
}

// ---------------- causal flash attention: 128-row items, 8 waves x 16 rows (512 thr).
// Round-17 config (measured best): 256 workers (1 block/CU), per-XCD tickets,
// 64 items over 32 workers/partition = 2:1 heavy-first STEALING (1:1 maps regress --
// rounds 12 & 18). 64KB LDS double-buffer; setprio around MFMA clusters.
__global__ __launch_bounds__(512, 2) void k_attn(const u16* __restrict__ qP,
                                                 const u16* __restrict__ kvP,
                                                 const u16* __restrict__ vT,
                                                 const u16* __restrict__ krope,
                                                 const u16* __restrict__ qrope,
                                                 u16* __restrict__ aout,
                                                 int* __restrict__ ticket){
  __shared__ alignas(16) u16 smem[32768];   // 64 KB: 2 buffers x (K [64][128] + V [128][64])
  const int tid = threadIdx.x, wid = tid >> 6, lane = tid & 63;
  const int l16 = lane & 15, g = lane >> 4;
  const int lk = g << 3, r4 = g << 2;
  const int sw8 = (l16 & 7) << 3;
  const int xcd = blockIdx.x & 7;

  while (true){
    if (tid == 0) *(int*)&smem[0] = atomicAdd(&ticket[xcd << 4], 1);
    __syncthreads();
    const int it = *(const int*)&smem[0];
    __syncthreads();
    if (it >= 64) break;
    const int qt = 15 - (it >> 2);          // heavy-first within partition (128-row tiles)
    const int bh = (xcd << 2) + (it & 3), b = bh >> 4, h = bh & 15;
    const int q0 = qt << 7;
    const size_t bT = (size_t)b * T_;
    const u16* kvPb = kvP + bT * 1024 + (h << 6);
    const u16* krb  = krope + bT * 64;
    const u16* vTb  = vT + (size_t)bh * 128 * T_;
    const int qlo = q0 + (wid << 4);
    const int qhi = qlo + 15;
    const int nkv = (qt << 1) + 2;

    auto STAGE = [&](int buf, int k0){
      const int base = buf << 14;
      #pragma unroll
      for (int r = 0; r < 4; ++r){
        int c = (r << 9) + tid;              // 0..2047 chunks of 16B
        const u16* src;
        if (r < 2){
          int row = c >> 4, cc = c & 15;
          int ccx = (cc & 8) | ((cc & 7) ^ (row & 7));
          int col0 = ccx << 3;
          src = (col0 < 64) ? (kvPb + (size_t)(k0 + row) * 1024 + col0)
                            : (krb  + (size_t)(k0 + row) * 64 + (col0 - 64));
        } else {
          int cv = c - 1024;
          int row = cv >> 3, cc = cv & 7;
          int ccx = cc ^ (row & 7);
          src = vTb + (size_t)row * T_ + k0 + (ccx << 3);
        }
        gld_lds16(src, &smem[base + (c << 3)]);
      }
    };

    bf16x8 qf[4];
    {
      size_t grow = bT + qlo + l16;
      #pragma unroll
      for (int ks = 0; ks < 4; ++ks){
        int d = (ks << 5) + lk;
        const u16* src = (ks < 2) ? (qP + grow * 1024 + (h << 6) + d)
                                  : (qrope + grow * 64 + (d - 64));
        qf[ks] = *reinterpret_cast<const bf16x8*>(src);
      }
    }
    f32x4 o[8] = {};
    float m = -3e38f, l = 0.f;

    STAGE(0, 0);
    __syncthreads();
    int cur = 0;

    for (int kv = 0; kv < nkv; ++kv){
      const int k0 = kv << 6;
      if (kv + 1 < nkv) STAGE(cur ^ 1, (kv + 1) << 6);
      if (k0 <= qhi){
        const int kb = cur << 14;
        f32x4 s[4] = {};
        __builtin_amdgcn_s_setprio(1);
        #pragma unroll
        for (int ks = 0; ks < 4; ++ks){
          int colsw = ((ks << 5) + lk) ^ sw8;
          #pragma unroll
          for (int n = 0; n < 4; ++n){
            bf16x8 kf = *reinterpret_cast<const bf16x8*>(&smem[kb + ((n << 4) + l16) * 128 + colsw]);
            s[n] = mfma16(kf, qf[ks], s[n]);
          }
        }
        __builtin_amdgcn_s_setprio(0);
        if (k0 + 63 > qlo){                  // only the wave's diagonal tile needs masking
          const int tq = qlo + l16;
          #pragma unroll
          for (int n = 0; n < 4; ++n)
            #pragma unroll
            for (int j = 0; j < 4; ++j)
              s[n][j] = (k0 + (n << 4) + r4 + j <= tq) ? s[n][j] : -3e38f;
        }
        float mx;
        {
          float a0 = fmaxf(fmaxf(s[0][0], s[0][1]), fmaxf(s[0][2], s[0][3]));
          float a1 = fmaxf(fmaxf(s[1][0], s[1][1]), fmaxf(s[1][2], s[1][3]));
          float a2 = fmaxf(fmaxf(s[2][0], s[2][1]), fmaxf(s[2][2], s[2][3]));
          float a3 = fmaxf(fmaxf(s[3][0], s[3][1]), fmaxf(s[3][2], s[3][3]));
          mx = fmaxf(fmaxf(a0, a1), fmaxf(a2, a3));
          mx = fmaxf(mx, __shfl_xor(mx, 16));
          mx = fmaxf(mx, __shfl_xor(mx, 32));
        }
        if (__ballot(mx > m + 8.f)){
          float mnew = fmaxf(m, mx);
          float alpha = exp2f(m - mnew);
          m = mnew; l *= alpha;
          #pragma unroll
          for (int j = 0; j < 4; ++j){
            float av = __shfl(alpha, r4 + j);
            #pragma unroll
            for (int db = 0; db < 8; ++db) o[db][j] *= av;
          }
        }
        unsigned w[4][2];
        float rs = 0.f;
        #pragma unroll
        for (int n = 0; n < 4; ++n)
          #pragma unroll
          for (int jh = 0; jh < 2; ++jh){
            float p0 = exp2f(s[n][2*jh]     - m);
            float p1 = exp2f(s[n][2*jh + 1] - m);
            rs += p0 + p1;
            w[n][jh] = cvt_pk_bf16(p0, p1);
          }
        rs += __shfl_xor(rs, 16);
        rs += __shfl_xor(rs, 32);
        l += rs;
        const int srcA = l16 + ((g & 1) << 5);
        const int srcB = srcA + 16;
        const bool hi = (g >= 2);
        bf16x8 pa[2];
        #pragma unroll
        for (int ks2 = 0; ks2 < 2; ++ks2){
          unsigned a0 = __shfl((int)w[2*ks2][0],     srcA);
          unsigned b0 = __shfl((int)w[2*ks2 + 1][0], srcA);
          unsigned a1 = __shfl((int)w[2*ks2][1],     srcA);
          unsigned b1 = __shfl((int)w[2*ks2 + 1][1], srcA);
          unsigned a2 = __shfl((int)w[2*ks2][0],     srcB);
          unsigned b2 = __shfl((int)w[2*ks2 + 1][0], srcB);
          unsigned a3 = __shfl((int)w[2*ks2][1],     srcB);
          unsigned b3 = __shfl((int)w[2*ks2 + 1][1], srcB);
          union { unsigned u[4]; bf16x8 v; } pk;
          pk.u[0] = hi ? b0 : a0;
          pk.u[1] = hi ? b1 : a1;
          pk.u[2] = hi ? b2 : a2;
          pk.u[3] = hi ? b3 : a3;
          pa[ks2] = pk.v;
        }
        __builtin_amdgcn_s_setprio(1);
        #pragma unroll
        for (int ks2 = 0; ks2 < 2; ++ks2){
          int colsw = ((ks2 << 5) + lk) ^ sw8;
          #pragma unroll
          for (int db = 0; db < 8; ++db){
            bf16x8 vb = *reinterpret_cast<const bf16x8*>(&smem[(cur << 14) + 8192 + ((db << 4) + l16) * 64 + colsw]);
            o[db] = mfma16(pa[ks2], vb, o[db]);
          }
        }
        __builtin_amdgcn_s_setprio(0);
      }
      __syncthreads();                      // drains prefetch; reads done before buffer reuse
      cur ^= 1;
    }
    #pragma unroll
    for (int j = 0; j < 4; ++j){
      float lv = __shfl(l, r4 + j);
      float rinv = 1.f / lv;
      const int tq = qlo + r4 + j;
      u16* dst = aout + (bT + tq) * 2048 + (h << 7) + l16;
      #pragma unroll
      for (int db = 0; db < 8; ++db)
        dst[db << 4] = f2bf(o[db][j] * rinv);
    }
  }
}

extern "C" void kernel_launch(void* const* d_in, const int* in_sizes, int n_in,
                              void* d_out, int out_size, void* d_ws, size_t ws_size,
                              hipStream_t stream){
  const void* x       = d_in[0];
  const void* cosp    = d_in[1];
  const void* sinp    = d_in[2];
  const void* w_kv    = d_in[3];
  const void* w_kdec  = d_in[4];
  const void* w_vdec  = d_in[5];
  const void* w_qc    = d_in[6];
  const void* w_qdec  = d_in[7];
  const void* w_krope = d_in[8];
  const void* w_qrope = d_in[9];
  const void* w_o     = d_in[10];

  char* ws = (char*)d_ws;
  size_t off = 0;
  auto alloc = [&](size_t bytes){ void* p = ws + off; off += (bytes + 255) & ~(size_t)255; return p; };
  int* ticket   = (int*)alloc(1024);                         // 8 tickets, stride 16 ints
  u16* x_bf     = (u16*)alloc((size_t)NROWS * DIM_ * 2);
  u16* w_c1T    = (u16*)alloc((size_t)2304 * DIM_ * 2);      // [kvT(512); qcT(1536); kropeT(64); qropeT(64); pad] x 2048
  u16* w_kvdT   = (u16*)alloc((size_t)3072 * DC_ * 2);       // [kdecPackedT(1024); vdecT(2048)] x 512
  u16* w_qdPT   = (u16*)alloc((size_t)1024 * DCQ_ * 2);      // packed qdecT (1024 x 1536)
  u16* w_oT     = (u16*)alloc((size_t)DIM_ * DIM_ * 2);
  u16* xc       = (u16*)alloc((size_t)NROWS * 2304 * 2);     // [c_kv(512) | c_q(1536) | ropes(128) | pad]
  u16* qP       = (u16*)alloc((size_t)NROWS * 1024 * 2);     // packed q decode (pre-scaled)
  u16* kvP      = (u16*)alloc((size_t)NROWS * 1024 * 2);     // packed K only (stride 1024)
  u16* krope    = (u16*)alloc((size_t)NROWS * 64 * 2);
  u16* qrope    = (u16*)alloc((size_t)NROWS * 64 * 2);       // pre-scaled
  u16* vT       = (u16*)alloc((size_t)32 * 128 * T_ * 2);    // [bh][d][t], written by G2 epilogue
  u16* aout     = (u16*)alloc((size_t)NROWS * DIM_ * 2);
  (void)in_sizes; (void)n_in; (void)out_size; (void)ws_size;

  const float SC2 = 0.12753139626374414f;   // 1/sqrt(128) * log2(e)
  const u16* cosr = (const u16*)cosp;

  // prep: w_c1T transposes FIRST (G13's dependency), then x-convert (2048 x 4-wide blocks)
  TPack tp = {};
  tp.d[0] = { w_kv,    w_c1T,                        512,  2048, 64,  8,  0    };
  tp.d[1] = { w_qc,    w_c1T + (size_t)512 * 2048,   1536, 2048, 64,  24, 256  };
  tp.d[2] = { w_krope, w_c1T + (size_t)2048 * 2048,  64,   2048, 64,  1,  1024 };
  tp.d[3] = { w_qrope, w_c1T + (size_t)2112 * 2048,  64,   2048, 64,  1,  1056 };
  tp.d[4] = { nullptr, nullptr, 0, 0, 0, 1, 1 << 30 };
  tp.d[5] = { nullptr, nullptr, 0, 0, 0, 1, 1 << 30 };
  tp.d[6] = { nullptr, nullptr, 0, 0, 0, 1, 1 << 30 };
  tp.d[7] = { nullptr, nullptr, 0, 0, 0, 1, 1 << 30 };
  hipLaunchKernelGGL(k_prep, dim3(TBLK + CONVBLK), dim3(256), 0, stream, x, x_bf, tp, cosr);

  // decode/output-weight transposes: side blocks of the G13 launch (fill its tail round)
  TPack ts = {};
  ts.d[0] = { w_kdec, w_kvdT,                       2048, 512,  128, 16, 0    };
  ts.d[1] = { w_vdec, w_kvdT + (size_t)1024 * 512,  2048, 512,  64,  32, 128  };
  ts.d[2] = { w_qdec, w_qdPT,                       2048, 1536, 128, 16, 384  };
  ts.d[3] = { w_o,    w_oT,                         2048, 2048, 64,  32, 768  };
  ts.d[4] = { nullptr, nullptr, 0, 0, 0, 1, 1 << 30 };
  ts.d[5] = { nullptr, nullptr, 0, 0, 0, 1, 1 << 30 };
  ts.d[6] = { nullptr, nullptr, 0, 0, 0, 1, 1 << 30 };
  ts.d[7] = { nullptr, nullptr, 0, 0, 0, 1, 1 << 30 };
  TPack tz = {};

  // G13: xc = x @ [w_kv | w_qc | rope-pre], 544 gemm blocks (XCD-swizzled over ngemm=544)
  // + 1792 transpose side blocks = 2336 total. A straight from x when bf16.
  hipLaunchKernelGGL(k_gemm, dim3(2336, 1), dim3(256), 0, stream,
                     x_bf, DIM_, w_c1T, DIM_, xc, 2304, 1.0f,
                     x_bf, DIM_, w_c1T, DIM_, xc, 2304, 1.0f,
                     17, 1, (void*)nullptr, cosr,
                     (const u16*)x, (const u16*)x,
                     (u16*)nullptr, (u16*)nullptr,
                     (const u16*)nullptr, (const void*)nullptr, (const void*)nullptr,
                     (u16*)nullptr, (u16*)nullptr, (int*)nullptr,
                     544, 2, ts);
  // G4 + G2 + RoPE in ONE launch (1024 gemm blocks + 2048 rope blocks):
  //   flat<256:       qP = xc[:, 512:2048] @ w_qdecP  (K=1536, heavy group first)
  //   256<=flat<1024: K -> kvP (cols<1024); V -> vT direct transposed (cols>=1024)
  //   flat>=1024:     RoPE from xc cols 2048.. (block 1024 resets tickets)
  hipLaunchKernelGGL(k_gemm, dim3(3072, 1), dim3(256), 0, stream,
                     xc + 512, 2304, w_qdPT, DCQ_, qP, 1024, SC2,
                     xc, 2304, w_kvdT, DC_, kvP, 1024, 1.0f,
                     8, 0, (void*)nullptr, (const u16*)nullptr,
                     (const u16*)nullptr, (const u16*)nullptr,
                     (u16*)nullptr, vT,
                     xc, cosp, sinp, krope, qrope, ticket,
                     1024, 1, tz);
  // attention (256 workers x 8 waves, 128-row items, 2:1 stealing, XCD-partitioned tickets)
  hipLaunchKernelGGL(k_attn, dim3(256), dim3(512), 0, stream,
                     qP, kvP, vT, krope, qrope, aout, ticket);
  // G5: out = aout @ w_o  (4096 x 2048, K=2048) -> (32,16) = 512 blocks = 2/CU, XCD-chunked
  hipLaunchKernelGGL(k_gemm, dim3(32, 16), dim3(256), 0, stream,
                     aout, DIM_, w_oT, DIM_, (u16*)nullptr, DIM_, 1.0f,
                     aout, DIM_, w_oT, DIM_, (u16*)nullptr, DIM_, 1.0f,
                     16, 1, d_out, cosr,
                     (const u16*)nullptr, (const u16*)nullptr,
                     (u16*)nullptr, (u16*)nullptr,
                     (const u16*)nullptr, (const void*)nullptr, (const void*)nullptr,
                     (u16*)nullptr, (u16*)nullptr, (int*)nullptr,
                     512, 0, tz);
}

// Round 26
// 228.183 us; speedup vs baseline: 1.1075x; 1.0071x over previous
//
#include <hip/hip_runtime.h>
#include <stdint.h>
#include <math.h>

#define B_    2
#define T_    2048
#define DIM_  2048
#define H_    16
#define DC_   512
#define DCQ_  1536
#define NROWS (B_*T_)   // 4096

typedef unsigned short u16;
typedef __attribute__((ext_vector_type(8))) __bf16 bf16x8;
typedef __attribute__((ext_vector_type(4))) float  f32x4;
typedef __attribute__((ext_vector_type(8))) unsigned short u16x8;
typedef __attribute__((ext_vector_type(4))) float  f4v;

__device__ __forceinline__ u16 f2bf(float f){
  unsigned u = __float_as_uint(f);
  u += 0x7FFFu + ((u >> 16) & 1u);   // RNE
  return (u16)(u >> 16);
}
__device__ __forceinline__ float bf2f(u16 h){ return __uint_as_float(((unsigned)h) << 16); }

__device__ __forceinline__ unsigned cvt_pk_bf16(float lo, float hi){
  unsigned r;
  asm("v_cvt_pk_bf16_f32 %0, %1, %2" : "=v"(r) : "v"(lo), "v"(hi));
  return r;
}

// async global->LDS, 16B per lane; LDS dest = wave-uniform base + lane*16.
__device__ __forceinline__ void gld_lds16(const void* g, void* l){
  auto gp = reinterpret_cast<__attribute__((address_space(1))) unsigned int*>(
      reinterpret_cast<uintptr_t>(g));
  auto lp = reinterpret_cast<__attribute__((address_space(3))) unsigned int*>(
      reinterpret_cast<uintptr_t>(l));
  __builtin_amdgcn_global_load_lds(gp, lp, 16, 0, 0);
}

__device__ __forceinline__ f32x4 mfma16(bf16x8 a, bf16x8 b, f32x4 c){
  return __builtin_amdgcn_mfma_f32_16x16x32_bf16(a, b, c, 0, 0, 0);
}

__device__ __forceinline__ void vmwait0(){ asm volatile("s_waitcnt vmcnt(0)" ::: "memory"); }
__device__ __forceinline__ void vmwait8(){ asm volatile("s_waitcnt vmcnt(8)" ::: "memory"); }
__device__ __forceinline__ void barr(){ asm volatile("s_barrier" ::: "memory"); }

// dtype flag: cos[0,0]==1.0 -> bf16 u16[0]=0x3F80, fp32 u16[0]=0x0000.

struct TDesc { const void* src; u16* dst; int srcStride, dstStride, cblk, nbx, blk0; };
struct TPack { TDesc d[8]; };
#define TBLK 1088
#define CONVBLK 2048

// transpose one 64x64 tile (shared by k_prep and k_gemm side path)
__device__ __forceinline__ void do_transpose(void* ldsbuf, const TPack& p, int tb,
                                             int tid, int f){
  u16 (*tile)[72] = reinterpret_cast<u16(*)[72]>(ldsbuf);
  int i = 0;
  #pragma unroll
  for (int k = 1; k < 8; ++k) if (tb >= p.d[k].blk0) i = k;
  const void* src = p.d[i].src;
  u16* dst = p.d[i].dst;
  const int srcStride = p.d[i].srcStride, dstStride = p.d[i].dstStride;
  const int rel = tb - p.d[i].blk0;
  const int bx = rel % p.d[i].nbx, by = rel / p.d[i].nbx;
  const int r0 = by << 6, c0 = bx * p.d[i].cblk;
  #pragma unroll
  for (int it = 0; it < 2; ++it){
    int task = (it << 8) + tid;
    int r = task >> 3, c8 = (task & 7) << 3;
    if (f){
      const u16* pp = (const u16*)src + (size_t)(r0 + r) * srcStride + c0 + c8;
      u16x8 v = *reinterpret_cast<const u16x8*>(pp);
      #pragma unroll
      for (int j = 0; j < 8; ++j) tile[r][c8 + j] = v[j];
    } else {
      const float* pp = (const float*)src + (size_t)(r0 + r) * srcStride + c0 + c8;
      f4v a = reinterpret_cast<const f4v*>(pp)[0];
      f4v b = reinterpret_cast<const f4v*>(pp)[1];
      tile[r][c8+0]=f2bf(a.x); tile[r][c8+1]=f2bf(a.y); tile[r][c8+2]=f2bf(a.z); tile[r][c8+3]=f2bf(a.w);
      tile[r][c8+4]=f2bf(b.x); tile[r][c8+5]=f2bf(b.y); tile[r][c8+6]=f2bf(b.z); tile[r][c8+7]=f2bf(b.w);
    }
  }
  __syncthreads();
  #pragma unroll
  for (int it = 0; it < 2; ++it){
    int task = (it << 8) + tid;
    int rr = task >> 3, cc8 = (task & 7) << 3;
    u16x8 v;
    #pragma unroll
    for (int j = 0; j < 8; ++j) v[j] = tile[cc8 + j][rr];
    *reinterpret_cast<u16x8*>(dst + (size_t)((bx << 6) + rr) * dstStride + r0 + cc8) = v;
  }
}

// ---------------- w_c1T transposes (grid head, G13's dependency) + x-convert (tail;
// 2048 blocks x 4 uint2/thread; all early-return when input is already bf16).
__global__ void k_prep(const void* __restrict__ xsrc, u16* __restrict__ x_bf,
                       TPack p, const u16* __restrict__ cosr){
  __shared__ u16 tile[64][72];
  const int bid = blockIdx.x;
  const int tid = threadIdx.x;
  const int f = (cosr[0] == (u16)0x3F80u);
  if (bid < TBLK){
    do_transpose(tile, p, bid, tid, f);
    return;
  }
  if (f) return;                              // bf16 input: G13 reads x directly, skip copy
  const int base = ((bid - TBLK) * 256 + tid) * 4;   // 4 uint2 per thread; n4 = 2097152
  #pragma unroll
  for (int q = 0; q < 4; ++q){
    int id = base + q;
    f4v v = reinterpret_cast<const f4v*>(xsrc)[id];
    unsigned lo = (unsigned)f2bf(v.x) | ((unsigned)f2bf(v.y) << 16);
    unsigned hi = (unsigned)f2bf(v.z) | ((unsigned)f2bf(v.w) << 16);
    reinterpret_cast<uint2*>(x_bf)[id] = make_uint2(lo, hi);
  }
}

// ---------------- unified 128x128 GEMM: 256 thr / 4 waves (2x2), 64x64 per wave,
// LDS 64 KB -> 2 blocks/CU. Row-XOR swizzle via inverse-swizzled global_load_lds sources;
// counted vmcnt(8) pipeline; setprio around MFMA cluster. Two groups by N-tile index.
// alt-A: bf16 passthrough of unconverted input. vt: group cols >= 1024 -> vT transposed.
// Side paths (blocks with flat >= ngemm; EARLY-RETURN, safe per round-23/24 evidence):
//   sidemode 1 = RoPE elementwise (depends only on G13's xc; used in G2G4 launch)
//   sidemode 2 = weight transposes (depend only on inputs; used in G13 launch, fills tail)
__global__ __launch_bounds__(256, 2) void k_gemm(
    const u16* __restrict__ A0, int lda0, const u16* __restrict__ Bt0, int K0,
    u16* __restrict__ C0, int ldc0, float os0,
    const u16* __restrict__ A1, int lda1, const u16* __restrict__ Bt1, int K1,
    u16* __restrict__ C1, int ldc1, float os1,
    int ysplit, int swz, void* outp, const u16* __restrict__ cosr,
    const u16* __restrict__ alt0, const u16* __restrict__ alt1,
    u16* __restrict__ vt0, u16* __restrict__ vt1,
    const u16* __restrict__ ropeXc, const void* __restrict__ rcosp,
    const void* __restrict__ rsinp, u16* __restrict__ ropeK,
    u16* __restrict__ ropeQ, int* __restrict__ rticket,
    int ngemm, int sidemode, TPack tpp){
  __shared__ alignas(16) u16 lds[32768];   // 64 KB
  const int tid = threadIdx.x;
  const int flat = blockIdx.y * gridDim.x + blockIdx.x;

  if (sidemode && flat >= ngemm){
    const int tb = flat - ngemm;
    if (sidemode == 1){
      // ---- RoPE path (2048 trailing blocks; reads xc cols 2048..2175, stride 2304)
      if (tb == 0 && tid < 128) rticket[tid] = 0;    // ticket reset ahead of k_attn
      const int f2 = (((const u16*)rcosp)[0] == (u16)0x3F80u);
      int id = tb * 256 + tid;                       // exactly NROWS*128
      int row = id >> 7, c = id & 127;
      int t = row & (T_ - 1);
      int d = c & 63, i = d & 31;
      float cs, sn;
      if (f2){ cs = bf2f(((const u16*)rcosp)[t * 32 + i]); sn = bf2f(((const u16*)rsinp)[t * 32 + i]); }
      else   { cs = ((const float*)rcosp)[t * 32 + i];     sn = ((const float*)rsinp)[t * 32 + i]; }
      int base = c & 64;
      float t1 = bf2f(ropeXc[(size_t)row * 2304 + 2048 + base + i]);
      float t2 = bf2f(ropeXc[(size_t)row * 2304 + 2048 + base + 32 + i]);
      float v = (d < 32) ? (t1 * cs - t2 * sn) : (t2 * cs + t1 * sn);
      if (c >= 64) v *= 0.12753139626374414f;        // 1/sqrt(128)*log2(e) folded into q
      ((c < 64) ? ropeK : ropeQ)[(size_t)row * 64 + d] = f2bf(v);
    } else {
      // ---- weight-transpose path (1792 trailing blocks in the G13 launch)
      const int f2 = cosr ? (cosr[0] == (u16)0x3F80u) : 1;
      do_transpose(lds, tpp, tb, tid, f2);
    }
    return;
  }

  const int wid = tid >> 6, lane = tid & 63;
  const int wr = wid >> 1, wc = wid & 1;
  const int l16 = lane & 15, g = lane >> 4;
  int lin = flat;
  if (swz){
    const int q8 = ngemm >> 3;               // swizzle over gemm blocks only (ngemm%8==0)
    lin = (lin & 7) * q8 + (lin >> 3);       // bijective XCD chunking
  }
  const int m0 = (lin & 31) << 7;
  int nt = lin >> 5;
  const u16 *A, *Bt, *alt; u16 *C, *vtp; int lda, K, ldc; float oscale;
  if (nt < ysplit){ A = A0; lda = lda0; Bt = Bt0; K = K0; C = C0; ldc = ldc0; oscale = os0; alt = alt0; vtp = vt0; }
  else { nt -= ysplit; A = A1; lda = lda1; Bt = Bt1; K = K1; C = C1; ldc = ldc1; oscale = os1; alt = alt1; vtp = vt1; }
  const int f = cosr ? (cosr[0] == (u16)0x3F80u) : 1;
  if (alt && f) A = alt;                     // bf16 input: read source directly
  const int n0 = nt << 7;
  const size_t Kz = (size_t)K;
  const int nkt = K >> 6;

  auto STAGE = [&](int kt, int bufn){
    const int kb = kt << 6;
    #pragma unroll
    for (int q = 0; q < 8; ++q){
      const int ht = q >> 2;                 // 0 = A half, 1 = B half
      const int cq = ((q & 3) << 8) + tid;   // chunk 0..1023 within half
      const int Lb = cq << 4;                // byte in [128][128B] half-tile
      const int row = Lb >> 7;
      const int colb = (Lb & 127) ^ ((row & 7) << 4);   // inverse-swizzled source
      const u16* src = ht ? (Bt + (size_t)(n0 + row) * Kz + kb + (colb >> 1))
                          : (A  + (size_t)(m0 + row) * lda + kb + (colb >> 1));
      gld_lds16(src, &lds[bufn * 16384 + ht * 8192 + (cq << 3)]);
    }
  };

  f32x4 acc[4][4] = {};

  STAGE(0, 0);
  int buf = 0;

  for (int kt = 0; kt < nkt; ++kt){
    if (kt + 1 < nkt){ STAGE(kt + 1, buf ^ 1); vmwait8(); }   // waits tile-kt's 8 loads
    else vmwait0();
    barr();                                                    // staged tile visible to all
    bf16x8 af[2][4], bfr[2][4];
    #pragma unroll
    for (int ks = 0; ks < 2; ++ks){
      #pragma unroll
      for (int mi = 0; mi < 4; ++mi){
        int row = (wr << 6) + (mi << 4) + l16;
        int cb = ((ks << 6) + (g << 4)) ^ ((row & 7) << 4);
        af[ks][mi] = *reinterpret_cast<const bf16x8*>(&lds[buf * 16384 + (((row << 7) + cb) >> 1)]);
      }
      #pragma unroll
      for (int ni = 0; ni < 4; ++ni){
        int row = (wc << 6) + (ni << 4) + l16;
        int cb = ((ks << 6) + (g << 4)) ^ ((row & 7) << 4);
        bfr[ks][ni] = *reinterpret_cast<const bf16x8*>(&lds[buf * 16384 + 8192 + (((row << 7) + cb) >> 1)]);
      }
    }
    __builtin_amdgcn_s_setprio(1);
    #pragma unroll
    for (int ks = 0; ks < 2; ++ks)
      #pragma unroll
      for (int mi = 0; mi < 4; ++mi)
        #pragma unroll
        for (int ni = 0; ni < 4; ++ni)
          acc[mi][ni] = mfma16(af[ks][mi], bfr[ks][ni], acc[mi][ni]);
    __builtin_amdgcn_s_setprio(0);
    barr();                                  // reads done before next STAGE overwrites
    buf ^= 1;
  }

  const int r4 = g << 2;
  #pragma unroll
  for (int mi = 0; mi < 4; ++mi){
    int row = m0 + (wr << 6) + (mi << 4) + r4;
    #pragma unroll
    for (int ni = 0; ni < 4; ++ni){
      int col = n0 + (wc << 6) + (ni << 4) + l16;
      if (vtp && col >= 1024){
        // V quadrant: write transposed to vT[bh][d][t]; rows j are consecutive t.
        int hd = col - 1024;
        u16* dst = vtp + (((size_t)(((row >> 11) << 4) + (hd >> 7)) << 7) + (hd & 127)) * (size_t)T_ + (row & (T_ - 1));
        union { u16 u[4]; uint2 v; } pk;
        #pragma unroll
        for (int j = 0; j < 4; ++j) pk.u[j] = f2bf(acc[mi][ni][j] * oscale);
        *reinterpret_cast<uint2*>(dst) = pk.v;
        continue;
      }
      #pragma unroll
      for (int j = 0; j < 4; ++j){
        float v = acc[mi][ni][j] * oscale;
        if (outp){
          if (f) ((u16*)outp)[(size_t)(row + j) * ldc + col] = f2bf(v);
          else   ((float*)outp)[(size_t)(row + j) * ldc + col] = v;
        } else {
          C[(size_t)(row + j) * ldc + col] = f2bf(v);
        }
      }
    }
  }
}

// ---------------- causal flash attention: 128-row items, 8 waves x 16 rows (512 thr).
// KVBLK=128: per buffer {K[128][128] + V[128][128]} = 64 KB, double-buffered = 128 KB LDS
// (free: grid is 1 block/CU by design, 160 KB available, 32 KB margin). Halves barriers,
// STAGE calls, and softmax fixed costs per KV row vs KVBLK=64. 256 workers, per-XCD
// tickets, 64 items over 32 workers = 2:1 heavy-first stealing (1:1 regresses, r12/r18).
__global__ __launch_bounds__(512, 2) void k_attn(const u16* __restrict__ qP,
                                                 const u16* __restrict__ kvP,
                                                 const u16* __restrict__ vT,
                                                 const u16* __restrict__ krope,
                                                 const u16* __restrict__ qrope,
                                                 u16* __restrict__ aout,
                                                 int* __restrict__ ticket){
  __shared__ alignas(16) u16 smem[65536];   // 128 KB: 2 buffers x (K [128][128] + V [128][128])
  const int tid = threadIdx.x, wid = tid >> 6, lane = tid & 63;
  const int l16 = lane & 15, g = lane >> 4;
  const int lk = g << 3, r4 = g << 2;
  const int sw8 = (l16 & 7) << 3;
  const int xcd = blockIdx.x & 7;

  while (true){
    if (tid == 0) *(int*)&smem[0] = atomicAdd(&ticket[xcd << 4], 1);
    __syncthreads();
    const int it = *(const int*)&smem[0];
    __syncthreads();
    if (it >= 64) break;
    const int qt = 15 - (it >> 2);          // heavy-first within partition (128-row tiles)
    const int bh = (xcd << 2) + (it & 3), b = bh >> 4, h = bh & 15;
    const int q0 = qt << 7;
    const size_t bT = (size_t)b * T_;
    const u16* kvPb = kvP + bT * 1024 + (h << 6);
    const u16* krb  = krope + bT * 64;
    const u16* vTb  = vT + (size_t)bh * 128 * T_;
    const int qlo = q0 + (wid << 4);
    const int nkv = qt + 1;                 // 128-row KV tiles

    auto STAGE = [&](int buf, int k0){
      const int base = buf << 15;           // u16 idx; 32768 u16 (64 KB) per buffer
      #pragma unroll
      for (int r = 0; r < 8; ++r){
        int c = (r << 9) + tid;             // 0..4095 chunks of 16B
        const u16* src;
        if (c < 2048){
          // K tile [128 rows][128 cols]: cols 0-63 packed kdec, 64-127 krope
          int row = c >> 4, cc = c & 15;
          int ccx = (cc & 8) | ((cc & 7) ^ (row & 7));
          int col0 = ccx << 3;
          src = (col0 < 64) ? (kvPb + (size_t)(k0 + row) * 1024 + col0)
                            : (krb  + (size_t)(k0 + row) * 64 + (col0 - 64));
        } else {
          // V tile [128 d][128 t] from vT[bh][d][t]
          int cv = c - 2048;
          int row = cv >> 4, cc = cv & 15;
          int ccx = (cc & 8) | ((cc & 7) ^ (row & 7));
          src = vTb + (size_t)row * T_ + k0 + (ccx << 3);
        }
        gld_lds16(src, &smem[base + (c << 3)]);
      }
    };

    bf16x8 qf[4];
    {
      size_t grow = bT + qlo + l16;
      #pragma unroll
      for (int ks = 0; ks < 4; ++ks){
        int d = (ks << 5) + lk;
        const u16* src = (ks < 2) ? (qP + grow * 1024 + (h << 6) + d)
                                  : (qrope + grow * 64 + (d - 64));
        qf[ks] = *reinterpret_cast<const bf16x8*>(src);
      }
    }
    f32x4 o[8] = {};
    float m = -3e38f, l = 0.f;

    STAGE(0, 0);
    __syncthreads();
    int cur = 0;

    for (int kv = 0; kv < nkv; ++kv){
      const int k0 = kv << 7;
      if (kv + 1 < nkv) STAGE(cur ^ 1, (kv + 1) << 7);
      const int kb = cur << 15;
      // ---- S^T = K Q^T : s[n][j] = S[k0 + 16n + r4 + j][q = qlo + l16]
      f32x4 s[8] = {};
      __builtin_amdgcn_s_setprio(1);
      #pragma unroll
      for (int ks = 0; ks < 4; ++ks){
        int colsw = ((ks << 5) + lk) ^ sw8;
        #pragma unroll
        for (int n = 0; n < 8; ++n){
          bf16x8 kf = *reinterpret_cast<const bf16x8*>(&smem[kb + ((n << 4) + l16) * 128 + colsw]);
          s[n] = mfma16(kf, qf[ks], s[n]);
        }
      }
      __builtin_amdgcn_s_setprio(0);
      if (k0 + 127 > qlo){                  // only the final (diagonal) tile needs masking
        const int tq = qlo + l16;
        #pragma unroll
        for (int n = 0; n < 8; ++n)
          #pragma unroll
          for (int j = 0; j < 4; ++j)
            s[n][j] = (k0 + (n << 4) + r4 + j <= tq) ? s[n][j] : -3e38f;
      }
      float mx;
      {
        float a0 = fmaxf(fmaxf(s[0][0], s[0][1]), fmaxf(s[0][2], s[0][3]));
        float a1 = fmaxf(fmaxf(s[1][0], s[1][1]), fmaxf(s[1][2], s[1][3]));
        float a2 = fmaxf(fmaxf(s[2][0], s[2][1]), fmaxf(s[2][2], s[2][3]));
        float a3 = fmaxf(fmaxf(s[3][0], s[3][1]), fmaxf(s[3][2], s[3][3]));
        float a4 = fmaxf(fmaxf(s[4][0], s[4][1]), fmaxf(s[4][2], s[4][3]));
        float a5 = fmaxf(fmaxf(s[5][0], s[5][1]), fmaxf(s[5][2], s[5][3]));
        float a6 = fmaxf(fmaxf(s[6][0], s[6][1]), fmaxf(s[6][2], s[6][3]));
        float a7 = fmaxf(fmaxf(s[7][0], s[7][1]), fmaxf(s[7][2], s[7][3]));
        mx = fmaxf(fmaxf(fmaxf(a0, a1), fmaxf(a2, a3)),
                   fmaxf(fmaxf(a4, a5), fmaxf(a6, a7)));
        mx = fmaxf(mx, __shfl_xor(mx, 16));
        mx = fmaxf(mx, __shfl_xor(mx, 32));
      }
      if (__ballot(mx > m + 8.f)){
        float mnew = fmaxf(m, mx);
        float alpha = exp2f(m - mnew);
        m = mnew; l *= alpha;
        #pragma unroll
        for (int j = 0; j < 4; ++j){
          float av = __shfl(alpha, r4 + j);
          #pragma unroll
          for (int db = 0; db < 8; ++db) o[db][j] *= av;
        }
      }
      unsigned w[8][2];
      float rs = 0.f;
      #pragma unroll
      for (int n = 0; n < 8; ++n)
        #pragma unroll
        for (int jh = 0; jh < 2; ++jh){
          float p0 = exp2f(s[n][2*jh]     - m);
          float p1 = exp2f(s[n][2*jh + 1] - m);
          rs += p0 + p1;
          w[n][jh] = cvt_pk_bf16(p0, p1);
        }
      rs += __shfl_xor(rs, 16);
      rs += __shfl_xor(rs, 32);
      l += rs;
      const int srcA = l16 + ((g & 1) << 5);
      const int srcB = srcA + 16;
      const bool hi = (g >= 2);
      bf16x8 pa[4];
      #pragma unroll
      for (int ks2 = 0; ks2 < 4; ++ks2){
        unsigned a0 = __shfl((int)w[2*ks2][0],     srcA);
        unsigned b0 = __shfl((int)w[2*ks2 + 1][0], srcA);
        unsigned a1 = __shfl((int)w[2*ks2][1],     srcA);
        unsigned b1 = __shfl((int)w[2*ks2 + 1][1], srcA);
        unsigned a2 = __shfl((int)w[2*ks2][0],     srcB);
        unsigned b2 = __shfl((int)w[2*ks2 + 1][0], srcB);
        unsigned a3 = __shfl((int)w[2*ks2][1],     srcB);
        unsigned b3 = __shfl((int)w[2*ks2 + 1][1], srcB);
        union { unsigned u[4]; bf16x8 v; } pk;
        pk.u[0] = hi ? b0 : a0;
        pk.u[1] = hi ? b1 : a1;
        pk.u[2] = hi ? b2 : a2;
        pk.u[3] = hi ? b3 : a3;
        pa[ks2] = pk.v;
      }
      __builtin_amdgcn_s_setprio(1);
      #pragma unroll
      for (int ks2 = 0; ks2 < 4; ++ks2){
        int colsw = ((ks2 << 5) + lk) ^ sw8;
        #pragma unroll
        for (int db = 0; db < 8; ++db){
          bf16x8 vb = *reinterpret_cast<const bf16x8*>(&smem[kb + 16384 + ((db << 4) + l16) * 128 + colsw]);
          o[db] = mfma16(pa[ks2], vb, o[db]);
        }
      }
      __builtin_amdgcn_s_setprio(0);
      __syncthreads();                      // drains prefetch; reads done before buffer reuse
      cur ^= 1;
    }
    #pragma unroll
    for (int j = 0; j < 4; ++j){
      float lv = __shfl(l, r4 + j);
      float rinv = 1.f / lv;
      const int tq = qlo + r4 + j;
      u16* dst = aout + (bT + tq) * 2048 + (h << 7) + l16;
      #pragma unroll
      for (int db = 0; db < 8; ++db)
        dst[db << 4] = f2bf(o[db][j] * rinv);
    }
  }
}

extern "C" void kernel_launch(void* const* d_in, const int* in_sizes, int n_in,
                              void* d_out, int out_size, void* d_ws, size_t ws_size,
                              hipStream_t stream){
  const void* x       = d_in[0];
  const void* cosp    = d_in[1];
  const void* sinp    = d_in[2];
  const void* w_kv    = d_in[3];
  const void* w_kdec  = d_in[4];
  const void* w_vdec  = d_in[5];
  const void* w_qc    = d_in[6];
  const void* w_qdec  = d_in[7];
  const void* w_krope = d_in[8];
  const void* w_qrope = d_in[9];
  const void* w_o     = d_in[10];

  char* ws = (char*)d_ws;
  size_t off = 0;
  auto alloc = [&](size_t bytes){ void* p = ws + off; off += (bytes + 255) & ~(size_t)255; return p; };
  int* ticket   = (int*)alloc(1024);                         // 8 tickets, stride 16 ints
  u16* x_bf     = (u16*)alloc((size_t)NROWS * DIM_ * 2);
  u16* w_c1T    = (u16*)alloc((size_t)2304 * DIM_ * 2);      // [kvT(512); qcT(1536); kropeT(64); qropeT(64); pad] x 2048
  u16* w_kvdT   = (u16*)alloc((size_t)3072 * DC_ * 2);       // [kdecPackedT(1024); vdecT(2048)] x 512
  u16* w_qdPT   = (u16*)alloc((size_t)1024 * DCQ_ * 2);      // packed qdecT (1024 x 1536)
  u16* w_oT     = (u16*)alloc((size_t)DIM_ * DIM_ * 2);
  u16* xc       = (u16*)alloc((size_t)NROWS * 2304 * 2);     // [c_kv(512) | c_q(1536) | ropes(128) | pad]
  u16* qP       = (u16*)alloc((size_t)NROWS * 1024 * 2);     // packed q decode (pre-scaled)
  u16* kvP      = (u16*)alloc((size_t)NROWS * 1024 * 2);     // packed K only (stride 1024)
  u16* krope    = (u16*)alloc((size_t)NROWS * 64 * 2);
  u16* qrope    = (u16*)alloc((size_t)NROWS * 64 * 2);       // pre-scaled
  u16* vT       = (u16*)alloc((size_t)32 * 128 * T_ * 2);    // [bh][d][t], written by G2 epilogue
  u16* aout     = (u16*)alloc((size_t)NROWS * DIM_ * 2);
  (void)in_sizes; (void)n_in; (void)out_size; (void)ws_size;

  const float SC2 = 0.12753139626374414f;   // 1/sqrt(128) * log2(e)
  const u16* cosr = (const u16*)cosp;

  // prep: w_c1T transposes FIRST (G13's dependency), then x-convert (2048 x 4-wide blocks)
  TPack tp = {};
  tp.d[0] = { w_kv,    w_c1T,                        512,  2048, 64,  8,  0    };
  tp.d[1] = { w_qc,    w_c1T + (size_t)512 * 2048,   1536, 2048, 64,  24, 256  };
  tp.d[2] = { w_krope, w_c1T + (size_t)2048 * 2048,  64,   2048, 64,  1,  1024 };
  tp.d[3] = { w_qrope, w_c1T + (size_t)2112 * 2048,  64,   2048, 64,  1,  1056 };
  tp.d[4] = { nullptr, nullptr, 0, 0, 0, 1, 1 << 30 };
  tp.d[5] = { nullptr, nullptr, 0, 0, 0, 1, 1 << 30 };
  tp.d[6] = { nullptr, nullptr, 0, 0, 0, 1, 1 << 30 };
  tp.d[7] = { nullptr, nullptr, 0, 0, 0, 1, 1 << 30 };
  hipLaunchKernelGGL(k_prep, dim3(TBLK + CONVBLK), dim3(256), 0, stream, x, x_bf, tp, cosr);

  // decode/output-weight transposes: side blocks of the G13 launch (fill its tail round)
  TPack ts = {};
  ts.d[0] = { w_kdec, w_kvdT,                       2048, 512,  128, 16, 0    };
  ts.d[1] = { w_vdec, w_kvdT + (size_t)1024 * 512,  2048, 512,  64,  32, 128  };
  ts.d[2] = { w_qdec, w_qdPT,                       2048, 1536, 128, 16, 384  };
  ts.d[3] = { w_o,    w_oT,                         2048, 2048, 64,  32, 768  };
  ts.d[4] = { nullptr, nullptr, 0, 0, 0, 1, 1 << 30 };
  ts.d[5] = { nullptr, nullptr, 0, 0, 0, 1, 1 << 30 };
  ts.d[6] = { nullptr, nullptr, 0, 0, 0, 1, 1 << 30 };
  ts.d[7] = { nullptr, nullptr, 0, 0, 0, 1, 1 << 30 };
  TPack tz = {};

  // G13: xc = x @ [w_kv | w_qc | rope-pre], 544 gemm blocks (XCD-swizzled over ngemm=544)
  // + 1792 transpose side blocks = 2336 total. A straight from x when bf16.
  hipLaunchKernelGGL(k_gemm, dim3(2336, 1), dim3(256), 0, stream,
                     x_bf, DIM_, w_c1T, DIM_, xc, 2304, 1.0f,
                     x_bf, DIM_, w_c1T, DIM_, xc, 2304, 1.0f,
                     17, 1, (void*)nullptr, cosr,
                     (const u16*)x, (const u16*)x,
                     (u16*)nullptr, (u16*)nullptr,
                     (const u16*)nullptr, (const void*)nullptr, (const void*)nullptr,
                     (u16*)nullptr, (u16*)nullptr, (int*)nullptr,
                     544, 2, ts);
  // G4 + G2 + RoPE in ONE launch (1024 gemm blocks + 2048 rope blocks):
  //   flat<256:       qP = xc[:, 512:2048] @ w_qdecP  (K=1536, heavy group first)
  //   256<=flat<1024: K -> kvP (cols<1024); V -> vT direct transposed (cols>=1024)
  //   flat>=1024:     RoPE from xc cols 2048.. (block 1024 resets tickets)
  hipLaunchKernelGGL(k_gemm, dim3(3072, 1), dim3(256), 0, stream,
                     xc + 512, 2304, w_qdPT, DCQ_, qP, 1024, SC2,
                     xc, 2304, w_kvdT, DC_, kvP, 1024, 1.0f,
                     8, 0, (void*)nullptr, (const u16*)nullptr,
                     (const u16*)nullptr, (const u16*)nullptr,
                     (u16*)nullptr, vT,
                     xc, cosp, sinp, krope, qrope, ticket,
                     1024, 1, tz);
  // attention (256 workers x 8 waves, 128-row items, KVBLK=128, 2:1 stealing)
  hipLaunchKernelGGL(k_attn, dim3(256), dim3(512), 0, stream,
                     qP, kvP, vT, krope, qrope, aout, ticket);
  // G5: out = aout @ w_o  (4096 x 2048, K=2048) -> (32,16) = 512 blocks = 2/CU, XCD-chunked
  hipLaunchKernelGGL(k_gemm, dim3(32, 16), dim3(256), 0, stream,
                     aout, DIM_, w_oT, DIM_, (u16*)nullptr, DIM_, 1.0f,
                     aout, DIM_, w_oT, DIM_, (u16*)nullptr, DIM_, 1.0f,
                     16, 1, d_out, cosr,
                     (const u16*)nullptr, (const u16*)nullptr,
                     (u16*)nullptr, (u16*)nullptr,
                     (const u16*)nullptr, (const void*)nullptr, (const void*)nullptr,
                     (u16*)nullptr, (u16*)nullptr, (int*)nullptr,
                     512, 0, tz);
}

// Round 27
// 221.703 us; speedup vs baseline: 1.1399x; 1.0292x over previous
//
#include <hip/hip_runtime.h>
#include <stdint.h>
#include <math.h>

#define B_    2
#define T_    2048
#define DIM_  2048
#define H_    16
#define DC_   512
#define DCQ_  1536
#define NROWS (B_*T_)   // 4096

typedef unsigned short u16;
typedef __attribute__((ext_vector_type(8))) __bf16 bf16x8;
typedef __attribute__((ext_vector_type(4))) float  f32x4;
typedef __attribute__((ext_vector_type(8))) unsigned short u16x8;
typedef __attribute__((ext_vector_type(4))) float  f4v;

__device__ __forceinline__ u16 f2bf(float f){
  unsigned u = __float_as_uint(f);
  u += 0x7FFFu + ((u >> 16) & 1u);   // RNE
  return (u16)(u >> 16);
}
__device__ __forceinline__ float bf2f(u16 h){ return __uint_as_float(((unsigned)h) << 16); }

__device__ __forceinline__ unsigned cvt_pk_bf16(float lo, float hi){
  unsigned r;
  asm("v_cvt_pk_bf16_f32 %0, %1, %2" : "=v"(r) : "v"(lo), "v"(hi));
  return r;
}

// async global->LDS, 16B per lane; LDS dest = wave-uniform base + lane*16.
__device__ __forceinline__ void gld_lds16(const void* g, void* l){
  auto gp = reinterpret_cast<__attribute__((address_space(1))) unsigned int*>(
      reinterpret_cast<uintptr_t>(g));
  auto lp = reinterpret_cast<__attribute__((address_space(3))) unsigned int*>(
      reinterpret_cast<uintptr_t>(l));
  __builtin_amdgcn_global_load_lds(gp, lp, 16, 0, 0);
}

__device__ __forceinline__ f32x4 mfma16(bf16x8 a, bf16x8 b, f32x4 c){
  return __builtin_amdgcn_mfma_f32_16x16x32_bf16(a, b, c, 0, 0, 0);
}

__device__ __forceinline__ void vmwait0(){ asm volatile("s_waitcnt vmcnt(0)" ::: "memory"); }
__device__ __forceinline__ void vmwait8(){ asm volatile("s_waitcnt vmcnt(8)" ::: "memory"); }
__device__ __forceinline__ void barr(){ asm volatile("s_barrier" ::: "memory"); }

// dtype flag: cos[0,0]==1.0 -> bf16 u16[0]=0x3F80, fp32 u16[0]=0x0000.

struct TDesc { const void* src; u16* dst; int srcStride, dstStride, cblk, nbx, blk0; };
struct TPack { TDesc d[8]; };
#define TBLK 1088
#define CONVBLK 2048

// transpose one 64x64 tile (shared by k_prep and k_gemm side path)
__device__ __forceinline__ void do_transpose(void* ldsbuf, const TPack& p, int tb,
                                             int tid, int f){
  u16 (*tile)[72] = reinterpret_cast<u16(*)[72]>(ldsbuf);
  int i = 0;
  #pragma unroll
  for (int k = 1; k < 8; ++k) if (tb >= p.d[k].blk0) i = k;
  const void* src = p.d[i].src;
  u16* dst = p.d[i].dst;
  const int srcStride = p.d[i].srcStride, dstStride = p.d[i].dstStride;
  const int rel = tb - p.d[i].blk0;
  const int bx = rel % p.d[i].nbx, by = rel / p.d[i].nbx;
  const int r0 = by << 6, c0 = bx * p.d[i].cblk;
  #pragma unroll
  for (int it = 0; it < 2; ++it){
    int task = (it << 8) + tid;
    int r = task >> 3, c8 = (task & 7) << 3;
    if (f){
      const u16* pp = (const u16*)src + (size_t)(r0 + r) * srcStride + c0 + c8;
      u16x8 v = *reinterpret_cast<const u16x8*>(pp);
      #pragma unroll
      for (int j = 0; j < 8; ++j) tile[r][c8 + j] = v[j];
    } else {
      const float* pp = (const float*)src + (size_t)(r0 + r) * srcStride + c0 + c8;
      f4v a = reinterpret_cast<const f4v*>(pp)[0];
      f4v b = reinterpret_cast<const f4v*>(pp)[1];
      tile[r][c8+0]=f2bf(a.x); tile[r][c8+1]=f2bf(a.y); tile[r][c8+2]=f2bf(a.z); tile[r][c8+3]=f2bf(a.w);
      tile[r][c8+4]=f2bf(b.x); tile[r][c8+5]=f2bf(b.y); tile[r][c8+6]=f2bf(b.z); tile[r][c8+7]=f2bf(b.w);
    }
  }
  __syncthreads();
  #pragma unroll
  for (int it = 0; it < 2; ++it){
    int task = (it << 8) + tid;
    int rr = task >> 3, cc8 = (task & 7) << 3;
    u16x8 v;
    #pragma unroll
    for (int j = 0; j < 8; ++j) v[j] = tile[cc8 + j][rr];
    *reinterpret_cast<u16x8*>(dst + (size_t)((bx << 6) + rr) * dstStride + r0 + cc8) = v;
  }
}

// ---------------- w_c1T transposes (grid head, G13's dependency) + x-convert (tail;
// 2048 blocks x 4 uint2/thread; all early-return when input is already bf16).
__global__ void k_prep(const void* __restrict__ xsrc, u16* __restrict__ x_bf,
                       TPack p, const u16* __restrict__ cosr){
  __shared__ u16 tile[64][72];
  const int bid = blockIdx.x;
  const int tid = threadIdx.x;
  const int f = (cosr[0] == (u16)0x3F80u);
  if (bid < TBLK){
    do_transpose(tile, p, bid, tid, f);
    return;
  }
  if (f) return;                              // bf16 input: G13 reads x directly, skip copy
  const int base = ((bid - TBLK) * 256 + tid) * 4;   // 4 uint2 per thread; n4 = 2097152
  #pragma unroll
  for (int q = 0; q < 4; ++q){
    int id = base + q;
    f4v v = reinterpret_cast<const f4v*>(xsrc)[id];
    unsigned lo = (unsigned)f2bf(v.x) | ((unsigned)f2bf(v.y) << 16);
    unsigned hi = (unsigned)f2bf(v.z) | ((unsigned)f2bf(v.w) << 16);
    reinterpret_cast<uint2*>(x_bf)[id] = make_uint2(lo, hi);
  }
}

// ---------------- unified 128x128 GEMM: 256 thr / 4 waves (2x2), 64x64 per wave,
// LDS 64 KB -> 2 blocks/CU. Row-XOR swizzle via inverse-swizzled global_load_lds sources;
// counted vmcnt(8) pipeline; setprio around MFMA cluster. Two groups by N-tile index.
// alt-A: bf16 passthrough of unconverted input. vt: group cols >= 1024 -> vT transposed.
// Side paths (blocks with flat >= ngemm; EARLY-RETURN, safe per round-23/24 evidence):
//   sidemode 1 = RoPE elementwise (depends only on G13's xc; used in G2G4 launch)
//   sidemode 2 = weight transposes (depend only on inputs; used in G13 launch, fills tail)
__global__ __launch_bounds__(256, 2) void k_gemm(
    const u16* __restrict__ A0, int lda0, const u16* __restrict__ Bt0, int K0,
    u16* __restrict__ C0, int ldc0, float os0,
    const u16* __restrict__ A1, int lda1, const u16* __restrict__ Bt1, int K1,
    u16* __restrict__ C1, int ldc1, float os1,
    int ysplit, int swz, void* outp, const u16* __restrict__ cosr,
    const u16* __restrict__ alt0, const u16* __restrict__ alt1,
    u16* __restrict__ vt0, u16* __restrict__ vt1,
    const u16* __restrict__ ropeXc, const void* __restrict__ rcosp,
    const void* __restrict__ rsinp, u16* __restrict__ ropeK,
    u16* __restrict__ ropeQ, int* __restrict__ rticket,
    int ngemm, int sidemode, TPack tpp){
  __shared__ alignas(16) u16 lds[32768];   // 64 KB
  const int tid = threadIdx.x;
  const int flat = blockIdx.y * gridDim.x + blockIdx.x;

  if (sidemode && flat >= ngemm){
    const int tb = flat - ngemm;
    if (sidemode == 1){
      // ---- RoPE path (2048 trailing blocks; reads xc cols 2048..2175, stride 2304)
      if (tb == 0 && tid < 128) rticket[tid] = 0;    // ticket reset ahead of k_attn
      const int f2 = (((const u16*)rcosp)[0] == (u16)0x3F80u);
      int id = tb * 256 + tid;                       // exactly NROWS*128
      int row = id >> 7, c = id & 127;
      int t = row & (T_ - 1);
      int d = c & 63, i = d & 31;
      float cs, sn;
      if (f2){ cs = bf2f(((const u16*)rcosp)[t * 32 + i]); sn = bf2f(((const u16*)rsinp)[t * 32 + i]); }
      else   { cs = ((const float*)rcosp)[t * 32 + i];     sn = ((const float*)rsinp)[t * 32 + i]; }
      int base = c & 64;
      float t1 = bf2f(ropeXc[(size_t)row * 2304 + 2048 + base + i]);
      float t2 = bf2f(ropeXc[(size_t)row * 2304 + 2048 + base + 32 + i]);
      float v = (d < 32) ? (t1 * cs - t2 * sn) : (t2 * cs + t1 * sn);
      if (c >= 64) v *= 0.12753139626374414f;        // 1/sqrt(128)*log2(e) folded into q
      ((c < 64) ? ropeK : ropeQ)[(size_t)row * 64 + d] = f2bf(v);
    } else {
      // ---- weight-transpose path (1792 trailing blocks in the G13 launch)
      const int f2 = cosr ? (cosr[0] == (u16)0x3F80u) : 1;
      do_transpose(lds, tpp, tb, tid, f2);
    }
    return;
  }

  const int wid = tid >> 6, lane = tid & 63;
  const int wr = wid >> 1, wc = wid & 1;
  const int l16 = lane & 15, g = lane >> 4;
  int lin = flat;
  if (swz){
    const int q8 = ngemm >> 3;               // swizzle over gemm blocks only (ngemm%8==0)
    lin = (lin & 7) * q8 + (lin >> 3);       // bijective XCD chunking
  }
  const int m0 = (lin & 31) << 7;
  int nt = lin >> 5;
  const u16 *A, *Bt, *alt; u16 *C, *vtp; int lda, K, ldc; float oscale;
  if (nt < ysplit){ A = A0; lda = lda0; Bt = Bt0; K = K0; C = C0; ldc = ldc0; oscale = os0; alt = alt0; vtp = vt0; }
  else { nt -= ysplit; A = A1; lda = lda1; Bt = Bt1; K = K1; C = C1; ldc = ldc1; oscale = os1; alt = alt1; vtp = vt1; }
  const int f = cosr ? (cosr[0] == (u16)0x3F80u) : 1;
  if (alt && f) A = alt;                     // bf16 input: read source directly
  const int n0 = nt << 7;
  const size_t Kz = (size_t)K;
  const int nkt = K >> 6;

  auto STAGE = [&](int kt, int bufn){
    const int kb = kt << 6;
    #pragma unroll
    for (int q = 0; q < 8; ++q){
      const int ht = q >> 2;                 // 0 = A half, 1 = B half
      const int cq = ((q & 3) << 8) + tid;   // chunk 0..1023 within half
      const int Lb = cq << 4;                // byte in [128][128B] half-tile
      const int row = Lb >> 7;
      const int colb = (Lb & 127) ^ ((row & 7) << 4);   // inverse-swizzled source
      const u16* src = ht ? (Bt + (size_t)(n0 + row) * Kz + kb + (colb >> 1))
                          : (A  + (size_t)(m0 + row) * lda + kb + (colb >> 1));
      gld_lds16(src, &lds[bufn * 16384 + ht * 8192 + (cq << 3)]);
    }
  };

  f32x4 acc[4][4] = {};

  STAGE(0, 0);
  int buf = 0;

  for (int kt = 0; kt < nkt; ++kt){
    if (kt + 1 < nkt){ STAGE(kt + 1, buf ^ 1); vmwait8(); }   // waits tile-kt's 8 loads
    else vmwait0();
    barr();                                                    // staged tile visible to all
    bf16x8 af[2][4], bfr[2][4];
    #pragma unroll
    for (int ks = 0; ks < 2; ++ks){
      #pragma unroll
      for (int mi = 0; mi < 4; ++mi){
        int row = (wr << 6) + (mi << 4) + l16;
        int cb = ((ks << 6) + (g << 4)) ^ ((row & 7) << 4);
        af[ks][mi] = *reinterpret_cast<const bf16x8*>(&lds[buf * 16384 + (((row << 7) + cb) >> 1)]);
      }
      #pragma unroll
      for (int ni = 0; ni < 4; ++ni){
        int row = (wc << 6) + (ni << 4) + l16;
        int cb = ((ks << 6) + (g << 4)) ^ ((row & 7) << 4);
        bfr[ks][ni] = *reinterpret_cast<const bf16x8*>(&lds[buf * 16384 + 8192 + (((row << 7) + cb) >> 1)]);
      }
    }
    __builtin_amdgcn_s_setprio(1);
    #pragma unroll
    for (int ks = 0; ks < 2; ++ks)
      #pragma unroll
      for (int mi = 0; mi < 4; ++mi)
        #pragma unroll
        for (int ni = 0; ni < 4; ++ni)
          acc[mi][ni] = mfma16(af[ks][mi], bfr[ks][ni], acc[mi][ni]);
    __builtin_amdgcn_s_setprio(0);
    barr();                                  // reads done before next STAGE overwrites
    buf ^= 1;
  }

  const int r4 = g << 2;
  #pragma unroll
  for (int mi = 0; mi < 4; ++mi){
    int row = m0 + (wr << 6) + (mi << 4) + r4;
    #pragma unroll
    for (int ni = 0; ni < 4; ++ni){
      int col = n0 + (wc << 6) + (ni << 4) + l16;
      if (vtp && col >= 1024){
        // V quadrant: write transposed to vT[bh][d][t]; rows j are consecutive t.
        int hd = col - 1024;
        u16* dst = vtp + (((size_t)(((row >> 11) << 4) + (hd >> 7)) << 7) + (hd & 127)) * (size_t)T_ + (row & (T_ - 1));
        union { u16 u[4]; uint2 v; } pk;
        #pragma unroll
        for (int j = 0; j < 4; ++j) pk.u[j] = f2bf(acc[mi][ni][j] * oscale);
        *reinterpret_cast<uint2*>(dst) = pk.v;
        continue;
      }
      #pragma unroll
      for (int j = 0; j < 4; ++j){
        float v = acc[mi][ni][j] * oscale;
        if (outp){
          if (f) ((u16*)outp)[(size_t)(row + j) * ldc + col] = f2bf(v);
          else   ((float*)outp)[(size_t)(row + j) * ldc + col] = v;
        } else {
          C[(size_t)(row + j) * ldc + col] = f2bf(v);
        }
      }
    }
  }
}

// ---------------- causal flash attention: 128-row items, 8 waves x 16 rows (512 thr).
// KVBLK=128, 128 KB LDS double-buffer (1 block/CU by design). Full 4-bit chunk swizzle
// (chunk ^= row&15): reads span 16 rows of [*][128] tiles -> 16 distinct 16B slots,
// conflict-free on K and V ds_read_b128 (the 3-bit form left 2-way conflicts, r26 PMC).
// 256 workers, per-XCD tickets, 64 items over 32 workers = 2:1 heavy-first stealing.
__global__ __launch_bounds__(512, 2) void k_attn(const u16* __restrict__ qP,
                                                 const u16* __restrict__ kvP,
                                                 const u16* __restrict__ vT,
                                                 const u16* __restrict__ krope,
                                                 const u16* __restrict__ qrope,
                                                 u16* __restrict__ aout,
                                                 int* __restrict__ ticket){
  __shared__ alignas(16) u16 smem[65536];   // 128 KB: 2 buffers x (K [128][128] + V [128][128])
  const int tid = threadIdx.x, wid = tid >> 6, lane = tid & 63;
  const int l16 = lane & 15, g = lane >> 4;
  const int lk = g << 3, r4 = g << 2;
  const int swl = l16 << 3;                 // full 4-bit read swizzle (row&15 == l16)
  const int xcd = blockIdx.x & 7;

  while (true){
    if (tid == 0) *(int*)&smem[0] = atomicAdd(&ticket[xcd << 4], 1);
    __syncthreads();
    const int it = *(const int*)&smem[0];
    __syncthreads();
    if (it >= 64) break;
    const int qt = 15 - (it >> 2);          // heavy-first within partition (128-row tiles)
    const int bh = (xcd << 2) + (it & 3), b = bh >> 4, h = bh & 15;
    const int q0 = qt << 7;
    const size_t bT = (size_t)b * T_;
    const u16* kvPb = kvP + bT * 1024 + (h << 6);
    const u16* krb  = krope + bT * 64;
    const u16* vTb  = vT + (size_t)bh * 128 * T_;
    const int qlo = q0 + (wid << 4);
    const int nkv = qt + 1;                 // 128-row KV tiles

    auto STAGE = [&](int buf, int k0){
      const int base = buf << 15;           // u16 idx; 32768 u16 (64 KB) per buffer
      #pragma unroll
      for (int r = 0; r < 8; ++r){
        int c = (r << 9) + tid;             // 0..4095 chunks of 16B
        const u16* src;
        if (c < 2048){
          // K tile [128 rows][128 cols]: cols 0-63 packed kdec, 64-127 krope
          int row = c >> 4, cc = c & 15;
          int ccx = cc ^ (row & 15);        // full 4-bit involution
          int col0 = ccx << 3;
          src = (col0 < 64) ? (kvPb + (size_t)(k0 + row) * 1024 + col0)
                            : (krb  + (size_t)(k0 + row) * 64 + (col0 - 64));
        } else {
          // V tile [128 d][128 t] from vT[bh][d][t]
          int cv = c - 2048;
          int row = cv >> 4, cc = cv & 15;
          int ccx = cc ^ (row & 15);        // full 4-bit involution
          src = vTb + (size_t)row * T_ + k0 + (ccx << 3);
        }
        gld_lds16(src, &smem[base + (c << 3)]);
      }
    };

    bf16x8 qf[4];
    {
      size_t grow = bT + qlo + l16;
      #pragma unroll
      for (int ks = 0; ks < 4; ++ks){
        int d = (ks << 5) + lk;
        const u16* src = (ks < 2) ? (qP + grow * 1024 + (h << 6) + d)
                                  : (qrope + grow * 64 + (d - 64));
        qf[ks] = *reinterpret_cast<const bf16x8*>(src);
      }
    }
    f32x4 o[8] = {};
    float m = -3e38f, l = 0.f;

    STAGE(0, 0);
    __syncthreads();
    int cur = 0;

    for (int kv = 0; kv < nkv; ++kv){
      const int k0 = kv << 7;
      if (kv + 1 < nkv) STAGE(cur ^ 1, (kv + 1) << 7);
      const int kb = cur << 15;
      // ---- S^T = K Q^T : s[n][j] = S[k0 + 16n + r4 + j][q = qlo + l16]
      f32x4 s[8] = {};
      __builtin_amdgcn_s_setprio(1);
      #pragma unroll
      for (int ks = 0; ks < 4; ++ks){
        int colsw = ((ks << 5) + lk) ^ swl;
        #pragma unroll
        for (int n = 0; n < 8; ++n){
          bf16x8 kf = *reinterpret_cast<const bf16x8*>(&smem[kb + ((n << 4) + l16) * 128 + colsw]);
          s[n] = mfma16(kf, qf[ks], s[n]);
        }
      }
      __builtin_amdgcn_s_setprio(0);
      if (k0 + 127 > qlo){                  // only the final (diagonal) tile needs masking
        const int tq = qlo + l16;
        #pragma unroll
        for (int n = 0; n < 8; ++n)
          #pragma unroll
          for (int j = 0; j < 4; ++j)
            s[n][j] = (k0 + (n << 4) + r4 + j <= tq) ? s[n][j] : -3e38f;
      }
      float mx;
      {
        float a0 = fmaxf(fmaxf(s[0][0], s[0][1]), fmaxf(s[0][2], s[0][3]));
        float a1 = fmaxf(fmaxf(s[1][0], s[1][1]), fmaxf(s[1][2], s[1][3]));
        float a2 = fmaxf(fmaxf(s[2][0], s[2][1]), fmaxf(s[2][2], s[2][3]));
        float a3 = fmaxf(fmaxf(s[3][0], s[3][1]), fmaxf(s[3][2], s[3][3]));
        float a4 = fmaxf(fmaxf(s[4][0], s[4][1]), fmaxf(s[4][2], s[4][3]));
        float a5 = fmaxf(fmaxf(s[5][0], s[5][1]), fmaxf(s[5][2], s[5][3]));
        float a6 = fmaxf(fmaxf(s[6][0], s[6][1]), fmaxf(s[6][2], s[6][3]));
        float a7 = fmaxf(fmaxf(s[7][0], s[7][1]), fmaxf(s[7][2], s[7][3]));
        mx = fmaxf(fmaxf(fmaxf(a0, a1), fmaxf(a2, a3)),
                   fmaxf(fmaxf(a4, a5), fmaxf(a6, a7)));
        mx = fmaxf(mx, __shfl_xor(mx, 16));
        mx = fmaxf(mx, __shfl_xor(mx, 32));
      }
      if (__ballot(mx > m + 8.f)){
        float mnew = fmaxf(m, mx);
        float alpha = exp2f(m - mnew);
        m = mnew; l *= alpha;
        #pragma unroll
        for (int j = 0; j < 4; ++j){
          float av = __shfl(alpha, r4 + j);
          #pragma unroll
          for (int db = 0; db < 8; ++db) o[db][j] *= av;
        }
      }
      unsigned w[8][2];
      float rs = 0.f;
      #pragma unroll
      for (int n = 0; n < 8; ++n)
        #pragma unroll
        for (int jh = 0; jh < 2; ++jh){
          float p0 = exp2f(s[n][2*jh]     - m);
          float p1 = exp2f(s[n][2*jh + 1] - m);
          rs += p0 + p1;
          w[n][jh] = cvt_pk_bf16(p0, p1);
        }
      rs += __shfl_xor(rs, 16);
      rs += __shfl_xor(rs, 32);
      l += rs;
      const int srcA = l16 + ((g & 1) << 5);
      const int srcB = srcA + 16;
      const bool hi = (g >= 2);
      bf16x8 pa[4];
      #pragma unroll
      for (int ks2 = 0; ks2 < 4; ++ks2){
        unsigned a0 = __shfl((int)w[2*ks2][0],     srcA);
        unsigned b0 = __shfl((int)w[2*ks2 + 1][0], srcA);
        unsigned a1 = __shfl((int)w[2*ks2][1],     srcA);
        unsigned b1 = __shfl((int)w[2*ks2 + 1][1], srcA);
        unsigned a2 = __shfl((int)w[2*ks2][0],     srcB);
        unsigned b2 = __shfl((int)w[2*ks2 + 1][0], srcB);
        unsigned a3 = __shfl((int)w[2*ks2][1],     srcB);
        unsigned b3 = __shfl((int)w[2*ks2 + 1][1], srcB);
        union { unsigned u[4]; bf16x8 v; } pk;
        pk.u[0] = hi ? b0 : a0;
        pk.u[1] = hi ? b1 : a1;
        pk.u[2] = hi ? b2 : a2;
        pk.u[3] = hi ? b3 : a3;
        pa[ks2] = pk.v;
      }
      __builtin_amdgcn_s_setprio(1);
      #pragma unroll
      for (int ks2 = 0; ks2 < 4; ++ks2){
        int colsw = ((ks2 << 5) + lk) ^ swl;
        #pragma unroll
        for (int db = 0; db < 8; ++db){
          bf16x8 vb = *reinterpret_cast<const bf16x8*>(&smem[kb + 16384 + ((db << 4) + l16) * 128 + colsw]);
          o[db] = mfma16(pa[ks2], vb, o[db]);
        }
      }
      __builtin_amdgcn_s_setprio(0);
      __syncthreads();                      // drains prefetch; reads done before buffer reuse
      cur ^= 1;
    }
    #pragma unroll
    for (int j = 0; j < 4; ++j){
      float lv = __shfl(l, r4 + j);
      float rinv = 1.f / lv;
      const int tq = qlo + r4 + j;
      u16* dst = aout + (bT + tq) * 2048 + (h << 7) + l16;
      #pragma unroll
      for (int db = 0; db < 8; ++db)
        dst[db << 4] = f2bf(o[db][j] * rinv);
    }
  }
}

extern "C" void kernel_launch(void* const* d_in, const int* in_sizes, int n_in,
                              void* d_out, int out_size, void* d_ws, size_t ws_size,
                              hipStream_t stream){
  const void* x       = d_in[0];
  const void* cosp    = d_in[1];
  const void* sinp    = d_in[2];
  const void* w_kv    = d_in[3];
  const void* w_kdec  = d_in[4];
  const void* w_vdec  = d_in[5];
  const void* w_qc    = d_in[6];
  const void* w_qdec  = d_in[7];
  const void* w_krope = d_in[8];
  const void* w_qrope = d_in[9];
  const void* w_o     = d_in[10];

  char* ws = (char*)d_ws;
  size_t off = 0;
  auto alloc = [&](size_t bytes){ void* p = ws + off; off += (bytes + 255) & ~(size_t)255; return p; };
  int* ticket   = (int*)alloc(1024);                         // 8 tickets, stride 16 ints
  u16* x_bf     = (u16*)alloc((size_t)NROWS * DIM_ * 2);
  u16* w_c1T    = (u16*)alloc((size_t)2304 * DIM_ * 2);      // [kvT(512); qcT(1536); kropeT(64); qropeT(64); pad] x 2048
  u16* w_kvdT   = (u16*)alloc((size_t)3072 * DC_ * 2);       // [kdecPackedT(1024); vdecT(2048)] x 512
  u16* w_qdPT   = (u16*)alloc((size_t)1024 * DCQ_ * 2);      // packed qdecT (1024 x 1536)
  u16* w_oT     = (u16*)alloc((size_t)DIM_ * DIM_ * 2);
  u16* xc       = (u16*)alloc((size_t)NROWS * 2304 * 2);     // [c_kv(512) | c_q(1536) | ropes(128) | pad]
  u16* qP       = (u16*)alloc((size_t)NROWS * 1024 * 2);     // packed q decode (pre-scaled)
  u16* kvP      = (u16*)alloc((size_t)NROWS * 1024 * 2);     // packed K only (stride 1024)
  u16* krope    = (u16*)alloc((size_t)NROWS * 64 * 2);
  u16* qrope    = (u16*)alloc((size_t)NROWS * 64 * 2);       // pre-scaled
  u16* vT       = (u16*)alloc((size_t)32 * 128 * T_ * 2);    // [bh][d][t], written by G2 epilogue
  u16* aout     = (u16*)alloc((size_t)NROWS * DIM_ * 2);
  (void)in_sizes; (void)n_in; (void)out_size; (void)ws_size;

  const float SC2 = 0.12753139626374414f;   // 1/sqrt(128) * log2(e)
  const u16* cosr = (const u16*)cosp;

  // prep: w_c1T transposes FIRST (G13's dependency), then x-convert (2048 x 4-wide blocks)
  TPack tp = {};
  tp.d[0] = { w_kv,    w_c1T,                        512,  2048, 64,  8,  0    };
  tp.d[1] = { w_qc,    w_c1T + (size_t)512 * 2048,   1536, 2048, 64,  24, 256  };
  tp.d[2] = { w_krope, w_c1T + (size_t)2048 * 2048,  64,   2048, 64,  1,  1024 };
  tp.d[3] = { w_qrope, w_c1T + (size_t)2112 * 2048,  64,   2048, 64,  1,  1056 };
  tp.d[4] = { nullptr, nullptr, 0, 0, 0, 1, 1 << 30 };
  tp.d[5] = { nullptr, nullptr, 0, 0, 0, 1, 1 << 30 };
  tp.d[6] = { nullptr, nullptr, 0, 0, 0, 1, 1 << 30 };
  tp.d[7] = { nullptr, nullptr, 0, 0, 0, 1, 1 << 30 };
  hipLaunchKernelGGL(k_prep, dim3(TBLK + CONVBLK), dim3(256), 0, stream, x, x_bf, tp, cosr);

  // decode/output-weight transposes: side blocks of the G13 launch (fill its tail round)
  TPack ts = {};
  ts.d[0] = { w_kdec, w_kvdT,                       2048, 512,  128, 16, 0    };
  ts.d[1] = { w_vdec, w_kvdT + (size_t)1024 * 512,  2048, 512,  64,  32, 128  };
  ts.d[2] = { w_qdec, w_qdPT,                       2048, 1536, 128, 16, 384  };
  ts.d[3] = { w_o,    w_oT,                         2048, 2048, 64,  32, 768  };
  ts.d[4] = { nullptr, nullptr, 0, 0, 0, 1, 1 << 30 };
  ts.d[5] = { nullptr, nullptr, 0, 0, 0, 1, 1 << 30 };
  ts.d[6] = { nullptr, nullptr, 0, 0, 0, 1, 1 << 30 };
  ts.d[7] = { nullptr, nullptr, 0, 0, 0, 1, 1 << 30 };
  TPack tz = {};

  // G13: xc = x @ [w_kv | w_qc | rope-pre], 544 gemm blocks (XCD-swizzled over ngemm=544)
  // + 1792 transpose side blocks = 2336 total. A straight from x when bf16.
  hipLaunchKernelGGL(k_gemm, dim3(2336, 1), dim3(256), 0, stream,
                     x_bf, DIM_, w_c1T, DIM_, xc, 2304, 1.0f,
                     x_bf, DIM_, w_c1T, DIM_, xc, 2304, 1.0f,
                     17, 1, (void*)nullptr, cosr,
                     (const u16*)x, (const u16*)x,
                     (u16*)nullptr, (u16*)nullptr,
                     (const u16*)nullptr, (const void*)nullptr, (const void*)nullptr,
                     (u16*)nullptr, (u16*)nullptr, (int*)nullptr,
                     544, 2, ts);
  // G4 + G2 + RoPE in ONE launch (1024 gemm blocks + 2048 rope blocks):
  //   flat<256:       qP = xc[:, 512:2048] @ w_qdecP  (K=1536, heavy group first)
  //   256<=flat<1024: K -> kvP (cols<1024); V -> vT direct transposed (cols>=1024)
  //   flat>=1024:     RoPE from xc cols 2048.. (block 1024 resets tickets)
  hipLaunchKernelGGL(k_gemm, dim3(3072, 1), dim3(256), 0, stream,
                     xc + 512, 2304, w_qdPT, DCQ_, qP, 1024, SC2,
                     xc, 2304, w_kvdT, DC_, kvP, 1024, 1.0f,
                     8, 0, (void*)nullptr, (const u16*)nullptr,
                     (const u16*)nullptr, (const u16*)nullptr,
                     (u16*)nullptr, vT,
                     xc, cosp, sinp, krope, qrope, ticket,
                     1024, 1, tz);
  // attention (256 workers x 8 waves, 128-row items, KVBLK=128, full 4-bit swizzle)
  hipLaunchKernelGGL(k_attn, dim3(256), dim3(512), 0, stream,
                     qP, kvP, vT, krope, qrope, aout, ticket);
  // G5: out = aout @ w_o  (4096 x 2048, K=2048) -> (32,16) = 512 blocks = 2/CU, XCD-chunked
  hipLaunchKernelGGL(k_gemm, dim3(32, 16), dim3(256), 0, stream,
                     aout, DIM_, w_oT, DIM_, (u16*)nullptr, DIM_, 1.0f,
                     aout, DIM_, w_oT, DIM_, (u16*)nullptr, DIM_, 1.0f,
                     16, 1, d_out, cosr,
                     (const u16*)nullptr, (const u16*)nullptr,
                     (u16*)nullptr, (u16*)nullptr,
                     (const u16*)nullptr, (const void*)nullptr, (const void*)nullptr,
                     (u16*)nullptr, (u16*)nullptr, (int*)nullptr,
                     512, 0, tz);
}

// Round 28
// 220.897 us; speedup vs baseline: 1.1440x; 1.0036x over previous
//
#include <hip/hip_runtime.h>
#include <stdint.h>
#include <math.h>

#define B_    2
#define T_    2048
#define DIM_  2048
#define H_    16
#define DC_   512
#define DCQ_  1536
#define NROWS (B_*T_)   // 4096

typedef unsigned short u16;
typedef __attribute__((ext_vector_type(8))) __bf16 bf16x8;
typedef __attribute__((ext_vector_type(4))) float  f32x4;
typedef __attribute__((ext_vector_type(8))) unsigned short u16x8;
typedef __attribute__((ext_vector_type(4))) float  f4v;

__device__ __forceinline__ u16 f2bf(float f){
  unsigned u = __float_as_uint(f);
  u += 0x7FFFu + ((u >> 16) & 1u);   // RNE
  return (u16)(u >> 16);
}
__device__ __forceinline__ float bf2f(u16 h){ return __uint_as_float(((unsigned)h) << 16); }

__device__ __forceinline__ unsigned cvt_pk_bf16(float lo, float hi){
  unsigned r;
  asm("v_cvt_pk_bf16_f32 %0, %1, %2" : "=v"(r) : "v"(lo), "v"(hi));
  return r;
}

// async global->LDS, 16B per lane; LDS dest = wave-uniform base + lane*16.
__device__ __forceinline__ void gld_lds16(const void* g, void* l){
  auto gp = reinterpret_cast<__attribute__((address_space(1))) unsigned int*>(
      reinterpret_cast<uintptr_t>(g));
  auto lp = reinterpret_cast<__attribute__((address_space(3))) unsigned int*>(
      reinterpret_cast<uintptr_t>(l));
  __builtin_amdgcn_global_load_lds(gp, lp, 16, 0, 0);
}

__device__ __forceinline__ f32x4 mfma16(bf16x8 a, bf16x8 b, f32x4 c){
  return __builtin_amdgcn_mfma_f32_16x16x32_bf16(a, b, c, 0, 0, 0);
}

__device__ __forceinline__ void vmwait0(){ asm volatile("s_waitcnt vmcnt(0)" ::: "memory"); }
__device__ __forceinline__ void vmwait8(){ asm volatile("s_waitcnt vmcnt(8)" ::: "memory"); }
__device__ __forceinline__ void barr(){ asm volatile("s_barrier" ::: "memory"); }

// dtype flag: cos[0,0]==1.0 -> bf16 u16[0]=0x3F80, fp32 u16[0]=0x0000.

struct TDesc { const void* src; u16* dst; int srcStride, dstStride, cblk, nbx, blk0; };
struct TPack { TDesc d[8]; };
#define TBLK 1088
#define CONVBLK 2048

// transpose one 64x64 tile (shared by k_prep and k_gemm side path)
__device__ __forceinline__ void do_transpose(void* ldsbuf, const TPack& p, int tb,
                                             int tid, int f){
  u16 (*tile)[72] = reinterpret_cast<u16(*)[72]>(ldsbuf);
  int i = 0;
  #pragma unroll
  for (int k = 1; k < 8; ++k) if (tb >= p.d[k].blk0) i = k;
  const void* src = p.d[i].src;
  u16* dst = p.d[i].dst;
  const int srcStride = p.d[i].srcStride, dstStride = p.d[i].dstStride;
  const int rel = tb - p.d[i].blk0;
  const int bx = rel % p.d[i].nbx, by = rel / p.d[i].nbx;
  const int r0 = by << 6, c0 = bx * p.d[i].cblk;
  #pragma unroll
  for (int it = 0; it < 2; ++it){
    int task = (it << 8) + tid;
    int r = task >> 3, c8 = (task & 7) << 3;
    if (f){
      const u16* pp = (const u16*)src + (size_t)(r0 + r) * srcStride + c0 + c8;
      u16x8 v = *reinterpret_cast<const u16x8*>(pp);
      #pragma unroll
      for (int j = 0; j < 8; ++j) tile[r][c8 + j] = v[j];
    } else {
      const float* pp = (const float*)src + (size_t)(r0 + r) * srcStride + c0 + c8;
      f4v a = reinterpret_cast<const f4v*>(pp)[0];
      f4v b = reinterpret_cast<const f4v*>(pp)[1];
      tile[r][c8+0]=f2bf(a.x); tile[r][c8+1]=f2bf(a.y); tile[r][c8+2]=f2bf(a.z); tile[r][c8+3]=f2bf(a.w);
      tile[r][c8+4]=f2bf(b.x); tile[r][c8+5]=f2bf(b.y); tile[r][c8+6]=f2bf(b.z); tile[r][c8+7]=f2bf(b.w);
    }
  }
  __syncthreads();
  #pragma unroll
  for (int it = 0; it < 2; ++it){
    int task = (it << 8) + tid;
    int rr = task >> 3, cc8 = (task & 7) << 3;
    u16x8 v;
    #pragma unroll
    for (int j = 0; j < 8; ++j) v[j] = tile[cc8 + j][rr];
    *reinterpret_cast<u16x8*>(dst + (size_t)((bx << 6) + rr) * dstStride + r0 + cc8) = v;
  }
}

// ---------------- w_c1T transposes (grid head, G13's dependency) + x-convert (tail;
// 2048 blocks x 4 uint2/thread; all early-return when input is already bf16).
__global__ void k_prep(const void* __restrict__ xsrc, u16* __restrict__ x_bf,
                       TPack p, const u16* __restrict__ cosr){
  __shared__ u16 tile[64][72];
  const int bid = blockIdx.x;
  const int tid = threadIdx.x;
  const int f = (cosr[0] == (u16)0x3F80u);
  if (bid < TBLK){
    do_transpose(tile, p, bid, tid, f);
    return;
  }
  if (f) return;                              // bf16 input: G13 reads x directly, skip copy
  const int base = ((bid - TBLK) * 256 + tid) * 4;   // 4 uint2 per thread; n4 = 2097152
  #pragma unroll
  for (int q = 0; q < 4; ++q){
    int id = base + q;
    f4v v = reinterpret_cast<const f4v*>(xsrc)[id];
    unsigned lo = (unsigned)f2bf(v.x) | ((unsigned)f2bf(v.y) << 16);
    unsigned hi = (unsigned)f2bf(v.z) | ((unsigned)f2bf(v.w) << 16);
    reinterpret_cast<uint2*>(x_bf)[id] = make_uint2(lo, hi);
  }
}

// ---------------- unified 128x128 GEMM: 256 thr / 4 waves (2x2), 64x64 per wave,
// LDS 64 KB -> 2 blocks/CU. Row-XOR swizzle via inverse-swizzled global_load_lds sources;
// counted vmcnt(8) pipeline; setprio around MFMA cluster. Two groups by N-tile index.
// alt-A: bf16 passthrough of unconverted input. vt: group cols >= 1024 -> vT transposed.
// Side paths (blocks with flat >= ngemm; EARLY-RETURN, safe per round-23/24 evidence):
//   sidemode 1 = RoPE elementwise (depends only on G13's xc; used in G2G4 launch)
//   sidemode 2 = weight transposes (depend only on inputs; used in G13 launch, fills tail)
__global__ __launch_bounds__(256, 2) void k_gemm(
    const u16* __restrict__ A0, int lda0, const u16* __restrict__ Bt0, int K0,
    u16* __restrict__ C0, int ldc0, float os0,
    const u16* __restrict__ A1, int lda1, const u16* __restrict__ Bt1, int K1,
    u16* __restrict__ C1, int ldc1, float os1,
    int ysplit, int swz, void* outp, const u16* __restrict__ cosr,
    const u16* __restrict__ alt0, const u16* __restrict__ alt1,
    u16* __restrict__ vt0, u16* __restrict__ vt1,
    const u16* __restrict__ ropeXc, const void* __restrict__ rcosp,
    const void* __restrict__ rsinp, u16* __restrict__ ropeK,
    u16* __restrict__ ropeQ, int* __restrict__ rticket,
    int ngemm, int sidemode, TPack tpp){
  __shared__ alignas(16) u16 lds[32768];   // 64 KB
  const int tid = threadIdx.x;
  const int flat = blockIdx.y * gridDim.x + blockIdx.x;

  if (sidemode && flat >= ngemm){
    const int tb = flat - ngemm;
    if (sidemode == 1){
      // ---- RoPE path (2048 trailing blocks; reads xc cols 2048..2175, stride 2304)
      if (tb == 0 && tid < 128) rticket[tid] = 0;    // vestigial (attn is static-mapped)
      const int f2 = (((const u16*)rcosp)[0] == (u16)0x3F80u);
      int id = tb * 256 + tid;                       // exactly NROWS*128
      int row = id >> 7, c = id & 127;
      int t = row & (T_ - 1);
      int d = c & 63, i = d & 31;
      float cs, sn;
      if (f2){ cs = bf2f(((const u16*)rcosp)[t * 32 + i]); sn = bf2f(((const u16*)rsinp)[t * 32 + i]); }
      else   { cs = ((const float*)rcosp)[t * 32 + i];     sn = ((const float*)rsinp)[t * 32 + i]; }
      int base = c & 64;
      float t1 = bf2f(ropeXc[(size_t)row * 2304 + 2048 + base + i]);
      float t2 = bf2f(ropeXc[(size_t)row * 2304 + 2048 + base + 32 + i]);
      float v = (d < 32) ? (t1 * cs - t2 * sn) : (t2 * cs + t1 * sn);
      if (c >= 64) v *= 0.12753139626374414f;        // 1/sqrt(128)*log2(e) folded into q
      ((c < 64) ? ropeK : ropeQ)[(size_t)row * 64 + d] = f2bf(v);
    } else {
      // ---- weight-transpose path (1792 trailing blocks in the G13 launch)
      const int f2 = cosr ? (cosr[0] == (u16)0x3F80u) : 1;
      do_transpose(lds, tpp, tb, tid, f2);
    }
    return;
  }

  const int wid = tid >> 6, lane = tid & 63;
  const int wr = wid >> 1, wc = wid & 1;
  const int l16 = lane & 15, g = lane >> 4;
  int lin = flat;
  if (swz){
    const int q8 = ngemm >> 3;               // swizzle over gemm blocks only (ngemm%8==0)
    lin = (lin & 7) * q8 + (lin >> 3);       // bijective XCD chunking
  }
  const int m0 = (lin & 31) << 7;
  int nt = lin >> 5;
  const u16 *A, *Bt, *alt; u16 *C, *vtp; int lda, K, ldc; float oscale;
  if (nt < ysplit){ A = A0; lda = lda0; Bt = Bt0; K = K0; C = C0; ldc = ldc0; oscale = os0; alt = alt0; vtp = vt0; }
  else { nt -= ysplit; A = A1; lda = lda1; Bt = Bt1; K = K1; C = C1; ldc = ldc1; oscale = os1; alt = alt1; vtp = vt1; }
  const int f = cosr ? (cosr[0] == (u16)0x3F80u) : 1;
  if (alt && f) A = alt;                     // bf16 input: read source directly
  const int n0 = nt << 7;
  const size_t Kz = (size_t)K;
  const int nkt = K >> 6;

  auto STAGE = [&](int kt, int bufn){
    const int kb = kt << 6;
    #pragma unroll
    for (int q = 0; q < 8; ++q){
      const int ht = q >> 2;                 // 0 = A half, 1 = B half
      const int cq = ((q & 3) << 8) + tid;   // chunk 0..1023 within half
      const int Lb = cq << 4;                // byte in [128][128B] half-tile
      const int row = Lb >> 7;
      const int colb = (Lb & 127) ^ ((row & 7) << 4);   // inverse-swizzled source
      const u16* src = ht ? (Bt + (size_t)(n0 + row) * Kz + kb + (colb >> 1))
                          : (A  + (size_t)(m0 + row) * lda + kb + (colb >> 1));
      gld_lds16(src, &lds[bufn * 16384 + ht * 8192 + (cq << 3)]);
    }
  };

  f32x4 acc[4][4] = {};

  STAGE(0, 0);
  int buf = 0;

  for (int kt = 0; kt < nkt; ++kt){
    if (kt + 1 < nkt){ STAGE(kt + 1, buf ^ 1); vmwait8(); }   // waits tile-kt's 8 loads
    else vmwait0();
    barr();                                                    // staged tile visible to all
    bf16x8 af[2][4], bfr[2][4];
    #pragma unroll
    for (int ks = 0; ks < 2; ++ks){
      #pragma unroll
      for (int mi = 0; mi < 4; ++mi){
        int row = (wr << 6) + (mi << 4) + l16;
        int cb = ((ks << 6) + (g << 4)) ^ ((row & 7) << 4);
        af[ks][mi] = *reinterpret_cast<const bf16x8*>(&lds[buf * 16384 + (((row << 7) + cb) >> 1)]);
      }
      #pragma unroll
      for (int ni = 0; ni < 4; ++ni){
        int row = (wc << 6) + (ni << 4) + l16;
        int cb = ((ks << 6) + (g << 4)) ^ ((row & 7) << 4);
        bfr[ks][ni] = *reinterpret_cast<const bf16x8*>(&lds[buf * 16384 + 8192 + (((row << 7) + cb) >> 1)]);
      }
    }
    __builtin_amdgcn_s_setprio(1);
    #pragma unroll
    for (int ks = 0; ks < 2; ++ks)
      #pragma unroll
      for (int mi = 0; mi < 4; ++mi)
        #pragma unroll
        for (int ni = 0; ni < 4; ++ni)
          acc[mi][ni] = mfma16(af[ks][mi], bfr[ks][ni], acc[mi][ni]);
    __builtin_amdgcn_s_setprio(0);
    barr();                                  // reads done before next STAGE overwrites
    buf ^= 1;
  }

  const int r4 = g << 2;
  #pragma unroll
  for (int mi = 0; mi < 4; ++mi){
    int row = m0 + (wr << 6) + (mi << 4) + r4;
    #pragma unroll
    for (int ni = 0; ni < 4; ++ni){
      int col = n0 + (wc << 6) + (ni << 4) + l16;
      if (vtp && col >= 1024){
        // V quadrant: write transposed to vT[bh][d][t]; rows j are consecutive t.
        int hd = col - 1024;
        u16* dst = vtp + (((size_t)(((row >> 11) << 4) + (hd >> 7)) << 7) + (hd & 127)) * (size_t)T_ + (row & (T_ - 1));
        union { u16 u[4]; uint2 v; } pk;
        #pragma unroll
        for (int j = 0; j < 4; ++j) pk.u[j] = f2bf(acc[mi][ni][j] * oscale);
        *reinterpret_cast<uint2*>(dst) = pk.v;
        continue;
      }
      #pragma unroll
      for (int j = 0; j < 4; ++j){
        float v = acc[mi][ni][j] * oscale;
        if (outp){
          if (f) ((u16*)outp)[(size_t)(row + j) * ldc + col] = f2bf(v);
          else   ((float*)outp)[(size_t)(row + j) * ldc + col] = v;
        } else {
          C[(size_t)(row + j) * ldc + col] = f2bf(v);
        }
      }
    }
  }
}

// ---------------- causal flash attention: 128-row items, 8 waves x 16 rows (512 thr).
// KVBLK=128, 128 KB LDS double-buffer, full 4-bit chunk swizzle (r27: conflicts -80%).
// STATIC uniform bundles (no ticket): block = (xcd, bh, p) runs qt = 15-p then qt = p
// -> exactly 17 KV tiles per block, identical for all 256 blocks (1/CU). Uniform work
// makes 1:1 static mapping safe (r12/r18 failures were non-uniform 1:1); deletes the
// atomic + broadcast + 2 barriers per item. XCD-partitioned bh preserved (L2 locality).
__global__ __launch_bounds__(512, 2) void k_attn(const u16* __restrict__ qP,
                                                 const u16* __restrict__ kvP,
                                                 const u16* __restrict__ vT,
                                                 const u16* __restrict__ krope,
                                                 const u16* __restrict__ qrope,
                                                 u16* __restrict__ aout){
  __shared__ alignas(16) u16 smem[65536];   // 128 KB: 2 buffers x (K [128][128] + V [128][128])
  const int tid = threadIdx.x, wid = tid >> 6, lane = tid & 63;
  const int l16 = lane & 15, g = lane >> 4;
  const int lk = g << 3, r4 = g << 2;
  const int swl = l16 << 3;                 // full 4-bit read swizzle (row&15 == l16)
  const int xcd = blockIdx.x & 7;
  const int idx = blockIdx.x >> 3;          // 0..31 within partition
  const int bh = (xcd << 2) + (idx & 3), b = bh >> 4, h = bh & 15;
  const int p = idx >> 2;                   // 0..7: bundle (qt = 15-p, then qt = p)
  const size_t bT = (size_t)b * T_;
  const u16* kvPb = kvP + bT * 1024 + (h << 6);
  const u16* krb  = krope + bT * 64;
  const u16* vTb  = vT + (size_t)bh * 128 * T_;

  for (int which = 0; which < 2; ++which){
    const int qt = which ? p : (15 - p);
    const int q0 = qt << 7;
    const int qlo = q0 + (wid << 4);
    const int nkv = qt + 1;                 // 128-row KV tiles

    auto STAGE = [&](int buf, int k0){
      const int base = buf << 15;           // u16 idx; 32768 u16 (64 KB) per buffer
      #pragma unroll
      for (int r = 0; r < 8; ++r){
        int c = (r << 9) + tid;             // 0..4095 chunks of 16B
        const u16* src;
        if (c < 2048){
          // K tile [128 rows][128 cols]: cols 0-63 packed kdec, 64-127 krope
          int row = c >> 4, cc = c & 15;
          int ccx = cc ^ (row & 15);        // full 4-bit involution
          int col0 = ccx << 3;
          src = (col0 < 64) ? (kvPb + (size_t)(k0 + row) * 1024 + col0)
                            : (krb  + (size_t)(k0 + row) * 64 + (col0 - 64));
        } else {
          // V tile [128 d][128 t] from vT[bh][d][t]
          int cv = c - 2048;
          int row = cv >> 4, cc = cv & 15;
          int ccx = cc ^ (row & 15);        // full 4-bit involution
          src = vTb + (size_t)row * T_ + k0 + (ccx << 3);
        }
        gld_lds16(src, &smem[base + (c << 3)]);
      }
    };

    bf16x8 qf[4];
    {
      size_t grow = bT + qlo + l16;
      #pragma unroll
      for (int ks = 0; ks < 4; ++ks){
        int d = (ks << 5) + lk;
        const u16* src = (ks < 2) ? (qP + grow * 1024 + (h << 6) + d)
                                  : (qrope + grow * 64 + (d - 64));
        qf[ks] = *reinterpret_cast<const bf16x8*>(src);
      }
    }
    f32x4 o[8] = {};
    float m = -3e38f, l = 0.f;

    STAGE(0, 0);
    __syncthreads();
    int cur = 0;

    for (int kv = 0; kv < nkv; ++kv){
      const int k0 = kv << 7;
      if (kv + 1 < nkv) STAGE(cur ^ 1, (kv + 1) << 7);
      const int kb = cur << 15;
      // ---- S^T = K Q^T : s[n][j] = S[k0 + 16n + r4 + j][q = qlo + l16]
      f32x4 s[8] = {};
      __builtin_amdgcn_s_setprio(1);
      #pragma unroll
      for (int ks = 0; ks < 4; ++ks){
        int colsw = ((ks << 5) + lk) ^ swl;
        #pragma unroll
        for (int n = 0; n < 8; ++n){
          bf16x8 kf = *reinterpret_cast<const bf16x8*>(&smem[kb + ((n << 4) + l16) * 128 + colsw]);
          s[n] = mfma16(kf, qf[ks], s[n]);
        }
      }
      __builtin_amdgcn_s_setprio(0);
      if (k0 + 127 > qlo){                  // only the final (diagonal) tile needs masking
        const int tq = qlo + l16;
        #pragma unroll
        for (int n = 0; n < 8; ++n)
          #pragma unroll
          for (int j = 0; j < 4; ++j)
            s[n][j] = (k0 + (n << 4) + r4 + j <= tq) ? s[n][j] : -3e38f;
      }
      float mx;
      {
        float a0 = fmaxf(fmaxf(s[0][0], s[0][1]), fmaxf(s[0][2], s[0][3]));
        float a1 = fmaxf(fmaxf(s[1][0], s[1][1]), fmaxf(s[1][2], s[1][3]));
        float a2 = fmaxf(fmaxf(s[2][0], s[2][1]), fmaxf(s[2][2], s[2][3]));
        float a3 = fmaxf(fmaxf(s[3][0], s[3][1]), fmaxf(s[3][2], s[3][3]));
        float a4 = fmaxf(fmaxf(s[4][0], s[4][1]), fmaxf(s[4][2], s[4][3]));
        float a5 = fmaxf(fmaxf(s[5][0], s[5][1]), fmaxf(s[5][2], s[5][3]));
        float a6 = fmaxf(fmaxf(s[6][0], s[6][1]), fmaxf(s[6][2], s[6][3]));
        float a7 = fmaxf(fmaxf(s[7][0], s[7][1]), fmaxf(s[7][2], s[7][3]));
        mx = fmaxf(fmaxf(fmaxf(a0, a1), fmaxf(a2, a3)),
                   fmaxf(fmaxf(a4, a5), fmaxf(a6, a7)));
        mx = fmaxf(mx, __shfl_xor(mx, 16));
        mx = fmaxf(mx, __shfl_xor(mx, 32));
      }
      if (__ballot(mx > m + 8.f)){
        float mnew = fmaxf(m, mx);
        float alpha = exp2f(m - mnew);
        m = mnew; l *= alpha;
        #pragma unroll
        for (int j = 0; j < 4; ++j){
          float av = __shfl(alpha, r4 + j);
          #pragma unroll
          for (int db = 0; db < 8; ++db) o[db][j] *= av;
        }
      }
      unsigned w[8][2];
      float rs = 0.f;
      #pragma unroll
      for (int n = 0; n < 8; ++n)
        #pragma unroll
        for (int jh = 0; jh < 2; ++jh){
          float p0 = exp2f(s[n][2*jh]     - m);
          float p1 = exp2f(s[n][2*jh + 1] - m);
          rs += p0 + p1;
          w[n][jh] = cvt_pk_bf16(p0, p1);
        }
      rs += __shfl_xor(rs, 16);
      rs += __shfl_xor(rs, 32);
      l += rs;
      const int srcA = l16 + ((g & 1) << 5);
      const int srcB = srcA + 16;
      const bool hi = (g >= 2);
      bf16x8 pa[4];
      #pragma unroll
      for (int ks2 = 0; ks2 < 4; ++ks2){
        unsigned a0 = __shfl((int)w[2*ks2][0],     srcA);
        unsigned b0 = __shfl((int)w[2*ks2 + 1][0], srcA);
        unsigned a1 = __shfl((int)w[2*ks2][1],     srcA);
        unsigned b1 = __shfl((int)w[2*ks2 + 1][1], srcA);
        unsigned a2 = __shfl((int)w[2*ks2][0],     srcB);
        unsigned b2 = __shfl((int)w[2*ks2 + 1][0], srcB);
        unsigned a3 = __shfl((int)w[2*ks2][1],     srcB);
        unsigned b3 = __shfl((int)w[2*ks2 + 1][1], srcB);
        union { unsigned u[4]; bf16x8 v; } pk;
        pk.u[0] = hi ? b0 : a0;
        pk.u[1] = hi ? b1 : a1;
        pk.u[2] = hi ? b2 : a2;
        pk.u[3] = hi ? b3 : a3;
        pa[ks2] = pk.v;
      }
      __builtin_amdgcn_s_setprio(1);
      #pragma unroll
      for (int ks2 = 0; ks2 < 4; ++ks2){
        int colsw = ((ks2 << 5) + lk) ^ swl;
        #pragma unroll
        for (int db = 0; db < 8; ++db){
          bf16x8 vb = *reinterpret_cast<const bf16x8*>(&smem[kb + 16384 + ((db << 4) + l16) * 128 + colsw]);
          o[db] = mfma16(pa[ks2], vb, o[db]);
        }
      }
      __builtin_amdgcn_s_setprio(0);
      __syncthreads();                      // drains prefetch; reads done before buffer reuse
      cur ^= 1;
    }
    #pragma unroll
    for (int j = 0; j < 4; ++j){
      float lv = __shfl(l, r4 + j);
      float rinv = 1.f / lv;
      const int tq = qlo + r4 + j;
      u16* dst = aout + (bT + tq) * 2048 + (h << 7) + l16;
      #pragma unroll
      for (int db = 0; db < 8; ++db)
        dst[db << 4] = f2bf(o[db][j] * rinv);
    }
  }
}

extern "C" void kernel_launch(void* const* d_in, const int* in_sizes, int n_in,
                              void* d_out, int out_size, void* d_ws, size_t ws_size,
                              hipStream_t stream){
  const void* x       = d_in[0];
  const void* cosp    = d_in[1];
  const void* sinp    = d_in[2];
  const void* w_kv    = d_in[3];
  const void* w_kdec  = d_in[4];
  const void* w_vdec  = d_in[5];
  const void* w_qc    = d_in[6];
  const void* w_qdec  = d_in[7];
  const void* w_krope = d_in[8];
  const void* w_qrope = d_in[9];
  const void* w_o     = d_in[10];

  char* ws = (char*)d_ws;
  size_t off = 0;
  auto alloc = [&](size_t bytes){ void* p = ws + off; off += (bytes + 255) & ~(size_t)255; return p; };
  int* ticket   = (int*)alloc(1024);                         // vestigial (rope resets it)
  u16* x_bf     = (u16*)alloc((size_t)NROWS * DIM_ * 2);
  u16* w_c1T    = (u16*)alloc((size_t)2304 * DIM_ * 2);      // [kvT(512); qcT(1536); kropeT(64); qropeT(64); pad] x 2048
  u16* w_kvdT   = (u16*)alloc((size_t)3072 * DC_ * 2);       // [kdecPackedT(1024); vdecT(2048)] x 512
  u16* w_qdPT   = (u16*)alloc((size_t)1024 * DCQ_ * 2);      // packed qdecT (1024 x 1536)
  u16* w_oT     = (u16*)alloc((size_t)DIM_ * DIM_ * 2);
  u16* xc       = (u16*)alloc((size_t)NROWS * 2304 * 2);     // [c_kv(512) | c_q(1536) | ropes(128) | pad]
  u16* qP       = (u16*)alloc((size_t)NROWS * 1024 * 2);     // packed q decode (pre-scaled)
  u16* kvP      = (u16*)alloc((size_t)NROWS * 1024 * 2);     // packed K only (stride 1024)
  u16* krope    = (u16*)alloc((size_t)NROWS * 64 * 2);
  u16* qrope    = (u16*)alloc((size_t)NROWS * 64 * 2);       // pre-scaled
  u16* vT       = (u16*)alloc((size_t)32 * 128 * T_ * 2);    // [bh][d][t], written by G2 epilogue
  u16* aout     = (u16*)alloc((size_t)NROWS * DIM_ * 2);
  (void)in_sizes; (void)n_in; (void)out_size; (void)ws_size;

  const float SC2 = 0.12753139626374414f;   // 1/sqrt(128) * log2(e)
  const u16* cosr = (const u16*)cosp;

  // prep: w_c1T transposes FIRST (G13's dependency), then x-convert (2048 x 4-wide blocks)
  TPack tp = {};
  tp.d[0] = { w_kv,    w_c1T,                        512,  2048, 64,  8,  0    };
  tp.d[1] = { w_qc,    w_c1T + (size_t)512 * 2048,   1536, 2048, 64,  24, 256  };
  tp.d[2] = { w_krope, w_c1T + (size_t)2048 * 2048,  64,   2048, 64,  1,  1024 };
  tp.d[3] = { w_qrope, w_c1T + (size_t)2112 * 2048,  64,   2048, 64,  1,  1056 };
  tp.d[4] = { nullptr, nullptr, 0, 0, 0, 1, 1 << 30 };
  tp.d[5] = { nullptr, nullptr, 0, 0, 0, 1, 1 << 30 };
  tp.d[6] = { nullptr, nullptr, 0, 0, 0, 1, 1 << 30 };
  tp.d[7] = { nullptr, nullptr, 0, 0, 0, 1, 1 << 30 };
  hipLaunchKernelGGL(k_prep, dim3(TBLK + CONVBLK), dim3(256), 0, stream, x, x_bf, tp, cosr);

  // decode/output-weight transposes: side blocks of the G13 launch (fill its tail round)
  TPack ts = {};
  ts.d[0] = { w_kdec, w_kvdT,                       2048, 512,  128, 16, 0    };
  ts.d[1] = { w_vdec, w_kvdT + (size_t)1024 * 512,  2048, 512,  64,  32, 128  };
  ts.d[2] = { w_qdec, w_qdPT,                       2048, 1536, 128, 16, 384  };
  ts.d[3] = { w_o,    w_oT,                         2048, 2048, 64,  32, 768  };
  ts.d[4] = { nullptr, nullptr, 0, 0, 0, 1, 1 << 30 };
  ts.d[5] = { nullptr, nullptr, 0, 0, 0, 1, 1 << 30 };
  ts.d[6] = { nullptr, nullptr, 0, 0, 0, 1, 1 << 30 };
  ts.d[7] = { nullptr, nullptr, 0, 0, 0, 1, 1 << 30 };
  TPack tz = {};

  // G13: xc = x @ [w_kv | w_qc | rope-pre], 544 gemm blocks (XCD-swizzled over ngemm=544)
  // + 1792 transpose side blocks = 2336 total. A straight from x when bf16.
  hipLaunchKernelGGL(k_gemm, dim3(2336, 1), dim3(256), 0, stream,
                     x_bf, DIM_, w_c1T, DIM_, xc, 2304, 1.0f,
                     x_bf, DIM_, w_c1T, DIM_, xc, 2304, 1.0f,
                     17, 1, (void*)nullptr, cosr,
                     (const u16*)x, (const u16*)x,
                     (u16*)nullptr, (u16*)nullptr,
                     (const u16*)nullptr, (const void*)nullptr, (const void*)nullptr,
                     (u16*)nullptr, (u16*)nullptr, (int*)nullptr,
                     544, 2, ts);
  // G4 + G2 + RoPE in ONE launch (1024 gemm blocks + 2048 rope blocks):
  //   flat<256:       qP = xc[:, 512:2048] @ w_qdecP  (K=1536, heavy group first)
  //   256<=flat<1024: K -> kvP (cols<1024); V -> vT direct transposed (cols>=1024)
  //   flat>=1024:     RoPE from xc cols 2048..
  hipLaunchKernelGGL(k_gemm, dim3(3072, 1), dim3(256), 0, stream,
                     xc + 512, 2304, w_qdPT, DCQ_, qP, 1024, SC2,
                     xc, 2304, w_kvdT, DC_, kvP, 1024, 1.0f,
                     8, 0, (void*)nullptr, (const u16*)nullptr,
                     (const u16*)nullptr, (const u16*)nullptr,
                     (u16*)nullptr, vT,
                     xc, cosp, sinp, krope, qrope, ticket,
                     1024, 1, tz);
  // attention (256 blocks = 1/CU, static uniform bundles: qt = 15-p then p, 17 tiles each)
  hipLaunchKernelGGL(k_attn, dim3(256), dim3(512), 0, stream,
                     qP, kvP, vT, krope, qrope, aout);
  // G5: out = aout @ w_o  (4096 x 2048, K=2048) -> (32,16) = 512 blocks = 2/CU, XCD-chunked
  hipLaunchKernelGGL(k_gemm, dim3(32, 16), dim3(256), 0, stream,
                     aout, DIM_, w_oT, DIM_, (u16*)nullptr, DIM_, 1.0f,
                     aout, DIM_, w_oT, DIM_, (u16*)nullptr, DIM_, 1.0f,
                     16, 1, d_out, cosr,
                     (const u16*)nullptr, (const u16*)nullptr,
                     (u16*)nullptr, (u16*)nullptr,
                     (const u16*)nullptr, (const void*)nullptr, (const void*)nullptr,
                     (u16*)nullptr, (u16*)nullptr, (int*)nullptr,
                     512, 0, tz);
}